// Round 5
// baseline (942.958 us; speedup 1.0000x reference)
//
#include <hip/hip_runtime.h>
#include <hip/hip_bf16.h>
#include <math.h>

// ---------------------------------------------------------------------------
// WNO1d. Round 24: producer-consumer fusion of (layer_i -> mix_{i+1}).
//  - layer blocks atomically accumulate proj results into LOacc[bb][x][c]
//    (device-scope f32 atomics = L3-coherent), then release-increment ctr[bb].
//  - 448 mix blocks appended to the same grid (scheduled last; capacity >>
//    448 so no deadlock): preload Ws into LDS, spin on 8 per-bb counters
//    (acquire + s_sleep), read LO, write next layer's D. Per-bb WAR on D is
//    safe (ctr[bb]==16 => all D[bb] readers exited).
//  - Ppart deleted (29.4MB/pair -> 14.7MB atomics). Dispatches 9 -> 6:
//    setup, mix0, fused x3, head. NOT grid.sync (round-2 disaster): only 448
//    consumers wait, on targeted counters; producers never stall.
// ---------------------------------------------------------------------------

#define BDIM 64
#define SLEN 1024
#define WCH  64
#define BC   (BDIM*WCH)

typedef short s16x8 __attribute__((ext_vector_type(8)));
typedef float f32x4 __attribute__((ext_vector_type(4)));
typedef unsigned short u16x4 __attribute__((ext_vector_type(4)));

constexpr float RLv[12] = {
    0.11154074335008017f, 0.4946238903983854f, 0.7511339080215775f,
    0.3152503517092432f, -0.22626469396516913f, -0.12976686756709563f,
    0.09750160558707936f, 0.02752286553001629f, -0.031582039318031156f,
    0.0005538422009938016f, 0.004777257511010651f, -0.00107730108499558f };
constexpr float AHv[12] = {
     RLv[11], -RLv[10],  RLv[9], -RLv[8],  RLv[7], -RLv[6],
     RLv[5],  -RLv[4],   RLv[3], -RLv[2],  RLv[1], -RLv[0] };
constexpr float SLv[12] = {
     RLv[11], RLv[10], RLv[9], RLv[8], RLv[7], RLv[6],
     RLv[5],  RLv[4],  RLv[3], RLv[2], RLv[1], RLv[0] };
constexpr float SHv[12] = {
    -RLv[0],  RLv[1], -RLv[2],  RLv[3], -RLv[4],  RLv[5],
    -RLv[6],  RLv[7], -RLv[8],  RLv[9], -RLv[10], RLv[11] };

__device__ __forceinline__ float gelu_f(float x) {
    float z = 0.7978845608f * (x + 0.044715f * x * x * x);
    return x / (1.0f + __expf(-2.0f * z));
}
__device__ __forceinline__ unsigned short f2bf(float f) {
    __hip_bfloat16 h = __float2bfloat16(f);
    union { __hip_bfloat16 h; unsigned short u; } cv; cv.h = h; return cv.u;
}
__device__ __forceinline__ float bf2f(unsigned short u) {
    union { unsigned short u; __hip_bfloat16 h; } cv; cv.u = u;
    return __bfloat162float(cv.h);
}
// unpack 8 packed u32 (as two uint4) -> hi frag + lo frag (8 v_perm)
__device__ __forceinline__ void unpack_frag2(uint4 a, uint4 b,
                                             s16x8* ah, s16x8* al) {
    union { s16x8 v; unsigned int d[4]; } H, L;
    H.d[0] = __builtin_amdgcn_perm(a.y, a.x, 0x05040100u);
    H.d[1] = __builtin_amdgcn_perm(a.w, a.z, 0x05040100u);
    H.d[2] = __builtin_amdgcn_perm(b.y, b.x, 0x05040100u);
    H.d[3] = __builtin_amdgcn_perm(b.w, b.z, 0x05040100u);
    L.d[0] = __builtin_amdgcn_perm(a.y, a.x, 0x07060302u);
    L.d[1] = __builtin_amdgcn_perm(a.w, a.z, 0x07060302u);
    L.d[2] = __builtin_amdgcn_perm(b.y, b.x, 0x07060302u);
    L.d[3] = __builtin_amdgcn_perm(b.w, b.z, 0x07060302u);
    *ah = H.v; *al = L.v;
}

// swizzled [c][s] plane (64x64 shorts)
__device__ __forceinline__ int swz(int c, int s) {
    return c * 64 + ((((s >> 3) ^ (c & 7)) << 3) | (s & 7));
}
// swizzled [s][c] plane
__device__ __forceinline__ int swz2(int s, int c) {
    return s * 64 + ((((c >> 3) ^ (s & 7)) << 3) | (c & 7));
}

// 2-wave proj with atomic LO accumulation. Wave w owns c-half.
__device__ __forceinline__ void proj2_acc(
    const unsigned short* Phi, const unsigned short* Plo,
    const unsigned short* __restrict__ Ahi, const unsigned short* __restrict__ Alo,
    float* __restrict__ LOacc, int bb, int s0, int t)
{
    const int lane = t & 63;
    const int w    = t >> 6;
    const int qr   = lane >> 4;
    const int ln   = lane & 15;

    s16x8 pah[2][2], pal[2][2];      // [kk][mt]
#pragma unroll
    for (int kk = 0; kk < 2; ++kk)
#pragma unroll
        for (int mt = 0; mt < 2; ++mt) {
            const int arow = (mt * 16 + ln) * SLEN + s0 + kk * 32 + qr * 8;
            pah[kk][mt] = *(const s16x8*)&Ahi[arow];
            pal[kk][mt] = *(const s16x8*)&Alo[arow];
        }

    f32x4 pP[2][2], pS[2][2];
#pragma unroll
    for (int mt = 0; mt < 2; ++mt)
#pragma unroll
        for (int ni = 0; ni < 2; ++ni) {
            pP[mt][ni] = (f32x4){0.f,0.f,0.f,0.f};
            pS[mt][ni] = (f32x4){0.f,0.f,0.f,0.f};
        }

#pragma unroll
    for (int kk = 0; kk < 2; ++kk) {
        const int bk = kk * 4 + qr;
#pragma unroll
        for (int ni = 0; ni < 2; ++ni) {
            const int c = w * 32 + ni * 16 + ln;
            const int boff = c * 64 + ((bk ^ (c & 7)) << 3);
            s16x8 bh = *(const s16x8*)&Phi[boff];
            s16x8 bl = *(const s16x8*)&Plo[boff];
#pragma unroll
            for (int mt = 0; mt < 2; ++mt) {
                pP[mt][ni] = __builtin_amdgcn_mfma_f32_16x16x32_bf16(pah[kk][mt], bh, pP[mt][ni], 0, 0, 0);
                pS[mt][ni] = __builtin_amdgcn_mfma_f32_16x16x32_bf16(pal[kk][mt], bh, pS[mt][ni], 0, 0, 0);
                pS[mt][ni] = __builtin_amdgcn_mfma_f32_16x16x32_bf16(pah[kk][mt], bl, pS[mt][ni], 0, 0, 0);
            }
        }
    }
#pragma unroll
    for (int mt = 0; mt < 2; ++mt)
#pragma unroll
        for (int ni = 0; ni < 2; ++ni) {
            const int c = w * 32 + ni * 16 + ln;
            f32x4 pv = pP[mt][ni] + pS[mt][ni];
#pragma unroll
            for (int r = 0; r < 4; ++r) {
                const int xr = mt * 16 + qr * 4 + r;
                if (xr < 28)
                    unsafeAtomicAdd(&LOacc[((size_t)bb * 28 + xr) * 64 + c], pv[r]);
            }
        }
}

// ---------------------------------------------------------------------------
// setup: 0..1023 A columns; 1024..1051 M rows; 1052..1117 data cascade;
//        1118..1125 weight prep (+ LOacc/ctr zero); 1126..1141 WsT transpose.
// ---------------------------------------------------------------------------
__global__ __launch_bounds__(256) void setup_kernel(
    const float* __restrict__ x,
    unsigned short* __restrict__ Ahi, unsigned short* __restrict__ Alo,
    unsigned short* __restrict__ MThi, unsigned short* __restrict__ MTlo,
    float* __restrict__ axbuf,
    const float* __restrict__ fc1w_0, const float* __restrict__ fc1w_1,
    const float* __restrict__ cw_0, const float* __restrict__ cw_1,
    const float* __restrict__ w1_0, const float* __restrict__ w2_0,
    const float* __restrict__ w1_1, const float* __restrict__ w2_1,
    unsigned short* __restrict__ w1hi, unsigned short* __restrict__ w1lo,
    unsigned short* __restrict__ cwPhi, unsigned short* __restrict__ cwPlo,
    unsigned short* __restrict__ Dhi,  unsigned short* __restrict__ Dlo,
    float* __restrict__ WsT,
    float* __restrict__ LOacc, int* __restrict__ ctr)
{
    __shared__ float Af[1024];
    __shared__ float Bff[520];
    __shared__ float hib[14];
    const int t = threadIdx.x;

    if (blockIdx.x < 1024 || (blockIdx.x >= 1052 && blockIdx.x < 1118)) {
        const bool isA = (blockIdx.x < 1024);
        const int s0 = blockIdx.x;
        const int di = blockIdx.x - 1052;
        for (int i = t; i < SLEN; i += 256) {
            float v;
            if (isA)           v = (i == s0) ? 1.0f : 0.0f;
            else if (di < 64)  v = x[di * SLEN + i];
            else if (di == 64) v = (float)i * (1.0f / 1023.0f);
            else               v = 1.0f;
            Af[i] = v;
        }
        __syncthreads();

        const int NIN[8]  = {1024, 517, 264, 137, 74, 42, 26, 18};
        const int NOUT[8] = { 517, 264, 137,  74, 42, 26, 18, 14};
#pragma unroll
        for (int lev = 0; lev < 8; ++lev) {
            float* in  = (lev & 1) ? Bff : Af;
            float* out = (lev & 1) ? Af : Bff;
            const int nin = NIN[lev], nout = NOUT[lev];
            for (int m = t; m < nout; m += 256) {
                float alo = 0.f, ahi = 0.f;
#pragma unroll
                for (int tt = 0; tt < 12; ++tt) {
                    int jj = 2 * m + tt - 10;
                    if (jj < 0)         jj = -1 - jj;
                    else if (jj >= nin) jj = 2 * nin - 1 - jj;
                    float xv = in[jj];
                    alo += xv * RLv[tt];
                    if (lev == 7) ahi += xv * AHv[tt];
                }
                out[m] = alo;
                if (lev == 7) {
                    if (isA) {
                        unsigned short h1 = f2bf(alo);
                        Ahi[m * SLEN + s0] = h1;
                        Alo[m * SLEN + s0] = f2bf(alo - bf2f(h1));
                        unsigned short h2 = f2bf(ahi);
                        Ahi[(14 + m) * SLEN + s0] = h2;
                        Alo[(14 + m) * SLEN + s0] = f2bf(ahi - bf2f(h2));
                    } else {
                        axbuf[di * 28 + m]      = alo;
                        axbuf[di * 28 + 14 + m] = ahi;
                    }
                }
            }
            __syncthreads();
        }
        if (isA && t < 4) {
            Ahi[(28 + t) * SLEN + s0] = 0; Alo[(28 + t) * SLEN + s0] = 0;
            MThi[s0 * 32 + 28 + t] = 0;    MTlo[s0 * 32 + 28 + t] = 0;
        }
        return;
    }

    if (blockIdx.x >= 1126) {
        // WsT: [(L*2+br)*28 + x][i*64+o] = (x<14 ? w1 : w2)[br][L][i][o][x%14]
        const int wsb = blockIdx.x - 1126;       // 0..15
        const int L = wsb >> 2, br = (wsb >> 1) & 1, which = wsb & 1;
        const float* src = (which ? (br ? w2_1 : w2_0) : (br ? w1_1 : w1_0))
                         + (size_t)L * 64 * 64 * 14;
        const size_t dbase = ((size_t)(L * 2 + br) * 28 + which * 14) * 4096;
        for (int e = t; e < 4096; e += 256) {
            const float* sp = src + (size_t)e * 14;
            float v[14];
#pragma unroll
            for (int xi = 0; xi < 14; ++xi) v[xi] = sp[xi];
#pragma unroll
            for (int xi = 0; xi < 14; ++xi)
                WsT[dbase + (size_t)xi * 4096 + e] = v[xi];
        }
        return;
    }

    if (blockIdx.x >= 1118) {
        // weight prep + LOacc/ctr zero
        const int gid = (blockIdx.x - 1118) * 256 + t;
        for (int idx = gid; idx < 16384; idx += 2048) {
            int br = idx >> 13, r = idx & 8191;
            int h = r >> 6, c = r & 63;
            float f = (br ? fc1w_1 : fc1w_0)[c * 128 + h];
            unsigned short hh = f2bf(f);
            w1hi[idx] = hh;
            w1lo[idx] = f2bf(f - bf2f(hh));
        }
        for (int idx = gid; idx < 32768; idx += 2048) {   // cwT split, all layers
            int L = idx >> 13, br = (idx >> 12) & 1, e = idx & 4095;
            int k = e >> 6, o = e & 63;
            float val = (br ? cw_1 : cw_0)[(size_t)L * 4096 + o * 64 + k]
                      + ((k == o) ? 1.0f : 0.0f);
            unsigned short h = f2bf(val);
            const int off = (L * 2 + br) * 4096 + o * 64 + k;
            cwPhi[off] = h;
            cwPlo[off] = f2bf(val - bf2f(h));
        }
        for (int idx = gid; idx < 32768; idx += 2048) {   // D pad rows 28..31
            int bb = idx >> 8, o = (idx >> 2) & 63, j = idx & 3;
            Dhi[bb * 2048 + o * 32 + 28 + j] = 0;
            Dlo[bb * 2048 + o * 32 + 28 + j] = 0;
        }
        for (int idx = gid; idx < 3 * 128 * 28 * 64; idx += 2048)
            LOacc[idx] = 0.f;
        for (int idx = gid; idx < 3 * 128; idx += 2048)
            ctr[idx] = 0;
        return;
    }

    // synthesis rows (M^T)
    const int u = blockIdx.x - 1024;     // 0..27
    if (t < 14) {
        Af[t]  = (u < 14 && t == u) ? 1.0f : 0.0f;
        hib[t] = (u >= 14 && t == (u - 14)) ? 1.0f : 0.0f;
    }
    __syncthreads();

    const int NH[8] = {14, 18, 26, 42, 74, 137, 264, 517};
    const int NO[8] = {18, 26, 42, 74, 138, 264, 518, 1024};

#pragma unroll
    for (int s = 0; s < 8; ++s) {
        const float* lo = (s & 1) ? Bff : Af;
        float* out      = (s & 1) ? Af : Bff;
        const int N = NH[s], nout = NO[s];
        for (int m = t; m < nout; m += 256) {
            float acc = 0.f;
#pragma unroll
            for (int tt = 0; tt < 12; ++tt) {
                int uu = m + tt - 1;
                if ((uu & 1) == 0) {
                    int q = uu >> 1;
                    if (q < N) {
                        acc += lo[q] * SLv[tt];
                        if (s == 0) acc += hib[q] * SHv[tt];
                    }
                }
            }
            out[m] = acc;
        }
        __syncthreads();
    }
    for (int m = t; m < SLEN; m += 256) {
        float f = Af[m];
        unsigned short h = f2bf(f);
        MThi[m * 32 + u] = h;
        MTlo[m * 32 + u] = f2bf(f - bf2f(h));
    }
}

// ---------------------------------------------------------------------------
// mix0: layer-0 mix from rank-3 formula. WsT0 = contiguous weight set 0.
// ---------------------------------------------------------------------------
__global__ __launch_bounds__(256) void mix0_kernel(
    const float* __restrict__ axbuf,
    const float* __restrict__ fc0w_0, const float* __restrict__ fc0b_0,
    const float* __restrict__ fc0w_1, const float* __restrict__ fc0b_1,
    const float* __restrict__ WsT0,
    unsigned short* __restrict__ Dhi, unsigned short* __restrict__ Dlo)
{
    const int t = threadIdx.x;
    const int br  = blockIdx.x / 224;
    const int sub = blockIdx.x % 224;

    __shared__ float Ws[64][65];
    __shared__ float LO[8][64];
    const int o = t & 63;
    const int w = t >> 6;
    const int x  = sub >> 3;
    const int b0 = (sub & 7) << 3;

    const float* wsrc = WsT0 + ((size_t)(br * 28 + x)) * 4096;
    for (int idx = t; idx < 4096; idx += 256)
        Ws[idx >> 6][idx & 63] = wsrc[idx];

    const float* fc0w = br ? fc0w_1 : fc0w_0;
    const float* fc0b = br ? fc0b_1 : fc0b_0;
    const float agv = axbuf[64 * 28 + x];
    const float a1v = axbuf[65 * 28 + x];
    const float w0o = fc0w[o];
    const float wgo = fc0w[WCH + o];
    const float b0o = fc0b[o];

#pragma unroll
    for (int j = 0; j < 2; ++j) {
        int bi = w + 4 * j;
        int b  = b0 + bi;
        float axv = axbuf[b * 28 + x];
        LO[bi][o] = axv * w0o + agv * wgo + a1v * b0o;
    }
    __syncthreads();

#pragma unroll
    for (int j = 0; j < 2; ++j) {
        int bi = w + 4 * j;
        int bb = br * 64 + b0 + bi;
        float acc = 0.f;
        for (int i = 0; i < 64; ++i)
            acc += LO[bi][i] * Ws[i][o];
        acc -= LO[bi][o];
        unsigned short h = f2bf(acc);
        Dhi[bb * 2048 + o * 32 + x] = h;
        Dlo[bb * 2048 + o * 32 + x] = f2bf(acc - bf2f(h));
    }
}

// ---------------------------------------------------------------------------
// Fused layer_i + mix_{i+1}. Blocks 0..2047: layer tile (2 waves, o-halves).
// Blocks 2048..2495: mix for next layer's D (spin on per-bb counters).
// ---------------------------------------------------------------------------
__global__ __launch_bounds__(128, 3) void fused_kernel(
    const unsigned int* __restrict__ vin0, const unsigned int* __restrict__ vin1,
    unsigned int* __restrict__ vout0, unsigned int* __restrict__ vout1,
    const unsigned short* __restrict__ MThi, const unsigned short* __restrict__ MTlo,
    const unsigned short* __restrict__ Ahi,  const unsigned short* __restrict__ Alo,
    const unsigned short* __restrict__ cwPhi, const unsigned short* __restrict__ cwPlo,
    unsigned short* __restrict__ Dhi,   unsigned short* __restrict__ Dlo,
    const float* __restrict__ cb_0, const float* __restrict__ cb_1,
    const float* __restrict__ fc0w_0, const float* __restrict__ fc0b_0,
    const float* __restrict__ fc0w_1, const float* __restrict__ fc0b_1,
    const float* __restrict__ xin,
    float* __restrict__ LOacc, int* __restrict__ ctr,
    const float* __restrict__ WsTnext, int Lidx)
{
    __shared__ __align__(16) char smem[64*65*4 + 8*64*4];   // 18688 B
    const int t = threadIdx.x;
    const int bid = blockIdx.x;

    if (bid >= 2048) {
        // ---------------- mix part: D for layer Lidx+1 ----------------
        float* Ws  = (float*)smem;                 // [64][65]
        float* LOs = (float*)(smem + 64 * 65 * 4); // [8][64]
        const int mb  = bid - 2048;
        const int br  = mb / 224;
        const int sub = mb % 224;
        const int x   = sub >> 3;
        const int b0  = (sub & 7) << 3;
        const int bbase = br * 64 + b0;

        // preload Ws while producers run (independent of them)
        const float* wsrc = WsTnext + ((size_t)(br * 28 + x)) * 4096;
        for (int idx = t; idx < 4096; idx += 128)
            Ws[(idx >> 6) * 65 + (idx & 63)] = wsrc[idx];

        // wait until all 16 tile-blocks of each of our 8 bbs are done
        if (t < 8) {
            int* cp = &ctr[bbase + t];
            while (__hip_atomic_load(cp, __ATOMIC_ACQUIRE,
                                     __HIP_MEMORY_SCOPE_AGENT) < 16)
                __builtin_amdgcn_s_sleep(8);
        }
        __syncthreads();
        __threadfence();     // acquire: invalidate stale lines before LO reads

        // stage LO (already fully summed by atomics)
        for (int e = t; e < 512; e += 128) {
            const int bi = e >> 6, c = e & 63;
            LOs[bi * 64 + c] = LOacc[((size_t)(bbase + bi) * 28 + x) * 64 + c];
        }
        __syncthreads();

        const int o = t & 63;
        const int w = t >> 6;
#pragma unroll
        for (int j = 0; j < 4; ++j) {
            const int bi = w * 4 + j;
            const int bb = bbase + bi;
            float acc = 0.f;
            for (int i = 0; i < 64; ++i)
                acc += LOs[bi * 64 + i] * Ws[i * 65 + o];
            acc -= LOs[bi * 64 + o];
            unsigned short h = f2bf(acc);
            Dhi[bb * 2048 + o * 32 + x] = h;
            Dlo[bb * 2048 + o * 32 + x] = f2bf(acc - bf2f(h));
        }
        return;
    }

    // ---------------- layer part ----------------
    unsigned short* Phi = (unsigned short*)smem;            // [4096]
    unsigned short* Plo = (unsigned short*)(smem + 8192);   // [4096]

    const int br  = bid >> 10;
    const int rem = bid & 1023;
    const int b    = rem >> 4;
    const int tile = rem & 15;
    const int s0   = tile << 6;
    const size_t bS = (size_t)b * SLEN;
    const unsigned int* vin = br ? vin1 : vin0;
    unsigned int* vout      = br ? vout1 : vout0;
    const float* cb = br ? cb_1 : cb_0;
    const float* f0w = br ? fc0w_1 : fc0w_0;
    const float* f0b = br ? fc0b_1 : fc0b_0;
    const int bb = br * 64 + b;
    const int cwbase = (Lidx * 2 + br) * 4096;

    const int lane = t & 63;
    const int w    = t >> 6;          // 0..1: o-half
    const int qr   = lane >> 4;
    const int ln   = lane & 15;

    // ---- preload B fragments for this wave's o-half ----
    s16x8 Bh[2][2], Bl[2][2];
#pragma unroll
    for (int kk = 0; kk < 2; ++kk)
#pragma unroll
        for (int ni = 0; ni < 2; ++ni) {
            const int o = w * 32 + ni * 16 + ln;
            const int boff = cwbase + o * 64 + kk * 32 + qr * 8;
            Bh[kk][ni] = *(const s16x8*)&cwPhi[boff];
            Bl[kk][ni] = *(const s16x8*)&cwPlo[boff];
        }
    s16x8 Dhf[2], Dlf[2];
#pragma unroll
    for (int ni = 0; ni < 2; ++ni) {
        const int o = w * 32 + ni * 16 + ln;
        const int boff = bb * 2048 + o * 32 + qr * 8;
        Dhf[ni] = *(const s16x8*)&Dhi[boff];
        Dlf[ni] = *(const s16x8*)&Dlo[boff];
    }
    float cbv[2];
#pragma unroll
    for (int ni = 0; ni < 2; ++ni) cbv[ni] = cb[w * 32 + ni * 16 + ln];

    // ---- prefetch vin (or x) for mi=0 ----
    uint4 vb[2][2];                 // [kk][half]
    float xpf = 0.f;
    if (Lidx == 0) {
        xpf = xin[bS + s0 + ln];
    } else {
        const size_t a0 = (bS + s0 + ln) * 64 + qr * 8;
        vb[0][0] = *(const uint4*)&vin[a0];
        vb[0][1] = *(const uint4*)&vin[a0 + 4];
        vb[1][0] = *(const uint4*)&vin[a0 + 32];
        vb[1][1] = *(const uint4*)&vin[a0 + 36];
    }

    // ---- 4 m-tiles ----
#pragma unroll
    for (int mi = 0; mi < 4; ++mi) {
        const int srow = mi * 16 + ln;
        uint4 vn[2][2];
        float xnf = 0.f;
        if (mi < 3) {
            if (Lidx == 0) {
                xnf = xin[bS + s0 + (mi + 1) * 16 + ln];
            } else {
                const size_t an = (bS + s0 + (mi + 1) * 16 + ln) * 64 + qr * 8;
                vn[0][0] = *(const uint4*)&vin[an];
                vn[0][1] = *(const uint4*)&vin[an + 4];
                vn[1][0] = *(const uint4*)&vin[an + 32];
                vn[1][1] = *(const uint4*)&vin[an + 36];
            }
        }

        f32x4 accP[2], accS[2];
#pragma unroll
        for (int ni = 0; ni < 2; ++ni) {
            accP[ni] = (f32x4){0.f,0.f,0.f,0.f};
            accS[ni] = (f32x4){0.f,0.f,0.f,0.f};
        }

#pragma unroll
        for (int kk = 0; kk < 2; ++kk) {
            s16x8 ah, al;
            if (Lidx == 0) {
                const int s = s0 + srow;
                const float gv = (float)s * (1.0f / 1023.0f);
#pragma unroll
                for (int j = 0; j < 8; ++j) {
                    const int c = kk * 32 + qr * 8 + j;
                    float val = xpf * f0w[c] + gv * f0w[WCH + c] + f0b[c];
                    unsigned short h = f2bf(val);
                    ah[j] = (short)h;
                    al[j] = (short)f2bf(val - bf2f(h));
                }
            } else {
                unpack_frag2(vb[kk][0], vb[kk][1], &ah, &al);
            }
#pragma unroll
            for (int ni = 0; ni < 2; ++ni) {
                accP[ni] = __builtin_amdgcn_mfma_f32_16x16x32_bf16(ah, Bh[kk][ni], accP[ni], 0, 0, 0);
                accS[ni] = __builtin_amdgcn_mfma_f32_16x16x32_bf16(al, Bh[kk][ni], accS[ni], 0, 0, 0);
                accS[ni] = __builtin_amdgcn_mfma_f32_16x16x32_bf16(ah, Bl[kk][ni], accS[ni], 0, 0, 0);
            }
        }
        {
            const size_t aoff = (size_t)(s0 + srow) * 32 + qr * 8;
            s16x8 mh = *(const s16x8*)&MThi[aoff];
            s16x8 ml = *(const s16x8*)&MTlo[aoff];
#pragma unroll
            for (int ni = 0; ni < 2; ++ni) {
                accP[ni] = __builtin_amdgcn_mfma_f32_16x16x32_bf16(mh, Dhf[ni], accP[ni], 0, 0, 0);
                accS[ni] = __builtin_amdgcn_mfma_f32_16x16x32_bf16(ml, Dhf[ni], accS[ni], 0, 0, 0);
                accS[ni] = __builtin_amdgcn_mfma_f32_16x16x32_bf16(mh, Dlf[ni], accS[ni], 0, 0, 0);
            }
        }
        // epilogue: gelu, split, packed global store + packed b64 LDS writes
#pragma unroll
        for (int ni = 0; ni < 2; ++ni) {
            const int o = w * 32 + ni * 16 + ln;
            f32x4 acc = accP[ni] + accS[ni];
            u16x4 hv, lv;
#pragma unroll
            for (int r = 0; r < 4; ++r) {
                const int sl64 = mi * 16 + qr * 4 + r;
                float val = gelu_f(acc[r] + cbv[ni]);
                unsigned short h = f2bf(val);
                unsigned short l = f2bf(val - bf2f(h));
                vout[(bS + s0 + sl64) * 64 + o] =
                    (unsigned int)h | ((unsigned int)l << 16);
                hv[r] = h;
                lv[r] = l;
            }
            const int a = swz(o, mi * 16 + qr * 4);
            *(u16x4*)&Phi[a] = hv;
            *(u16x4*)&Plo[a] = lv;
        }
        if (mi < 3) {
            if (Lidx == 0) {
                xpf = xnf;
            } else {
                vb[0][0] = vn[0][0]; vb[0][1] = vn[0][1];
                vb[1][0] = vn[1][0]; vb[1][1] = vn[1][1];
            }
        }
    }

    // ---- proj on own c-half -> atomic LO accumulation ----
    proj2_acc(Phi, Plo, Ahi, Alo, LOacc, bb, s0, t);

    // release: LO atomics visible, then signal
    __threadfence();
    __syncthreads();
    if (t == 0)
        __hip_atomic_fetch_add(&ctr[bb], 1, __ATOMIC_RELEASE,
                               __HIP_MEMORY_SCOPE_AGENT);
}

// ---------------------------------------------------------------------------
// Head with fused layer 3, BOTH branches: 256-thread blocks (4 waves =
// {br}x{o-half}). vin prefetch + P/S chains in both phases.
// ---------------------------------------------------------------------------
__global__ __launch_bounds__(256, 2) void head_kernel(
    const unsigned int* __restrict__ vin0, const unsigned int* __restrict__ vin1,
    const unsigned short* __restrict__ MThi, const unsigned short* __restrict__ MTlo,
    const unsigned short* __restrict__ cwPhi, const unsigned short* __restrict__ cwPlo,
    const unsigned short* __restrict__ Dhi,   const unsigned short* __restrict__ Dlo,
    const float* __restrict__ cb_0, const float* __restrict__ cb_1,
    const unsigned short* __restrict__ w1hi, const unsigned short* __restrict__ w1lo,
    const float* __restrict__ fc1b_0, const float* __restrict__ fc2w_0,
    const float* __restrict__ fc2b_0,
    const float* __restrict__ fc1b_1, const float* __restrict__ fc2w_1,
    const float* __restrict__ fc2b_1,
    float* __restrict__ out)
{
    __shared__ unsigned short Vh[8192];    // [br][swz2 plane]
    __shared__ unsigned short Vl[8192];
    __shared__ float SP[4][64];            // per-wave partials

    const int t = threadIdx.x;
    const int bid = blockIdx.x;            // 0..1023
    const int b    = bid >> 4;
    const int tile = bid & 15;
    const int s0   = tile << 6;
    const size_t bS = (size_t)b * SLEN;

    const int lane = t & 63;
    const int w    = t >> 6;          // 0..3
    const int br   = w >> 1;
    const int half = w & 1;
    const int qr   = lane >> 4;
    const int ln   = lane & 15;

    const unsigned int* vin = br ? vin1 : vin0;
    const float* cb   = (br ? cb_1 : cb_0) + 3 * WCH;
    const float* fc1b = br ? fc1b_1 : fc1b_0;
    const float* fc2w = br ? fc2w_1 : fc2w_0;
    const int bb = br * 64 + b;
    const int cwbase = (3 * 2 + br) * 4096;
    unsigned short* Vhp = Vh + br * 4096;
    unsigned short* Vlp = Vl + br * 4096;

    // ---- phase A: layer-3, own (br, 32-o half) ----
    {
        s16x8 Bh[2][2], Bl[2][2];
#pragma unroll
        for (int kk = 0; kk < 2; ++kk)
#pragma unroll
            for (int ni = 0; ni < 2; ++ni) {
                const int o = half * 32 + ni * 16 + ln;
                const int boff = cwbase + o * 64 + kk * 32 + qr * 8;
                Bh[kk][ni] = *(const s16x8*)&cwPhi[boff];
                Bl[kk][ni] = *(const s16x8*)&cwPlo[boff];
            }
        s16x8 Dhf[2], Dlf[2];
#pragma unroll
        for (int ni = 0; ni < 2; ++ni) {
            const int o = half * 32 + ni * 16 + ln;
            const int boff = bb * 2048 + o * 32 + qr * 8;
            Dhf[ni] = *(const s16x8*)&Dhi[boff];
            Dlf[ni] = *(const s16x8*)&Dlo[boff];
        }
        float cbv[2];
#pragma unroll
        for (int ni = 0; ni < 2; ++ni) cbv[ni] = cb[half * 32 + ni * 16 + ln];

        uint4 vb[2][2];
        {
            const size_t a0 = (bS + s0 + ln) * 64 + qr * 8;
            vb[0][0] = *(const uint4*)&vin[a0];
            vb[0][1] = *(const uint4*)&vin[a0 + 4];
            vb[1][0] = *(const uint4*)&vin[a0 + 32];
            vb[1][1] = *(const uint4*)&vin[a0 + 36];
        }

#pragma unroll
        for (int mi = 0; mi < 4; ++mi) {
            uint4 vn[2][2];
            if (mi < 3) {
                const size_t an = (bS + s0 + (mi + 1) * 16 + ln) * 64 + qr * 8;
                vn[0][0] = *(const uint4*)&vin[an];
                vn[0][1] = *(const uint4*)&vin[an + 4];
                vn[1][0] = *(const uint4*)&vin[an + 32];
                vn[1][1] = *(const uint4*)&vin[an + 36];
            }
            const int srow = mi * 16 + ln;
            f32x4 accP[2], accS[2];
#pragma unroll
            for (int ni = 0; ni < 2; ++ni) {
                accP[ni] = (f32x4){0.f,0.f,0.f,0.f};
                accS[ni] = (f32x4){0.f,0.f,0.f,0.f};
            }

#pragma unroll
            for (int kk = 0; kk < 2; ++kk) {
                s16x8 ah, al;
                unpack_frag2(vb[kk][0], vb[kk][1], &ah, &al);
#pragma unroll
                for (int ni = 0; ni < 2; ++ni) {
                    accP[ni] = __builtin_amdgcn_mfma_f32_16x16x32_bf16(ah, Bh[kk][ni], accP[ni], 0, 0, 0);
                    accS[ni] = __builtin_amdgcn_mfma_f32_16x16x32_bf16(al, Bh[kk][ni], accS[ni], 0, 0, 0);
                    accS[ni] = __builtin_amdgcn_mfma_f32_16x16x32_bf16(ah, Bl[kk][ni], accS[ni], 0, 0, 0);
                }
            }
            {
                const size_t aoff = (size_t)(s0 + srow) * 32 + qr * 8;
                s16x8 mh = *(const s16x8*)&MThi[aoff];
                s16x8 ml = *(const s16x8*)&MTlo[aoff];
#pragma unroll
                for (int ni = 0; ni < 2; ++ni) {
                    accP[ni] = __builtin_amdgcn_mfma_f32_16x16x32_bf16(mh, Dhf[ni], accP[ni], 0, 0, 0);
                    accS[ni] = __builtin_amdgcn_mfma_f32_16x16x32_bf16(ml, Dhf[ni], accS[ni], 0, 0, 0);
                    accS[ni] = __builtin_amdgcn_mfma_f32_16x16x32_bf16(mh, Dlf[ni], accS[ni], 0, 0, 0);
                }
            }
#pragma unroll
            for (int ni = 0; ni < 2; ++ni) {
                const int o = half * 32 + ni * 16 + ln;
                f32x4 acc = accP[ni] + accS[ni];
#pragma unroll
                for (int r = 0; r < 4; ++r) {
                    const int sl64 = mi * 16 + qr * 4 + r;
                    float val = acc[r] + cbv[ni];
                    unsigned short h = f2bf(val);
                    unsigned short l = f2bf(val - bf2f(h));
                    const int a = swz2(sl64, o);
                    Vhp[a] = h;
                    Vlp[a] = l;
                }
            }
            if (mi < 3) {
                vb[0][0] = vn[0][0]; vb[0][1] = vn[0][1];
                vb[1][0] = vn[1][0]; vb[1][1] = vn[1][1];
            }
        }
    }
    __syncthreads();

    // ---- phase B: fc1 GEMM, own (br, 64-h half) ----
    s16x8 Wh[2][4], Wl[2][4];
#pragma unroll
    for (int kk = 0; kk < 2; ++kk)
#pragma unroll
        for (int ni = 0; ni < 4; ++ni) {
            const int h = half * 64 + ni * 16 + ln;
            const int boff = br * 8192 + h * 64 + kk * 32 + qr * 8;
            Wh[kk][ni] = *(const s16x8*)&w1hi[boff];
            Wl[kk][ni] = *(const s16x8*)&w1lo[boff];
        }
    float b1v[4], w2v[4];
#pragma unroll
    for (int ni = 0; ni < 4; ++ni) {
        b1v[ni] = fc1b[half * 64 + ni * 16 + ln];
        w2v[ni] = fc2w[half * 64 + ni * 16 + ln];
    }

#pragma unroll
    for (int mi = 0; mi < 4; ++mi) {
        f32x4 a1P[4], a1S[4];
#pragma unroll
        for (int ni = 0; ni < 4; ++ni) {
            a1P[ni] = (f32x4){0.f,0.f,0.f,0.f};
            a1S[ni] = (f32x4){0.f,0.f,0.f,0.f};
        }

#pragma unroll
        for (int kk = 0; kk < 2; ++kk) {
            const int blk = kk * 4 + qr;
            const int sl  = mi * 16 + ln;
            const int a   = sl * 64 + ((blk ^ (sl & 7)) << 3);
            s16x8 ah = *(const s16x8*)&Vhp[a];
            s16x8 al = *(const s16x8*)&Vlp[a];
#pragma unroll
            for (int ni = 0; ni < 4; ++ni) {
                a1P[ni] = __builtin_amdgcn_mfma_f32_16x16x32_bf16(ah, Wh[kk][ni], a1P[ni], 0, 0, 0);
                a1S[ni] = __builtin_amdgcn_mfma_f32_16x16x32_bf16(al, Wh[kk][ni], a1S[ni], 0, 0, 0);
                a1S[ni] = __builtin_amdgcn_mfma_f32_16x16x32_bf16(ah, Wl[kk][ni], a1S[ni], 0, 0, 0);
            }
        }
        float partial[4] = {0.f, 0.f, 0.f, 0.f};
#pragma unroll
        for (int ni = 0; ni < 4; ++ni) {
            f32x4 acc1 = a1P[ni] + a1S[ni];
#pragma unroll
            for (int r = 0; r < 4; ++r)
                partial[r] += gelu_f(acc1[r] + b1v[ni]) * w2v[ni];
        }
#pragma unroll
        for (int r = 0; r < 4; ++r) {
            partial[r] += __shfl_xor(partial[r], 1, 64);
            partial[r] += __shfl_xor(partial[r], 2, 64);
            partial[r] += __shfl_xor(partial[r], 4, 64);
            partial[r] += __shfl_xor(partial[r], 8, 64);
        }
        if (ln == 0) {
#pragma unroll
            for (int r = 0; r < 4; ++r)
                SP[w][mi * 16 + qr * 4 + r] = partial[r];
        }
    }
    __syncthreads();

    if (t < 64) {
        const float bias = fc2b_0[0] + fc2b_1[0];
        out[bS + s0 + t] = SP[0][t] + SP[1][t] + SP[2][t] + SP[3][t] + bias;
    }
}

// ---------------------------------------------------------------------------
extern "C" void kernel_launch(void* const* d_in, const int* in_sizes, int n_in,
                              void* d_out, int out_size, void* d_ws, size_t ws_size,
                              hipStream_t stream)
{
    const float* x = (const float*)d_in[0];
    const float* P[2][10];
    for (int br = 0; br < 2; ++br)
        for (int k = 0; k < 10; ++k)
            P[br][k] = (const float*)d_in[1 + br * 10 + k];
    // order: fc0_w, fc0_b, wave_w1, wave_w2, cw, cb, fc1_w, fc1_b, fc2_w, fc2_b

    char* p = (char*)d_ws;
    const size_t PL = (size_t)BC * SLEN * 4;   // one packed u32 plane: 16.78 MB
    unsigned int* vplane[4];                   // [br][pingpong]
    for (int i = 0; i < 4; ++i) { vplane[i] = (unsigned int*)p; p += PL; }
    unsigned short* Ahi  = (unsigned short*)p; p += 32 * SLEN * 2;
    unsigned short* Alo  = (unsigned short*)p; p += 32 * SLEN * 2;
    unsigned short* MThi = (unsigned short*)p; p += SLEN * 32 * 2;
    unsigned short* MTlo = (unsigned short*)p; p += SLEN * 32 * 2;
    unsigned short* cwPhi = (unsigned short*)p; p += 8 * 4096 * 2;   // [L][br]
    unsigned short* cwPlo = (unsigned short*)p; p += 8 * 4096 * 2;
    unsigned short* Dhi   = (unsigned short*)p; p += (size_t)128 * 2048 * 2;
    unsigned short* Dlo   = (unsigned short*)p; p += (size_t)128 * 2048 * 2;
    unsigned short* w1hi  = (unsigned short*)p; p += 2 * 8192 * 2;
    unsigned short* w1lo  = (unsigned short*)p; p += 2 * 8192 * 2;
    float* axbuf          = (float*)p;          p += 66 * 28 * 4;
    float* WsT            = (float*)p;          p += (size_t)4 * 2 * 28 * 4096 * 4;
    float* LOacc          = (float*)p;          p += (size_t)3 * 128 * 28 * 64 * 4;
    int*   ctr            = (int*)p;            p += 3 * 128 * 4;

    unsigned int *v0a = vplane[0], *v0b = vplane[1];
    unsigned int *v1a = vplane[2], *v1b = vplane[3];

    setup_kernel<<<1142, 256, 0, stream>>>(
        x, Ahi, Alo, MThi, MTlo, axbuf,
        P[0][6], P[1][6], P[0][4], P[1][4],
        P[0][2], P[0][3], P[1][2], P[1][3],
        w1hi, w1lo, cwPhi, cwPlo, Dhi, Dlo, WsT, LOacc, ctr);

    mix0_kernel<<<448, 256, 0, stream>>>(
        axbuf, P[0][0], P[0][1], P[1][0], P[1][1],
        WsT, Dhi, Dlo);

    for (int i = 0; i < 3; ++i) {
        fused_kernel<<<2496, 128, 0, stream>>>(
            v0a, v1a, v0b, v1b,
            MThi, MTlo, Ahi, Alo, cwPhi, cwPlo, Dhi, Dlo,
            P[0][5] + (size_t)i * WCH, P[1][5] + (size_t)i * WCH,
            P[0][0], P[0][1], P[1][0], P[1][1], x,
            LOacc + (size_t)i * 128 * 28 * 64,
            ctr + i * 128,
            WsT + (size_t)(i + 1) * 2 * 28 * 4096,
            i);
        unsigned int* tmp;
        tmp = v0a; v0a = v0b; v0b = tmp;
        tmp = v1a; v1a = v1b; v1b = tmp;
    }

    head_kernel<<<1024, 256, 0, stream>>>(
        v0a, v1a,
        MThi, MTlo, cwPhi, cwPlo, Dhi, Dlo,
        P[0][5] + (size_t)3 * WCH, P[1][5] + (size_t)3 * WCH,
        w1hi, w1lo,
        P[0][7], P[0][8], P[0][9],
        P[1][7], P[1][8], P[1][9],
        (float*)d_out);
}

// Round 6
// 266.854 us; speedup vs baseline: 3.5336x; 3.5336x over previous
//
#include <hip/hip_runtime.h>
#include <hip/hip_bf16.h>
#include <math.h>

// ---------------------------------------------------------------------------
// WNO1d. Round 25: revert producer-consumer atomics (R5: 943us — device-scope
// atomic RMW serialization + non-resident consumers; kernel boundary IS the
// cheap sync on 8-XCD CDNA4). Back to R3/R4 9-dispatch structure, with finer
// layer decomposition: 2048 -> 4096 blocks (32-s tiles), LDS 16KB -> 8KB,
// per-wave MFMA halves, proj = single K=32 phase -> own Ppart plane (mix sums
// 32 planes). More resident waves/CU (16 -> ~24), shorter per-block chains.
// ---------------------------------------------------------------------------

#define BDIM 64
#define SLEN 1024
#define WCH  64
#define BC   (BDIM*WCH)
#define NT2  32         // 32-s proj tiles per batch

typedef short s16x8 __attribute__((ext_vector_type(8)));
typedef float f32x4 __attribute__((ext_vector_type(4)));
typedef unsigned short u16x4 __attribute__((ext_vector_type(4)));

constexpr float RLv[12] = {
    0.11154074335008017f, 0.4946238903983854f, 0.7511339080215775f,
    0.3152503517092432f, -0.22626469396516913f, -0.12976686756709563f,
    0.09750160558707936f, 0.02752286553001629f, -0.031582039318031156f,
    0.0005538422009938016f, 0.004777257511010651f, -0.00107730108499558f };
constexpr float AHv[12] = {
     RLv[11], -RLv[10],  RLv[9], -RLv[8],  RLv[7], -RLv[6],
     RLv[5],  -RLv[4],   RLv[3], -RLv[2],  RLv[1], -RLv[0] };
constexpr float SLv[12] = {
     RLv[11], RLv[10], RLv[9], RLv[8], RLv[7], RLv[6],
     RLv[5],  RLv[4],  RLv[3], RLv[2], RLv[1], RLv[0] };
constexpr float SHv[12] = {
    -RLv[0],  RLv[1], -RLv[2],  RLv[3], -RLv[4],  RLv[5],
    -RLv[6],  RLv[7], -RLv[8],  RLv[9], -RLv[10], RLv[11] };

__device__ __forceinline__ float gelu_f(float x) {
    float z = 0.7978845608f * (x + 0.044715f * x * x * x);
    return x / (1.0f + __expf(-2.0f * z));
}
__device__ __forceinline__ unsigned short f2bf(float f) {
    __hip_bfloat16 h = __float2bfloat16(f);
    union { __hip_bfloat16 h; unsigned short u; } cv; cv.h = h; return cv.u;
}
__device__ __forceinline__ float bf2f(unsigned short u) {
    union { unsigned short u; __hip_bfloat16 h; } cv; cv.u = u;
    return __bfloat162float(cv.h);
}
// unpack 8 packed u32 (as two uint4) -> hi frag + lo frag (8 v_perm)
__device__ __forceinline__ void unpack_frag2(uint4 a, uint4 b,
                                             s16x8* ah, s16x8* al) {
    union { s16x8 v; unsigned int d[4]; } H, L;
    H.d[0] = __builtin_amdgcn_perm(a.y, a.x, 0x05040100u);
    H.d[1] = __builtin_amdgcn_perm(a.w, a.z, 0x05040100u);
    H.d[2] = __builtin_amdgcn_perm(b.y, b.x, 0x05040100u);
    H.d[3] = __builtin_amdgcn_perm(b.w, b.z, 0x05040100u);
    L.d[0] = __builtin_amdgcn_perm(a.y, a.x, 0x07060302u);
    L.d[1] = __builtin_amdgcn_perm(a.w, a.z, 0x07060302u);
    L.d[2] = __builtin_amdgcn_perm(b.y, b.x, 0x07060302u);
    L.d[3] = __builtin_amdgcn_perm(b.w, b.z, 0x07060302u);
    *ah = H.v; *al = L.v;
}

// swizzled [c][s32] plane (64x32 shorts): 16B blocks XORed per row
__device__ __forceinline__ int swz32(int c, int s) {
    return c * 32 + ((((s >> 3) ^ (c & 3)) << 3) | (s & 7));
}
// swizzled [s][c] plane (64x64)
__device__ __forceinline__ int swz2(int s, int c) {
    return s * 64 + ((((c >> 3) ^ (s & 7)) << 3) | (c & 7));
}

// ---------------------------------------------------------------------------
// setup: 0..1023 A columns; 1024..1051 M rows; 1052..1117 data cascade;
//        1118..1125 weight prep; 1126..1141 WsT transpose.
// ---------------------------------------------------------------------------
__global__ __launch_bounds__(256) void setup_kernel(
    const float* __restrict__ x,
    unsigned short* __restrict__ Ahi, unsigned short* __restrict__ Alo,
    unsigned short* __restrict__ MThi, unsigned short* __restrict__ MTlo,
    float* __restrict__ axbuf,
    const float* __restrict__ fc1w_0, const float* __restrict__ fc1w_1,
    const float* __restrict__ cw_0, const float* __restrict__ cw_1,
    const float* __restrict__ w1_0, const float* __restrict__ w2_0,
    const float* __restrict__ w1_1, const float* __restrict__ w2_1,
    unsigned short* __restrict__ w1hi, unsigned short* __restrict__ w1lo,
    unsigned short* __restrict__ cwPhi, unsigned short* __restrict__ cwPlo,
    unsigned short* __restrict__ Dhi,  unsigned short* __restrict__ Dlo,
    float* __restrict__ WsT)
{
    __shared__ float Af[1024];
    __shared__ float Bff[520];
    __shared__ float hib[14];
    const int t = threadIdx.x;

    if (blockIdx.x < 1024 || (blockIdx.x >= 1052 && blockIdx.x < 1118)) {
        const bool isA = (blockIdx.x < 1024);
        const int s0 = blockIdx.x;
        const int di = blockIdx.x - 1052;
        for (int i = t; i < SLEN; i += 256) {
            float v;
            if (isA)           v = (i == s0) ? 1.0f : 0.0f;
            else if (di < 64)  v = x[di * SLEN + i];
            else if (di == 64) v = (float)i * (1.0f / 1023.0f);
            else               v = 1.0f;
            Af[i] = v;
        }
        __syncthreads();

        const int NIN[8]  = {1024, 517, 264, 137, 74, 42, 26, 18};
        const int NOUT[8] = { 517, 264, 137,  74, 42, 26, 18, 14};
#pragma unroll
        for (int lev = 0; lev < 8; ++lev) {
            float* in  = (lev & 1) ? Bff : Af;
            float* out = (lev & 1) ? Af : Bff;
            const int nin = NIN[lev], nout = NOUT[lev];
            for (int m = t; m < nout; m += 256) {
                float alo = 0.f, ahi = 0.f;
#pragma unroll
                for (int tt = 0; tt < 12; ++tt) {
                    int jj = 2 * m + tt - 10;
                    if (jj < 0)         jj = -1 - jj;
                    else if (jj >= nin) jj = 2 * nin - 1 - jj;
                    float xv = in[jj];
                    alo += xv * RLv[tt];
                    if (lev == 7) ahi += xv * AHv[tt];
                }
                out[m] = alo;
                if (lev == 7) {
                    if (isA) {
                        unsigned short h1 = f2bf(alo);
                        Ahi[m * SLEN + s0] = h1;
                        Alo[m * SLEN + s0] = f2bf(alo - bf2f(h1));
                        unsigned short h2 = f2bf(ahi);
                        Ahi[(14 + m) * SLEN + s0] = h2;
                        Alo[(14 + m) * SLEN + s0] = f2bf(ahi - bf2f(h2));
                    } else {
                        axbuf[di * 28 + m]      = alo;
                        axbuf[di * 28 + 14 + m] = ahi;
                    }
                }
            }
            __syncthreads();
        }
        if (isA && t < 4) {
            Ahi[(28 + t) * SLEN + s0] = 0; Alo[(28 + t) * SLEN + s0] = 0;
            MThi[s0 * 32 + 28 + t] = 0;    MTlo[s0 * 32 + 28 + t] = 0;
        }
        return;
    }

    if (blockIdx.x >= 1126) {
        // WsT: [(L*2+br)*28 + x][i*64+o]
        const int wsb = blockIdx.x - 1126;       // 0..15
        const int L = wsb >> 2, br = (wsb >> 1) & 1, which = wsb & 1;
        const float* src = (which ? (br ? w2_1 : w2_0) : (br ? w1_1 : w1_0))
                         + (size_t)L * 64 * 64 * 14;
        const size_t dbase = ((size_t)(L * 2 + br) * 28 + which * 14) * 4096;
        for (int e = t; e < 4096; e += 256) {
            const float* sp = src + (size_t)e * 14;
            float v[14];
#pragma unroll
            for (int xi = 0; xi < 14; ++xi) v[xi] = sp[xi];
#pragma unroll
            for (int xi = 0; xi < 14; ++xi)
                WsT[dbase + (size_t)xi * 4096 + e] = v[xi];
        }
        return;
    }

    if (blockIdx.x >= 1118) {
        // weight prep
        const int gid = (blockIdx.x - 1118) * 256 + t;
        for (int idx = gid; idx < 16384; idx += 2048) {
            int br = idx >> 13, r = idx & 8191;
            int h = r >> 6, c = r & 63;
            float f = (br ? fc1w_1 : fc1w_0)[c * 128 + h];
            unsigned short hh = f2bf(f);
            w1hi[idx] = hh;
            w1lo[idx] = f2bf(f - bf2f(hh));
        }
        for (int idx = gid; idx < 32768; idx += 2048) {   // cwT split, all layers
            int L = idx >> 13, br = (idx >> 12) & 1, e = idx & 4095;
            int k = e >> 6, o = e & 63;
            float val = (br ? cw_1 : cw_0)[(size_t)L * 4096 + o * 64 + k]
                      + ((k == o) ? 1.0f : 0.0f);
            unsigned short h = f2bf(val);
            const int off = (L * 2 + br) * 4096 + o * 64 + k;
            cwPhi[off] = h;
            cwPlo[off] = f2bf(val - bf2f(h));
        }
        for (int idx = gid; idx < 32768; idx += 2048) {   // D pad rows 28..31
            int bb = idx >> 8, o = (idx >> 2) & 63, j = idx & 3;
            Dhi[bb * 2048 + o * 32 + 28 + j] = 0;
            Dlo[bb * 2048 + o * 32 + 28 + j] = 0;
        }
        return;
    }

    // synthesis rows (M^T)
    const int u = blockIdx.x - 1024;     // 0..27
    if (t < 14) {
        Af[t]  = (u < 14 && t == u) ? 1.0f : 0.0f;
        hib[t] = (u >= 14 && t == (u - 14)) ? 1.0f : 0.0f;
    }
    __syncthreads();

    const int NH[8] = {14, 18, 26, 42, 74, 137, 264, 517};
    const int NO[8] = {18, 26, 42, 74, 138, 264, 518, 1024};

#pragma unroll
    for (int s = 0; s < 8; ++s) {
        const float* lo = (s & 1) ? Bff : Af;
        float* out      = (s & 1) ? Af : Bff;
        const int N = NH[s], nout = NO[s];
        for (int m = t; m < nout; m += 256) {
            float acc = 0.f;
#pragma unroll
            for (int tt = 0; tt < 12; ++tt) {
                int uu = m + tt - 1;
                if ((uu & 1) == 0) {
                    int q = uu >> 1;
                    if (q < N) {
                        acc += lo[q] * SLv[tt];
                        if (s == 0) acc += hib[q] * SHv[tt];
                    }
                }
            }
            out[m] = acc;
        }
        __syncthreads();
    }
    for (int m = t; m < SLEN; m += 256) {
        float f = Af[m];
        unsigned short h = f2bf(f);
        MThi[m * 32 + u] = h;
        MTlo[m * 32 + u] = f2bf(f - bf2f(h));
    }
}

// ---------------------------------------------------------------------------
// mix0: layer-0 mix from rank-3 formula. WsT0 = contiguous weight set 0.
// ---------------------------------------------------------------------------
__global__ __launch_bounds__(256) void mix0_kernel(
    const float* __restrict__ axbuf,
    const float* __restrict__ fc0w_0, const float* __restrict__ fc0b_0,
    const float* __restrict__ fc0w_1, const float* __restrict__ fc0b_1,
    const float* __restrict__ WsT0,
    unsigned short* __restrict__ Dhi, unsigned short* __restrict__ Dlo)
{
    const int t = threadIdx.x;
    const int br  = blockIdx.x / 224;
    const int sub = blockIdx.x % 224;

    __shared__ float Ws[64][65];
    __shared__ float LO[8][64];
    const int o = t & 63;
    const int w = t >> 6;
    const int x  = sub >> 3;
    const int b0 = (sub & 7) << 3;

    const float* wsrc = WsT0 + ((size_t)(br * 28 + x)) * 4096;
    for (int idx = t; idx < 4096; idx += 256)
        Ws[idx >> 6][idx & 63] = wsrc[idx];

    const float* fc0w = br ? fc0w_1 : fc0w_0;
    const float* fc0b = br ? fc0b_1 : fc0b_0;
    const float agv = axbuf[64 * 28 + x];
    const float a1v = axbuf[65 * 28 + x];
    const float w0o = fc0w[o];
    const float wgo = fc0w[WCH + o];
    const float b0o = fc0b[o];

#pragma unroll
    for (int j = 0; j < 2; ++j) {
        int bi = w + 4 * j;
        int b  = b0 + bi;
        float axv = axbuf[b * 28 + x];
        LO[bi][o] = axv * w0o + agv * wgo + a1v * b0o;
    }
    __syncthreads();

#pragma unroll
    for (int j = 0; j < 2; ++j) {
        int bi = w + 4 * j;
        int bb = br * 64 + b0 + bi;
        float acc = 0.f;
        for (int i = 0; i < 64; ++i)
            acc += LO[bi][i] * Ws[i][o];
        acc -= LO[bi][o];
        unsigned short h = f2bf(acc);
        Dhi[bb * 2048 + o * 32 + x] = h;
        Dlo[bb * 2048 + o * 32 + x] = f2bf(acc - bf2f(h));
    }
}

// ---------------------------------------------------------------------------
// Mix (layers 1..3): reads 32 Ppart planes per bb; WsTL contiguous weights.
// ---------------------------------------------------------------------------
__global__ __launch_bounds__(256) void mix_kernel(
    const float* __restrict__ Ppart,
    const float* __restrict__ WsTL,
    unsigned short* __restrict__ Dhi, unsigned short* __restrict__ Dlo)
{
    const int t = threadIdx.x;
    const int br  = blockIdx.x / 224;
    const int sub = blockIdx.x % 224;

    __shared__ float Ws[64][65];
    __shared__ float LO[8][64];
    const int o = t & 63;
    const int w = t >> 6;
    const int x  = sub >> 3;
    const int b0 = (sub & 7) << 3;

    const float* wsrc = WsTL + ((size_t)(br * 28 + x)) * 4096;
    for (int idx = t; idx < 4096; idx += 256)
        Ws[idx >> 6][idx & 63] = wsrc[idx];

#pragma unroll
    for (int j = 0; j < 2; ++j) {
        int bi = w + 4 * j;
        int bb = br * 64 + b0 + bi;
        float s = 0.f;
        for (int tp = 0; tp < NT2; ++tp)
            s += Ppart[((size_t)(bb * NT2 + tp) * 28 + x) * 64 + o];
        LO[bi][o] = s;
    }
    __syncthreads();

#pragma unroll
    for (int j = 0; j < 2; ++j) {
        int bi = w + 4 * j;
        int bb = br * 64 + b0 + bi;
        float acc = 0.f;
        for (int i = 0; i < 64; ++i)
            acc += LO[bi][i] * Ws[i][o];
        acc -= LO[bi][o];
        unsigned short h = f2bf(acc);
        Dhi[bb * 2048 + o * 32 + x] = h;
        Dlo[bb * 2048 + o * 32 + x] = f2bf(acc - bf2f(h));
    }
}

// ---------------------------------------------------------------------------
// Fused layer (i = 0,1,2): 4096 blocks x 128 thr, each block = 32-s tile of
// one bb; 2 waves = o-halves. 8KB LDS staging [64c][32s]; proj = single K=32
// phase writing its own Ppart plane. No barriers (wave-local LDS RAW).
// ---------------------------------------------------------------------------
__global__ __launch_bounds__(128, 3) void layer_kernel(
    const unsigned int* __restrict__ vin0, const unsigned int* __restrict__ vin1,
    unsigned int* __restrict__ vout0, unsigned int* __restrict__ vout1,
    const unsigned short* __restrict__ MThi, const unsigned short* __restrict__ MTlo,
    const unsigned short* __restrict__ Ahi,  const unsigned short* __restrict__ Alo,
    const unsigned short* __restrict__ cwPhi, const unsigned short* __restrict__ cwPlo,
    const unsigned short* __restrict__ Dhi,   const unsigned short* __restrict__ Dlo,
    const float* __restrict__ cb_0, const float* __restrict__ cb_1,
    const float* __restrict__ fc0w_0, const float* __restrict__ fc0b_0,
    const float* __restrict__ fc0w_1, const float* __restrict__ fc0b_1,
    const float* __restrict__ xin,
    float* __restrict__ Ppart, int Lidx)
{
    __shared__ unsigned short Phi[2048];   // swizzled [64c][32s]
    __shared__ unsigned short Plo[2048];

    const int t = threadIdx.x;
    const int bid = blockIdx.x;
    const int br  = bid >> 11;
    const int rem = bid & 2047;
    const int b    = rem >> 5;
    const int t32  = rem & 31;
    const int s0   = t32 << 5;
    const size_t bS = (size_t)b * SLEN;
    const unsigned int* vin = br ? vin1 : vin0;
    unsigned int* vout      = br ? vout1 : vout0;
    const float* cb = br ? cb_1 : cb_0;
    const float* f0w = br ? fc0w_1 : fc0w_0;
    const float* f0b = br ? fc0b_1 : fc0b_0;
    const int bb = br * 64 + b;
    const int cwbase = (Lidx * 2 + br) * 4096;

    const int lane = t & 63;
    const int w    = t >> 6;          // 0..1: o-half
    const int qr   = lane >> 4;
    const int ln   = lane & 15;

    // ---- preload B fragments for this wave's o-half ----
    s16x8 Bh[2][2], Bl[2][2];
#pragma unroll
    for (int kk = 0; kk < 2; ++kk)
#pragma unroll
        for (int ni = 0; ni < 2; ++ni) {
            const int o = w * 32 + ni * 16 + ln;
            const int boff = cwbase + o * 64 + kk * 32 + qr * 8;
            Bh[kk][ni] = *(const s16x8*)&cwPhi[boff];
            Bl[kk][ni] = *(const s16x8*)&cwPlo[boff];
        }
    s16x8 Dhf[2], Dlf[2];
#pragma unroll
    for (int ni = 0; ni < 2; ++ni) {
        const int o = w * 32 + ni * 16 + ln;
        const int boff = bb * 2048 + o * 32 + qr * 8;
        Dhf[ni] = *(const s16x8*)&Dhi[boff];
        Dlf[ni] = *(const s16x8*)&Dlo[boff];
    }
    float cbv[2];
#pragma unroll
    for (int ni = 0; ni < 2; ++ni) cbv[ni] = cb[w * 32 + ni * 16 + ln];

    // ---- 2 m-tiles ----
#pragma unroll
    for (int mi = 0; mi < 2; ++mi) {
        const int srow = mi * 16 + ln;
        f32x4 accP[2], accS[2];
#pragma unroll
        for (int ni = 0; ni < 2; ++ni) {
            accP[ni] = (f32x4){0.f,0.f,0.f,0.f};
            accS[ni] = (f32x4){0.f,0.f,0.f,0.f};
        }

#pragma unroll
        for (int kk = 0; kk < 2; ++kk) {
            s16x8 ah, al;
            if (Lidx == 0) {
                // inline fc0: v[s][c] = x[s]*w0[c] + grid(s)*wg[c] + b[c]
                const int s = s0 + srow;
                const float xv = xin[bS + s];
                const float gv = (float)s * (1.0f / 1023.0f);
#pragma unroll
                for (int j = 0; j < 8; ++j) {
                    const int c = kk * 32 + qr * 8 + j;
                    float val = xv * f0w[c] + gv * f0w[WCH + c] + f0b[c];
                    unsigned short h = f2bf(val);
                    ah[j] = (short)h;
                    al[j] = (short)f2bf(val - bf2f(h));
                }
            } else {
                const size_t aoff = (bS + s0 + srow) * 64 + kk * 32 + qr * 8;
                uint4 va = *(const uint4*)&vin[aoff];
                uint4 vbq = *(const uint4*)&vin[aoff + 4];
                unpack_frag2(va, vbq, &ah, &al);
            }
#pragma unroll
            for (int ni = 0; ni < 2; ++ni) {
                accP[ni] = __builtin_amdgcn_mfma_f32_16x16x32_bf16(ah, Bh[kk][ni], accP[ni], 0, 0, 0);
                accS[ni] = __builtin_amdgcn_mfma_f32_16x16x32_bf16(al, Bh[kk][ni], accS[ni], 0, 0, 0);
                accS[ni] = __builtin_amdgcn_mfma_f32_16x16x32_bf16(ah, Bl[kk][ni], accS[ni], 0, 0, 0);
            }
        }
        {
            const size_t aoff = (size_t)(s0 + srow) * 32 + qr * 8;
            s16x8 mh = *(const s16x8*)&MThi[aoff];
            s16x8 ml = *(const s16x8*)&MTlo[aoff];
#pragma unroll
            for (int ni = 0; ni < 2; ++ni) {
                accP[ni] = __builtin_amdgcn_mfma_f32_16x16x32_bf16(mh, Dhf[ni], accP[ni], 0, 0, 0);
                accS[ni] = __builtin_amdgcn_mfma_f32_16x16x32_bf16(ml, Dhf[ni], accS[ni], 0, 0, 0);
                accS[ni] = __builtin_amdgcn_mfma_f32_16x16x32_bf16(mh, Dlf[ni], accS[ni], 0, 0, 0);
            }
        }
        // epilogue: gelu, split, packed global store + packed b64 LDS writes
#pragma unroll
        for (int ni = 0; ni < 2; ++ni) {
            const int o = w * 32 + ni * 16 + ln;
            f32x4 acc = accP[ni] + accS[ni];
            u16x4 hv, lv;
#pragma unroll
            for (int r = 0; r < 4; ++r) {
                const int sl32 = mi * 16 + qr * 4 + r;
                float val = gelu_f(acc[r] + cbv[ni]);
                unsigned short h = f2bf(val);
                unsigned short l = f2bf(val - bf2f(h));
                vout[(bS + s0 + sl32) * 64 + o] =
                    (unsigned int)h | ((unsigned int)l << 16);
                hv[r] = h;
                lv[r] = l;
            }
            // 4 consecutive shorts under swz32 (s>>3 const, s&7 in-stripe)
            const int a = swz32(o, mi * 16 + qr * 4);
            *(u16x4*)&Phi[a] = hv;
            *(u16x4*)&Plo[a] = lv;
        }
    }

    // ---- proj: single K=32 phase on own c-half (wave-local LDS RAW) ----
    {
        s16x8 pah[2], pal[2];
#pragma unroll
        for (int mt = 0; mt < 2; ++mt) {
            const int arow = (mt * 16 + ln) * SLEN + s0 + qr * 8;
            pah[mt] = *(const s16x8*)&Ahi[arow];
            pal[mt] = *(const s16x8*)&Alo[arow];
        }
        f32x4 pP[2][2], pS[2][2];
#pragma unroll
        for (int mt = 0; mt < 2; ++mt)
#pragma unroll
            for (int ni = 0; ni < 2; ++ni) {
                pP[mt][ni] = (f32x4){0.f,0.f,0.f,0.f};
                pS[mt][ni] = (f32x4){0.f,0.f,0.f,0.f};
            }
#pragma unroll
        for (int ni = 0; ni < 2; ++ni) {
            const int c = w * 32 + ni * 16 + ln;
            const int boff = c * 32 + ((qr ^ (c & 3)) << 3);
            s16x8 bh = *(const s16x8*)&Phi[boff];
            s16x8 bl = *(const s16x8*)&Plo[boff];
#pragma unroll
            for (int mt = 0; mt < 2; ++mt) {
                pP[mt][ni] = __builtin_amdgcn_mfma_f32_16x16x32_bf16(pah[mt], bh, pP[mt][ni], 0, 0, 0);
                pS[mt][ni] = __builtin_amdgcn_mfma_f32_16x16x32_bf16(pal[mt], bh, pS[mt][ni], 0, 0, 0);
                pS[mt][ni] = __builtin_amdgcn_mfma_f32_16x16x32_bf16(pah[mt], bl, pS[mt][ni], 0, 0, 0);
            }
        }
#pragma unroll
        for (int mt = 0; mt < 2; ++mt)
#pragma unroll
            for (int ni = 0; ni < 2; ++ni) {
                const int c = w * 32 + ni * 16 + ln;
                f32x4 pv = pP[mt][ni] + pS[mt][ni];
#pragma unroll
                for (int r = 0; r < 4; ++r) {
                    const int xr = mt * 16 + qr * 4 + r;
                    if (xr < 28)
                        Ppart[((size_t)(bb * NT2 + t32) * 28 + xr) * 64 + c] = pv[r];
                }
            }
    }
}

// ---------------------------------------------------------------------------
// Head with fused layer 3, BOTH branches: 256-thread blocks (4 waves =
// {br}x{o-half}). vin prefetch + P/S chains in both phases.
// ---------------------------------------------------------------------------
__global__ __launch_bounds__(256, 2) void head_kernel(
    const unsigned int* __restrict__ vin0, const unsigned int* __restrict__ vin1,
    const unsigned short* __restrict__ MThi, const unsigned short* __restrict__ MTlo,
    const unsigned short* __restrict__ cwPhi, const unsigned short* __restrict__ cwPlo,
    const unsigned short* __restrict__ Dhi,   const unsigned short* __restrict__ Dlo,
    const float* __restrict__ cb_0, const float* __restrict__ cb_1,
    const unsigned short* __restrict__ w1hi, const unsigned short* __restrict__ w1lo,
    const float* __restrict__ fc1b_0, const float* __restrict__ fc2w_0,
    const float* __restrict__ fc2b_0,
    const float* __restrict__ fc1b_1, const float* __restrict__ fc2w_1,
    const float* __restrict__ fc2b_1,
    float* __restrict__ out)
{
    __shared__ unsigned short Vh[8192];    // [br][swz2 plane]
    __shared__ unsigned short Vl[8192];
    __shared__ float SP[4][64];            // per-wave partials

    const int t = threadIdx.x;
    const int bid = blockIdx.x;            // 0..1023
    const int b    = bid >> 4;
    const int tile = bid & 15;
    const int s0   = tile << 6;
    const size_t bS = (size_t)b * SLEN;

    const int lane = t & 63;
    const int w    = t >> 6;          // 0..3
    const int br   = w >> 1;
    const int half = w & 1;
    const int qr   = lane >> 4;
    const int ln   = lane & 15;

    const unsigned int* vin = br ? vin1 : vin0;
    const float* cb   = (br ? cb_1 : cb_0) + 3 * WCH;
    const float* fc1b = br ? fc1b_1 : fc1b_0;
    const float* fc2w = br ? fc2w_1 : fc2w_0;
    const int bb = br * 64 + b;
    const int cwbase = (3 * 2 + br) * 4096;
    unsigned short* Vhp = Vh + br * 4096;
    unsigned short* Vlp = Vl + br * 4096;

    // ---- phase A: layer-3, own (br, 32-o half) ----
    {
        s16x8 Bh[2][2], Bl[2][2];
#pragma unroll
        for (int kk = 0; kk < 2; ++kk)
#pragma unroll
            for (int ni = 0; ni < 2; ++ni) {
                const int o = half * 32 + ni * 16 + ln;
                const int boff = cwbase + o * 64 + kk * 32 + qr * 8;
                Bh[kk][ni] = *(const s16x8*)&cwPhi[boff];
                Bl[kk][ni] = *(const s16x8*)&cwPlo[boff];
            }
        s16x8 Dhf[2], Dlf[2];
#pragma unroll
        for (int ni = 0; ni < 2; ++ni) {
            const int o = half * 32 + ni * 16 + ln;
            const int boff = bb * 2048 + o * 32 + qr * 8;
            Dhf[ni] = *(const s16x8*)&Dhi[boff];
            Dlf[ni] = *(const s16x8*)&Dlo[boff];
        }
        float cbv[2];
#pragma unroll
        for (int ni = 0; ni < 2; ++ni) cbv[ni] = cb[half * 32 + ni * 16 + ln];

        uint4 vb[2][2];
        {
            const size_t a0 = (bS + s0 + ln) * 64 + qr * 8;
            vb[0][0] = *(const uint4*)&vin[a0];
            vb[0][1] = *(const uint4*)&vin[a0 + 4];
            vb[1][0] = *(const uint4*)&vin[a0 + 32];
            vb[1][1] = *(const uint4*)&vin[a0 + 36];
        }

#pragma unroll
        for (int mi = 0; mi < 4; ++mi) {
            uint4 vn[2][2];
            if (mi < 3) {
                const size_t an = (bS + s0 + (mi + 1) * 16 + ln) * 64 + qr * 8;
                vn[0][0] = *(const uint4*)&vin[an];
                vn[0][1] = *(const uint4*)&vin[an + 4];
                vn[1][0] = *(const uint4*)&vin[an + 32];
                vn[1][1] = *(const uint4*)&vin[an + 36];
            }
            const int srow = mi * 16 + ln;
            f32x4 accP[2], accS[2];
#pragma unroll
            for (int ni = 0; ni < 2; ++ni) {
                accP[ni] = (f32x4){0.f,0.f,0.f,0.f};
                accS[ni] = (f32x4){0.f,0.f,0.f,0.f};
            }

#pragma unroll
            for (int kk = 0; kk < 2; ++kk) {
                s16x8 ah, al;
                unpack_frag2(vb[kk][0], vb[kk][1], &ah, &al);
#pragma unroll
                for (int ni = 0; ni < 2; ++ni) {
                    accP[ni] = __builtin_amdgcn_mfma_f32_16x16x32_bf16(ah, Bh[kk][ni], accP[ni], 0, 0, 0);
                    accS[ni] = __builtin_amdgcn_mfma_f32_16x16x32_bf16(al, Bh[kk][ni], accS[ni], 0, 0, 0);
                    accS[ni] = __builtin_amdgcn_mfma_f32_16x16x32_bf16(ah, Bl[kk][ni], accS[ni], 0, 0, 0);
                }
            }
            {
                const size_t aoff = (size_t)(s0 + srow) * 32 + qr * 8;
                s16x8 mh = *(const s16x8*)&MThi[aoff];
                s16x8 ml = *(const s16x8*)&MTlo[aoff];
#pragma unroll
                for (int ni = 0; ni < 2; ++ni) {
                    accP[ni] = __builtin_amdgcn_mfma_f32_16x16x32_bf16(mh, Dhf[ni], accP[ni], 0, 0, 0);
                    accS[ni] = __builtin_amdgcn_mfma_f32_16x16x32_bf16(ml, Dhf[ni], accS[ni], 0, 0, 0);
                    accS[ni] = __builtin_amdgcn_mfma_f32_16x16x32_bf16(mh, Dlf[ni], accS[ni], 0, 0, 0);
                }
            }
#pragma unroll
            for (int ni = 0; ni < 2; ++ni) {
                const int o = half * 32 + ni * 16 + ln;
                f32x4 acc = accP[ni] + accS[ni];
#pragma unroll
                for (int r = 0; r < 4; ++r) {
                    const int sl64 = mi * 16 + qr * 4 + r;
                    float val = acc[r] + cbv[ni];
                    unsigned short h = f2bf(val);
                    unsigned short l = f2bf(val - bf2f(h));
                    const int a = swz2(sl64, o);
                    Vhp[a] = h;
                    Vlp[a] = l;
                }
            }
            if (mi < 3) {
                vb[0][0] = vn[0][0]; vb[0][1] = vn[0][1];
                vb[1][0] = vn[1][0]; vb[1][1] = vn[1][1];
            }
        }
    }
    __syncthreads();

    // ---- phase B: fc1 GEMM, own (br, 64-h half) ----
    s16x8 Wh[2][4], Wl[2][4];
#pragma unroll
    for (int kk = 0; kk < 2; ++kk)
#pragma unroll
        for (int ni = 0; ni < 4; ++ni) {
            const int h = half * 64 + ni * 16 + ln;
            const int boff = br * 8192 + h * 64 + kk * 32 + qr * 8;
            Wh[kk][ni] = *(const s16x8*)&w1hi[boff];
            Wl[kk][ni] = *(const s16x8*)&w1lo[boff];
        }
    float b1v[4], w2v[4];
#pragma unroll
    for (int ni = 0; ni < 4; ++ni) {
        b1v[ni] = fc1b[half * 64 + ni * 16 + ln];
        w2v[ni] = fc2w[half * 64 + ni * 16 + ln];
    }

#pragma unroll
    for (int mi = 0; mi < 4; ++mi) {
        f32x4 a1P[4], a1S[4];
#pragma unroll
        for (int ni = 0; ni < 4; ++ni) {
            a1P[ni] = (f32x4){0.f,0.f,0.f,0.f};
            a1S[ni] = (f32x4){0.f,0.f,0.f,0.f};
        }

#pragma unroll
        for (int kk = 0; kk < 2; ++kk) {
            const int blk = kk * 4 + qr;
            const int sl  = mi * 16 + ln;
            const int a   = sl * 64 + ((blk ^ (sl & 7)) << 3);
            s16x8 ah = *(const s16x8*)&Vhp[a];
            s16x8 al = *(const s16x8*)&Vlp[a];
#pragma unroll
            for (int ni = 0; ni < 4; ++ni) {
                a1P[ni] = __builtin_amdgcn_mfma_f32_16x16x32_bf16(ah, Wh[kk][ni], a1P[ni], 0, 0, 0);
                a1S[ni] = __builtin_amdgcn_mfma_f32_16x16x32_bf16(al, Wh[kk][ni], a1S[ni], 0, 0, 0);
                a1S[ni] = __builtin_amdgcn_mfma_f32_16x16x32_bf16(ah, Wl[kk][ni], a1S[ni], 0, 0, 0);
            }
        }
        float partial[4] = {0.f, 0.f, 0.f, 0.f};
#pragma unroll
        for (int ni = 0; ni < 4; ++ni) {
            f32x4 acc1 = a1P[ni] + a1S[ni];
#pragma unroll
            for (int r = 0; r < 4; ++r)
                partial[r] += gelu_f(acc1[r] + b1v[ni]) * w2v[ni];
        }
#pragma unroll
        for (int r = 0; r < 4; ++r) {
            partial[r] += __shfl_xor(partial[r], 1, 64);
            partial[r] += __shfl_xor(partial[r], 2, 64);
            partial[r] += __shfl_xor(partial[r], 4, 64);
            partial[r] += __shfl_xor(partial[r], 8, 64);
        }
        if (ln == 0) {
#pragma unroll
            for (int r = 0; r < 4; ++r)
                SP[w][mi * 16 + qr * 4 + r] = partial[r];
        }
    }
    __syncthreads();

    if (t < 64) {
        const float bias = fc2b_0[0] + fc2b_1[0];
        out[bS + s0 + t] = SP[0][t] + SP[1][t] + SP[2][t] + SP[3][t] + bias;
    }
}

// ---------------------------------------------------------------------------
extern "C" void kernel_launch(void* const* d_in, const int* in_sizes, int n_in,
                              void* d_out, int out_size, void* d_ws, size_t ws_size,
                              hipStream_t stream)
{
    const float* x = (const float*)d_in[0];
    const float* P[2][10];
    for (int br = 0; br < 2; ++br)
        for (int k = 0; k < 10; ++k)
            P[br][k] = (const float*)d_in[1 + br * 10 + k];
    // order: fc0_w, fc0_b, wave_w1, wave_w2, cw, cb, fc1_w, fc1_b, fc2_w, fc2_b

    char* p = (char*)d_ws;
    const size_t PL = (size_t)BC * SLEN * 4;   // one packed u32 plane: 16.78 MB
    unsigned int* vplane[4];                   // [br][pingpong]
    for (int i = 0; i < 4; ++i) { vplane[i] = (unsigned int*)p; p += PL; }
    unsigned short* Ahi  = (unsigned short*)p; p += 32 * SLEN * 2;
    unsigned short* Alo  = (unsigned short*)p; p += 32 * SLEN * 2;
    unsigned short* MThi = (unsigned short*)p; p += SLEN * 32 * 2;
    unsigned short* MTlo = (unsigned short*)p; p += SLEN * 32 * 2;
    float* Ppart = (float*)p;                  p += (size_t)128 * NT2 * 28 * 64 * 4;
    unsigned short* cwPhi = (unsigned short*)p; p += 8 * 4096 * 2;   // [L][br]
    unsigned short* cwPlo = (unsigned short*)p; p += 8 * 4096 * 2;
    unsigned short* Dhi   = (unsigned short*)p; p += (size_t)128 * 2048 * 2;
    unsigned short* Dlo   = (unsigned short*)p; p += (size_t)128 * 2048 * 2;
    unsigned short* w1hi  = (unsigned short*)p; p += 2 * 8192 * 2;
    unsigned short* w1lo  = (unsigned short*)p; p += 2 * 8192 * 2;
    float* axbuf          = (float*)p;          p += 66 * 28 * 4;
    float* WsT            = (float*)p;          p += (size_t)4 * 2 * 28 * 4096 * 4;

    unsigned int *v0a = vplane[0], *v0b = vplane[1];
    unsigned int *v1a = vplane[2], *v1b = vplane[3];

    setup_kernel<<<1142, 256, 0, stream>>>(
        x, Ahi, Alo, MThi, MTlo, axbuf,
        P[0][6], P[1][6], P[0][4], P[1][4],
        P[0][2], P[0][3], P[1][2], P[1][3],
        w1hi, w1lo, cwPhi, cwPlo, Dhi, Dlo, WsT);

    mix0_kernel<<<448, 256, 0, stream>>>(
        axbuf, P[0][0], P[0][1], P[1][0], P[1][1],
        WsT, Dhi, Dlo);

    for (int i = 0; i < 3; ++i) {
        layer_kernel<<<4096, 128, 0, stream>>>(
            v0a, v1a, v0b, v1b,
            MThi, MTlo, Ahi, Alo, cwPhi, cwPlo, Dhi, Dlo,
            P[0][5] + (size_t)i * WCH, P[1][5] + (size_t)i * WCH,
            P[0][0], P[0][1], P[1][0], P[1][1], x,
            Ppart, i);
        unsigned int* tmp;
        tmp = v0a; v0a = v0b; v0b = tmp;
        tmp = v1a; v1a = v1b; v1b = tmp;

        mix_kernel<<<448, 256, 0, stream>>>(
            Ppart,
            WsT + (size_t)(i + 1) * 2 * 28 * 4096,
            Dhi, Dlo);
    }

    head_kernel<<<1024, 256, 0, stream>>>(
        v0a, v1a,
        MThi, MTlo, cwPhi, cwPlo, Dhi, Dlo,
        P[0][5] + (size_t)3 * WCH, P[1][5] + (size_t)3 * WCH,
        w1hi, w1lo,
        P[0][7], P[0][8], P[0][9],
        P[1][7], P[1][8], P[1][9],
        (float*)d_out);
}

// Round 7
// 262.682 us; speedup vs baseline: 3.5897x; 1.0159x over previous
//
#include <hip/hip_runtime.h>
#include <hip/hip_bf16.h>
#include <math.h>

// ---------------------------------------------------------------------------
// WNO1d. Round 26: revert R6 layer fine-split (regressed: 2x A-frag re-reads
// + 2x Ppart planes). Layers/mix/Ppart back to R4 shape (252us config).
// Head fine-split instead (R6 counters: head 52us, 26% occupancy, 4 blk/CU
// all-resident => duration = single-block critical path): 1024x256/64-s ->
// 2048x256/32-s blocks, LDS 33.8 -> 16.9 KB, mi 4->2 both phases, 8 blk/CU,
// block owns both branches for its 32 s-rows => plain store, no atomics.
// ---------------------------------------------------------------------------

#define BDIM 64
#define SLEN 1024
#define WCH  64
#define BC   (BDIM*WCH)
#define NT   16         // 64-s proj tiles per batch

typedef short s16x8 __attribute__((ext_vector_type(8)));
typedef float f32x4 __attribute__((ext_vector_type(4)));
typedef unsigned short u16x4 __attribute__((ext_vector_type(4)));

constexpr float RLv[12] = {
    0.11154074335008017f, 0.4946238903983854f, 0.7511339080215775f,
    0.3152503517092432f, -0.22626469396516913f, -0.12976686756709563f,
    0.09750160558707936f, 0.02752286553001629f, -0.031582039318031156f,
    0.0005538422009938016f, 0.004777257511010651f, -0.00107730108499558f };
constexpr float AHv[12] = {
     RLv[11], -RLv[10],  RLv[9], -RLv[8],  RLv[7], -RLv[6],
     RLv[5],  -RLv[4],   RLv[3], -RLv[2],  RLv[1], -RLv[0] };
constexpr float SLv[12] = {
     RLv[11], RLv[10], RLv[9], RLv[8], RLv[7], RLv[6],
     RLv[5],  RLv[4],  RLv[3], RLv[2], RLv[1], RLv[0] };
constexpr float SHv[12] = {
    -RLv[0],  RLv[1], -RLv[2],  RLv[3], -RLv[4],  RLv[5],
    -RLv[6],  RLv[7], -RLv[8],  RLv[9], -RLv[10], RLv[11] };

__device__ __forceinline__ float gelu_f(float x) {
    float z = 0.7978845608f * (x + 0.044715f * x * x * x);
    return x / (1.0f + __expf(-2.0f * z));
}
__device__ __forceinline__ unsigned short f2bf(float f) {
    __hip_bfloat16 h = __float2bfloat16(f);
    union { __hip_bfloat16 h; unsigned short u; } cv; cv.h = h; return cv.u;
}
__device__ __forceinline__ float bf2f(unsigned short u) {
    union { unsigned short u; __hip_bfloat16 h; } cv; cv.u = u;
    return __bfloat162float(cv.h);
}
// unpack 8 packed u32 (as two uint4) -> hi frag + lo frag (8 v_perm)
__device__ __forceinline__ void unpack_frag2(uint4 a, uint4 b,
                                             s16x8* ah, s16x8* al) {
    union { s16x8 v; unsigned int d[4]; } H, L;
    H.d[0] = __builtin_amdgcn_perm(a.y, a.x, 0x05040100u);
    H.d[1] = __builtin_amdgcn_perm(a.w, a.z, 0x05040100u);
    H.d[2] = __builtin_amdgcn_perm(b.y, b.x, 0x05040100u);
    H.d[3] = __builtin_amdgcn_perm(b.w, b.z, 0x05040100u);
    L.d[0] = __builtin_amdgcn_perm(a.y, a.x, 0x07060302u);
    L.d[1] = __builtin_amdgcn_perm(a.w, a.z, 0x07060302u);
    L.d[2] = __builtin_amdgcn_perm(b.y, b.x, 0x07060302u);
    L.d[3] = __builtin_amdgcn_perm(b.w, b.z, 0x07060302u);
    *ah = H.v; *al = L.v;
}

// swizzled [c][s] plane (64x64 shorts)
__device__ __forceinline__ int swz(int c, int s) {
    return c * 64 + ((((s >> 3) ^ (c & 7)) << 3) | (s & 7));
}
// swizzled [s][c] plane
__device__ __forceinline__ int swz2(int s, int c) {
    return s * 64 + ((((c >> 3) ^ (s & 7)) << 3) | (c & 7));
}

// 2-wave proj: A[28 x 64-s-tile] x P[64c x 64s] -> Ppart. Wave w owns c-half.
__device__ __forceinline__ void proj2(
    const unsigned short* Phi, const unsigned short* Plo,
    const unsigned short* __restrict__ Ahi, const unsigned short* __restrict__ Alo,
    float* __restrict__ Ppart, int bb, int tile, int s0, int t)
{
    const int lane = t & 63;
    const int w    = t >> 6;
    const int qr   = lane >> 4;
    const int ln   = lane & 15;

    s16x8 pah[2][2], pal[2][2];      // [kk][mt]
#pragma unroll
    for (int kk = 0; kk < 2; ++kk)
#pragma unroll
        for (int mt = 0; mt < 2; ++mt) {
            const int arow = (mt * 16 + ln) * SLEN + s0 + kk * 32 + qr * 8;
            pah[kk][mt] = *(const s16x8*)&Ahi[arow];
            pal[kk][mt] = *(const s16x8*)&Alo[arow];
        }

    f32x4 pP[2][2], pS[2][2];
#pragma unroll
    for (int mt = 0; mt < 2; ++mt)
#pragma unroll
        for (int ni = 0; ni < 2; ++ni) {
            pP[mt][ni] = (f32x4){0.f,0.f,0.f,0.f};
            pS[mt][ni] = (f32x4){0.f,0.f,0.f,0.f};
        }

#pragma unroll
    for (int kk = 0; kk < 2; ++kk) {
        const int bk = kk * 4 + qr;
#pragma unroll
        for (int ni = 0; ni < 2; ++ni) {
            const int c = w * 32 + ni * 16 + ln;
            const int boff = c * 64 + ((bk ^ (c & 7)) << 3);
            s16x8 bh = *(const s16x8*)&Phi[boff];
            s16x8 bl = *(const s16x8*)&Plo[boff];
#pragma unroll
            for (int mt = 0; mt < 2; ++mt) {
                pP[mt][ni] = __builtin_amdgcn_mfma_f32_16x16x32_bf16(pah[kk][mt], bh, pP[mt][ni], 0, 0, 0);
                pS[mt][ni] = __builtin_amdgcn_mfma_f32_16x16x32_bf16(pal[kk][mt], bh, pS[mt][ni], 0, 0, 0);
                pS[mt][ni] = __builtin_amdgcn_mfma_f32_16x16x32_bf16(pah[kk][mt], bl, pS[mt][ni], 0, 0, 0);
            }
        }
    }
#pragma unroll
    for (int mt = 0; mt < 2; ++mt)
#pragma unroll
        for (int ni = 0; ni < 2; ++ni) {
            const int c = w * 32 + ni * 16 + ln;
            f32x4 pv = pP[mt][ni] + pS[mt][ni];
#pragma unroll
            for (int r = 0; r < 4; ++r) {
                const int xr = mt * 16 + qr * 4 + r;
                if (xr < 28)
                    Ppart[((size_t)(bb * NT + tile) * 28 + xr) * 64 + c] = pv[r];
            }
        }
}

// ---------------------------------------------------------------------------
// setup: 0..1023 A columns; 1024..1051 M rows; 1052..1117 data cascade;
//        1118..1125 weight prep; 1126..1141 WsT transpose.
// ---------------------------------------------------------------------------
__global__ __launch_bounds__(256) void setup_kernel(
    const float* __restrict__ x,
    unsigned short* __restrict__ Ahi, unsigned short* __restrict__ Alo,
    unsigned short* __restrict__ MThi, unsigned short* __restrict__ MTlo,
    float* __restrict__ axbuf,
    const float* __restrict__ fc1w_0, const float* __restrict__ fc1w_1,
    const float* __restrict__ cw_0, const float* __restrict__ cw_1,
    const float* __restrict__ w1_0, const float* __restrict__ w2_0,
    const float* __restrict__ w1_1, const float* __restrict__ w2_1,
    unsigned short* __restrict__ w1hi, unsigned short* __restrict__ w1lo,
    unsigned short* __restrict__ cwPhi, unsigned short* __restrict__ cwPlo,
    unsigned short* __restrict__ Dhi,  unsigned short* __restrict__ Dlo,
    float* __restrict__ WsT)
{
    __shared__ float Af[1024];
    __shared__ float Bff[520];
    __shared__ float hib[14];
    const int t = threadIdx.x;

    if (blockIdx.x < 1024 || (blockIdx.x >= 1052 && blockIdx.x < 1118)) {
        const bool isA = (blockIdx.x < 1024);
        const int s0 = blockIdx.x;
        const int di = blockIdx.x - 1052;
        for (int i = t; i < SLEN; i += 256) {
            float v;
            if (isA)           v = (i == s0) ? 1.0f : 0.0f;
            else if (di < 64)  v = x[di * SLEN + i];
            else if (di == 64) v = (float)i * (1.0f / 1023.0f);
            else               v = 1.0f;
            Af[i] = v;
        }
        __syncthreads();

        const int NIN[8]  = {1024, 517, 264, 137, 74, 42, 26, 18};
        const int NOUT[8] = { 517, 264, 137,  74, 42, 26, 18, 14};
#pragma unroll
        for (int lev = 0; lev < 8; ++lev) {
            float* in  = (lev & 1) ? Bff : Af;
            float* out = (lev & 1) ? Af : Bff;
            const int nin = NIN[lev], nout = NOUT[lev];
            for (int m = t; m < nout; m += 256) {
                float alo = 0.f, ahi = 0.f;
#pragma unroll
                for (int tt = 0; tt < 12; ++tt) {
                    int jj = 2 * m + tt - 10;
                    if (jj < 0)         jj = -1 - jj;
                    else if (jj >= nin) jj = 2 * nin - 1 - jj;
                    float xv = in[jj];
                    alo += xv * RLv[tt];
                    if (lev == 7) ahi += xv * AHv[tt];
                }
                out[m] = alo;
                if (lev == 7) {
                    if (isA) {
                        unsigned short h1 = f2bf(alo);
                        Ahi[m * SLEN + s0] = h1;
                        Alo[m * SLEN + s0] = f2bf(alo - bf2f(h1));
                        unsigned short h2 = f2bf(ahi);
                        Ahi[(14 + m) * SLEN + s0] = h2;
                        Alo[(14 + m) * SLEN + s0] = f2bf(ahi - bf2f(h2));
                    } else {
                        axbuf[di * 28 + m]      = alo;
                        axbuf[di * 28 + 14 + m] = ahi;
                    }
                }
            }
            __syncthreads();
        }
        if (isA && t < 4) {
            Ahi[(28 + t) * SLEN + s0] = 0; Alo[(28 + t) * SLEN + s0] = 0;
            MThi[s0 * 32 + 28 + t] = 0;    MTlo[s0 * 32 + 28 + t] = 0;
        }
        return;
    }

    if (blockIdx.x >= 1126) {
        // WsT: [(L*2+br)*28 + x][i*64+o]
        const int wsb = blockIdx.x - 1126;       // 0..15
        const int L = wsb >> 2, br = (wsb >> 1) & 1, which = wsb & 1;
        const float* src = (which ? (br ? w2_1 : w2_0) : (br ? w1_1 : w1_0))
                         + (size_t)L * 64 * 64 * 14;
        const size_t dbase = ((size_t)(L * 2 + br) * 28 + which * 14) * 4096;
        for (int e = t; e < 4096; e += 256) {
            const float* sp = src + (size_t)e * 14;
            float v[14];
#pragma unroll
            for (int xi = 0; xi < 14; ++xi) v[xi] = sp[xi];
#pragma unroll
            for (int xi = 0; xi < 14; ++xi)
                WsT[dbase + (size_t)xi * 4096 + e] = v[xi];
        }
        return;
    }

    if (blockIdx.x >= 1118) {
        // weight prep
        const int gid = (blockIdx.x - 1118) * 256 + t;
        for (int idx = gid; idx < 16384; idx += 2048) {
            int br = idx >> 13, r = idx & 8191;
            int h = r >> 6, c = r & 63;
            float f = (br ? fc1w_1 : fc1w_0)[c * 128 + h];
            unsigned short hh = f2bf(f);
            w1hi[idx] = hh;
            w1lo[idx] = f2bf(f - bf2f(hh));
        }
        for (int idx = gid; idx < 32768; idx += 2048) {   // cwT split, all layers
            int L = idx >> 13, br = (idx >> 12) & 1, e = idx & 4095;
            int k = e >> 6, o = e & 63;
            float val = (br ? cw_1 : cw_0)[(size_t)L * 4096 + o * 64 + k]
                      + ((k == o) ? 1.0f : 0.0f);
            unsigned short h = f2bf(val);
            const int off = (L * 2 + br) * 4096 + o * 64 + k;
            cwPhi[off] = h;
            cwPlo[off] = f2bf(val - bf2f(h));
        }
        for (int idx = gid; idx < 32768; idx += 2048) {   // D pad rows 28..31
            int bb = idx >> 8, o = (idx >> 2) & 63, j = idx & 3;
            Dhi[bb * 2048 + o * 32 + 28 + j] = 0;
            Dlo[bb * 2048 + o * 32 + 28 + j] = 0;
        }
        return;
    }

    // synthesis rows (M^T)
    const int u = blockIdx.x - 1024;     // 0..27
    if (t < 14) {
        Af[t]  = (u < 14 && t == u) ? 1.0f : 0.0f;
        hib[t] = (u >= 14 && t == (u - 14)) ? 1.0f : 0.0f;
    }
    __syncthreads();

    const int NH[8] = {14, 18, 26, 42, 74, 137, 264, 517};
    const int NO[8] = {18, 26, 42, 74, 138, 264, 518, 1024};

#pragma unroll
    for (int s = 0; s < 8; ++s) {
        const float* lo = (s & 1) ? Bff : Af;
        float* out      = (s & 1) ? Af : Bff;
        const int N = NH[s], nout = NO[s];
        for (int m = t; m < nout; m += 256) {
            float acc = 0.f;
#pragma unroll
            for (int tt = 0; tt < 12; ++tt) {
                int uu = m + tt - 1;
                if ((uu & 1) == 0) {
                    int q = uu >> 1;
                    if (q < N) {
                        acc += lo[q] * SLv[tt];
                        if (s == 0) acc += hib[q] * SHv[tt];
                    }
                }
            }
            out[m] = acc;
        }
        __syncthreads();
    }
    for (int m = t; m < SLEN; m += 256) {
        float f = Af[m];
        unsigned short h = f2bf(f);
        MThi[m * 32 + u] = h;
        MTlo[m * 32 + u] = f2bf(f - bf2f(h));
    }
}

// ---------------------------------------------------------------------------
// mix0: layer-0 mix from rank-3 formula. WsT0 = contiguous weight set 0.
// ---------------------------------------------------------------------------
__global__ __launch_bounds__(256) void mix0_kernel(
    const float* __restrict__ axbuf,
    const float* __restrict__ fc0w_0, const float* __restrict__ fc0b_0,
    const float* __restrict__ fc0w_1, const float* __restrict__ fc0b_1,
    const float* __restrict__ WsT0,
    unsigned short* __restrict__ Dhi, unsigned short* __restrict__ Dlo)
{
    const int t = threadIdx.x;
    const int br  = blockIdx.x / 224;
    const int sub = blockIdx.x % 224;

    __shared__ float Ws[64][65];
    __shared__ float LO[8][64];
    const int o = t & 63;
    const int w = t >> 6;
    const int x  = sub >> 3;
    const int b0 = (sub & 7) << 3;

    const float* wsrc = WsT0 + ((size_t)(br * 28 + x)) * 4096;
    for (int idx = t; idx < 4096; idx += 256)
        Ws[idx >> 6][idx & 63] = wsrc[idx];

    const float* fc0w = br ? fc0w_1 : fc0w_0;
    const float* fc0b = br ? fc0b_1 : fc0b_0;
    const float agv = axbuf[64 * 28 + x];
    const float a1v = axbuf[65 * 28 + x];
    const float w0o = fc0w[o];
    const float wgo = fc0w[WCH + o];
    const float b0o = fc0b[o];

#pragma unroll
    for (int j = 0; j < 2; ++j) {
        int bi = w + 4 * j;
        int b  = b0 + bi;
        float axv = axbuf[b * 28 + x];
        LO[bi][o] = axv * w0o + agv * wgo + a1v * b0o;
    }
    __syncthreads();

#pragma unroll
    for (int j = 0; j < 2; ++j) {
        int bi = w + 4 * j;
        int bb = br * 64 + b0 + bi;
        float acc = 0.f;
        for (int i = 0; i < 64; ++i)
            acc += LO[bi][i] * Ws[i][o];
        acc -= LO[bi][o];
        unsigned short h = f2bf(acc);
        Dhi[bb * 2048 + o * 32 + x] = h;
        Dlo[bb * 2048 + o * 32 + x] = f2bf(acc - bf2f(h));
    }
}

// ---------------------------------------------------------------------------
// Mix (layers 1..3): reads Ppart; WsTL = contiguous weight set for this layer.
// ---------------------------------------------------------------------------
__global__ __launch_bounds__(256) void mix_kernel(
    const float* __restrict__ Ppart,
    const float* __restrict__ WsTL,
    unsigned short* __restrict__ Dhi, unsigned short* __restrict__ Dlo)
{
    const int t = threadIdx.x;
    const int br  = blockIdx.x / 224;
    const int sub = blockIdx.x % 224;

    __shared__ float Ws[64][65];
    __shared__ float LO[8][64];
    const int o = t & 63;
    const int w = t >> 6;
    const int x  = sub >> 3;
    const int b0 = (sub & 7) << 3;

    const float* wsrc = WsTL + ((size_t)(br * 28 + x)) * 4096;
    for (int idx = t; idx < 4096; idx += 256)
        Ws[idx >> 6][idx & 63] = wsrc[idx];

#pragma unroll
    for (int j = 0; j < 2; ++j) {
        int bi = w + 4 * j;
        int bb = br * 64 + b0 + bi;
        float s = 0.f;
        for (int tile = 0; tile < NT; ++tile)
            s += Ppart[((size_t)(bb * NT + tile) * 28 + x) * 64 + o];
        LO[bi][o] = s;
    }
    __syncthreads();

#pragma unroll
    for (int j = 0; j < 2; ++j) {
        int bi = w + 4 * j;
        int bb = br * 64 + b0 + bi;
        float acc = 0.f;
        for (int i = 0; i < 64; ++i)
            acc += LO[bi][i] * Ws[i][o];
        acc -= LO[bi][o];
        unsigned short h = f2bf(acc);
        Dhi[bb * 2048 + o * 32 + x] = h;
        Dlo[bb * 2048 + o * 32 + x] = f2bf(acc - bf2f(h));
    }
}

// ---------------------------------------------------------------------------
// Fused layer (i = 0,1,2): 2048 blocks x 128 thr, 2 waves per 64-s tile.
// vin double-buffer prefetch; P/S split accumulator chains; no barriers.
// ---------------------------------------------------------------------------
__global__ __launch_bounds__(128, 3) void layer_kernel(
    const unsigned int* __restrict__ vin0, const unsigned int* __restrict__ vin1,
    unsigned int* __restrict__ vout0, unsigned int* __restrict__ vout1,
    const unsigned short* __restrict__ MThi, const unsigned short* __restrict__ MTlo,
    const unsigned short* __restrict__ Ahi,  const unsigned short* __restrict__ Alo,
    const unsigned short* __restrict__ cwPhi, const unsigned short* __restrict__ cwPlo,
    const unsigned short* __restrict__ Dhi,   const unsigned short* __restrict__ Dlo,
    const float* __restrict__ cb_0, const float* __restrict__ cb_1,
    const float* __restrict__ fc0w_0, const float* __restrict__ fc0b_0,
    const float* __restrict__ fc0w_1, const float* __restrict__ fc0b_1,
    const float* __restrict__ xin,
    float* __restrict__ Ppart, int Lidx)
{
    __shared__ unsigned short Phi[4096];   // block-shared swizzled [c][s64]
    __shared__ unsigned short Plo[4096];

    const int t = threadIdx.x;
    const int bid = blockIdx.x;
    const int br  = bid >> 10;
    const int rem = bid & 1023;
    const int b    = rem >> 4;
    const int tile = rem & 15;
    const int s0   = tile << 6;
    const size_t bS = (size_t)b * SLEN;
    const unsigned int* vin = br ? vin1 : vin0;
    unsigned int* vout      = br ? vout1 : vout0;
    const float* cb = br ? cb_1 : cb_0;
    const float* f0w = br ? fc0w_1 : fc0w_0;
    const float* f0b = br ? fc0b_1 : fc0b_0;
    const int bb = br * 64 + b;
    const int cwbase = (Lidx * 2 + br) * 4096;

    const int lane = t & 63;
    const int w    = t >> 6;          // 0..1: o-half
    const int qr   = lane >> 4;
    const int ln   = lane & 15;

    // ---- preload B fragments for this wave's o-half ----
    s16x8 Bh[2][2], Bl[2][2];
#pragma unroll
    for (int kk = 0; kk < 2; ++kk)
#pragma unroll
        for (int ni = 0; ni < 2; ++ni) {
            const int o = w * 32 + ni * 16 + ln;
            const int boff = cwbase + o * 64 + kk * 32 + qr * 8;
            Bh[kk][ni] = *(const s16x8*)&cwPhi[boff];
            Bl[kk][ni] = *(const s16x8*)&cwPlo[boff];
        }
    s16x8 Dhf[2], Dlf[2];
#pragma unroll
    for (int ni = 0; ni < 2; ++ni) {
        const int o = w * 32 + ni * 16 + ln;
        const int boff = bb * 2048 + o * 32 + qr * 8;
        Dhf[ni] = *(const s16x8*)&Dhi[boff];
        Dlf[ni] = *(const s16x8*)&Dlo[boff];
    }
    float cbv[2];
#pragma unroll
    for (int ni = 0; ni < 2; ++ni) cbv[ni] = cb[w * 32 + ni * 16 + ln];

    // ---- prefetch vin (or x) for mi=0 ----
    uint4 vb[2][2];                 // [kk][half]
    float xpf = 0.f;
    if (Lidx == 0) {
        xpf = xin[bS + s0 + ln];
    } else {
        const size_t a0 = (bS + s0 + ln) * 64 + qr * 8;
        vb[0][0] = *(const uint4*)&vin[a0];
        vb[0][1] = *(const uint4*)&vin[a0 + 4];
        vb[1][0] = *(const uint4*)&vin[a0 + 32];
        vb[1][1] = *(const uint4*)&vin[a0 + 36];
    }

    // ---- 4 m-tiles ----
#pragma unroll
    for (int mi = 0; mi < 4; ++mi) {
        const int srow = mi * 16 + ln;
        uint4 vn[2][2];
        float xnf = 0.f;
        if (mi < 3) {
            if (Lidx == 0) {
                xnf = xin[bS + s0 + (mi + 1) * 16 + ln];
            } else {
                const size_t an = (bS + s0 + (mi + 1) * 16 + ln) * 64 + qr * 8;
                vn[0][0] = *(const uint4*)&vin[an];
                vn[0][1] = *(const uint4*)&vin[an + 4];
                vn[1][0] = *(const uint4*)&vin[an + 32];
                vn[1][1] = *(const uint4*)&vin[an + 36];
            }
        }

        f32x4 accP[2], accS[2];
#pragma unroll
        for (int ni = 0; ni < 2; ++ni) {
            accP[ni] = (f32x4){0.f,0.f,0.f,0.f};
            accS[ni] = (f32x4){0.f,0.f,0.f,0.f};
        }

#pragma unroll
        for (int kk = 0; kk < 2; ++kk) {
            s16x8 ah, al;
            if (Lidx == 0) {
                const int s = s0 + srow;
                const float gv = (float)s * (1.0f / 1023.0f);
#pragma unroll
                for (int j = 0; j < 8; ++j) {
                    const int c = kk * 32 + qr * 8 + j;
                    float val = xpf * f0w[c] + gv * f0w[WCH + c] + f0b[c];
                    unsigned short h = f2bf(val);
                    ah[j] = (short)h;
                    al[j] = (short)f2bf(val - bf2f(h));
                }
            } else {
                unpack_frag2(vb[kk][0], vb[kk][1], &ah, &al);
            }
#pragma unroll
            for (int ni = 0; ni < 2; ++ni) {
                accP[ni] = __builtin_amdgcn_mfma_f32_16x16x32_bf16(ah, Bh[kk][ni], accP[ni], 0, 0, 0);
                accS[ni] = __builtin_amdgcn_mfma_f32_16x16x32_bf16(al, Bh[kk][ni], accS[ni], 0, 0, 0);
                accS[ni] = __builtin_amdgcn_mfma_f32_16x16x32_bf16(ah, Bl[kk][ni], accS[ni], 0, 0, 0);
            }
        }
        {
            const size_t aoff = (size_t)(s0 + srow) * 32 + qr * 8;
            s16x8 mh = *(const s16x8*)&MThi[aoff];
            s16x8 ml = *(const s16x8*)&MTlo[aoff];
#pragma unroll
            for (int ni = 0; ni < 2; ++ni) {
                accP[ni] = __builtin_amdgcn_mfma_f32_16x16x32_bf16(mh, Dhf[ni], accP[ni], 0, 0, 0);
                accS[ni] = __builtin_amdgcn_mfma_f32_16x16x32_bf16(ml, Dhf[ni], accS[ni], 0, 0, 0);
                accS[ni] = __builtin_amdgcn_mfma_f32_16x16x32_bf16(mh, Dlf[ni], accS[ni], 0, 0, 0);
            }
        }
        // epilogue: gelu, split, packed global store + packed b64 LDS writes
#pragma unroll
        for (int ni = 0; ni < 2; ++ni) {
            const int o = w * 32 + ni * 16 + ln;
            f32x4 acc = accP[ni] + accS[ni];
            u16x4 hv, lv;
#pragma unroll
            for (int r = 0; r < 4; ++r) {
                const int sl64 = mi * 16 + qr * 4 + r;
                float val = gelu_f(acc[r] + cbv[ni]);
                unsigned short h = f2bf(val);
                unsigned short l = f2bf(val - bf2f(h));
                vout[(bS + s0 + sl64) * 64 + o] =
                    (unsigned int)h | ((unsigned int)l << 16);
                hv[r] = h;
                lv[r] = l;
            }
            const int a = swz(o, mi * 16 + qr * 4);
            *(u16x4*)&Phi[a] = hv;
            *(u16x4*)&Plo[a] = lv;
        }
        if (mi < 3) {
            if (Lidx == 0) {
                xpf = xnf;
            } else {
                vb[0][0] = vn[0][0]; vb[0][1] = vn[0][1];
                vb[1][0] = vn[1][0]; vb[1][1] = vn[1][1];
            }
        }
    }

    // ---- proj on own c-half (same-wave LDS RAW: no barrier needed) ----
    proj2(Phi, Plo, Ahi, Alo, Ppart, bb, tile, s0, t);
}

// ---------------------------------------------------------------------------
// Head with fused layer 3, BOTH branches, 32-s blocks: 2048 blocks x 256 thr
// (4 waves = {br}x{o-half}); LDS 16.9KB -> 8 blk/CU, 32 waves/CU. Block owns
// both branches for its 32 s-rows => plain store, no atomics.
// ---------------------------------------------------------------------------
__global__ __launch_bounds__(256, 2) void head_kernel(
    const unsigned int* __restrict__ vin0, const unsigned int* __restrict__ vin1,
    const unsigned short* __restrict__ MThi, const unsigned short* __restrict__ MTlo,
    const unsigned short* __restrict__ cwPhi, const unsigned short* __restrict__ cwPlo,
    const unsigned short* __restrict__ Dhi,   const unsigned short* __restrict__ Dlo,
    const float* __restrict__ cb_0, const float* __restrict__ cb_1,
    const unsigned short* __restrict__ w1hi, const unsigned short* __restrict__ w1lo,
    const float* __restrict__ fc1b_0, const float* __restrict__ fc2w_0,
    const float* __restrict__ fc2b_0,
    const float* __restrict__ fc1b_1, const float* __restrict__ fc2w_1,
    const float* __restrict__ fc2b_1,
    float* __restrict__ out)
{
    __shared__ unsigned short Vh[4096];    // [br][swz2 32x64 plane]
    __shared__ unsigned short Vl[4096];
    __shared__ float SP[4][32];            // per-wave partials

    const int t = threadIdx.x;
    const int bid = blockIdx.x;            // 0..2047
    const int b    = bid >> 5;
    const int t32  = bid & 31;
    const int s0   = t32 << 5;
    const size_t bS = (size_t)b * SLEN;

    const int lane = t & 63;
    const int w    = t >> 6;          // 0..3
    const int br   = w >> 1;
    const int half = w & 1;
    const int qr   = lane >> 4;
    const int ln   = lane & 15;

    const unsigned int* vin = br ? vin1 : vin0;
    const float* cb   = (br ? cb_1 : cb_0) + 3 * WCH;
    const float* fc1b = br ? fc1b_1 : fc1b_0;
    const float* fc2w = br ? fc2w_1 : fc2w_0;
    const int bb = br * 64 + b;
    const int cwbase = (3 * 2 + br) * 4096;
    unsigned short* Vhp = Vh + br * 2048;
    unsigned short* Vlp = Vl + br * 2048;

    // ---- phase A: layer-3, own (br, 32-o half), 32 s-rows ----
    {
        s16x8 Bh[2][2], Bl[2][2];
#pragma unroll
        for (int kk = 0; kk < 2; ++kk)
#pragma unroll
            for (int ni = 0; ni < 2; ++ni) {
                const int o = half * 32 + ni * 16 + ln;
                const int boff = cwbase + o * 64 + kk * 32 + qr * 8;
                Bh[kk][ni] = *(const s16x8*)&cwPhi[boff];
                Bl[kk][ni] = *(const s16x8*)&cwPlo[boff];
            }
        s16x8 Dhf[2], Dlf[2];
#pragma unroll
        for (int ni = 0; ni < 2; ++ni) {
            const int o = half * 32 + ni * 16 + ln;
            const int boff = bb * 2048 + o * 32 + qr * 8;
            Dhf[ni] = *(const s16x8*)&Dhi[boff];
            Dlf[ni] = *(const s16x8*)&Dlo[boff];
        }
        float cbv[2];
#pragma unroll
        for (int ni = 0; ni < 2; ++ni) cbv[ni] = cb[half * 32 + ni * 16 + ln];

        uint4 vb[2][2];
        {
            const size_t a0 = (bS + s0 + ln) * 64 + qr * 8;
            vb[0][0] = *(const uint4*)&vin[a0];
            vb[0][1] = *(const uint4*)&vin[a0 + 4];
            vb[1][0] = *(const uint4*)&vin[a0 + 32];
            vb[1][1] = *(const uint4*)&vin[a0 + 36];
        }

#pragma unroll
        for (int mi = 0; mi < 2; ++mi) {
            uint4 vn[2][2];
            if (mi < 1) {
                const size_t an = (bS + s0 + 16 + ln) * 64 + qr * 8;
                vn[0][0] = *(const uint4*)&vin[an];
                vn[0][1] = *(const uint4*)&vin[an + 4];
                vn[1][0] = *(const uint4*)&vin[an + 32];
                vn[1][1] = *(const uint4*)&vin[an + 36];
            }
            const int srow = mi * 16 + ln;
            f32x4 accP[2], accS[2];
#pragma unroll
            for (int ni = 0; ni < 2; ++ni) {
                accP[ni] = (f32x4){0.f,0.f,0.f,0.f};
                accS[ni] = (f32x4){0.f,0.f,0.f,0.f};
            }

#pragma unroll
            for (int kk = 0; kk < 2; ++kk) {
                s16x8 ah, al;
                unpack_frag2(vb[kk][0], vb[kk][1], &ah, &al);
#pragma unroll
                for (int ni = 0; ni < 2; ++ni) {
                    accP[ni] = __builtin_amdgcn_mfma_f32_16x16x32_bf16(ah, Bh[kk][ni], accP[ni], 0, 0, 0);
                    accS[ni] = __builtin_amdgcn_mfma_f32_16x16x32_bf16(al, Bh[kk][ni], accS[ni], 0, 0, 0);
                    accS[ni] = __builtin_amdgcn_mfma_f32_16x16x32_bf16(ah, Bl[kk][ni], accS[ni], 0, 0, 0);
                }
            }
            {
                const size_t aoff = (size_t)(s0 + srow) * 32 + qr * 8;
                s16x8 mh = *(const s16x8*)&MThi[aoff];
                s16x8 ml = *(const s16x8*)&MTlo[aoff];
#pragma unroll
                for (int ni = 0; ni < 2; ++ni) {
                    accP[ni] = __builtin_amdgcn_mfma_f32_16x16x32_bf16(mh, Dhf[ni], accP[ni], 0, 0, 0);
                    accS[ni] = __builtin_amdgcn_mfma_f32_16x16x32_bf16(ml, Dhf[ni], accS[ni], 0, 0, 0);
                    accS[ni] = __builtin_amdgcn_mfma_f32_16x16x32_bf16(mh, Dlf[ni], accS[ni], 0, 0, 0);
                }
            }
#pragma unroll
            for (int ni = 0; ni < 2; ++ni) {
                const int o = half * 32 + ni * 16 + ln;
                f32x4 acc = accP[ni] + accS[ni];
#pragma unroll
                for (int r = 0; r < 4; ++r) {
                    const int sl32 = mi * 16 + qr * 4 + r;
                    float val = acc[r] + cbv[ni];
                    unsigned short h = f2bf(val);
                    unsigned short l = f2bf(val - bf2f(h));
                    const int a = swz2(sl32, o);
                    Vhp[a] = h;
                    Vlp[a] = l;
                }
            }
            if (mi < 1) {
                vb[0][0] = vn[0][0]; vb[0][1] = vn[0][1];
                vb[1][0] = vn[1][0]; vb[1][1] = vn[1][1];
            }
        }
    }
    __syncthreads();

    // ---- phase B: fc1 GEMM, own (br, 64-h half), 32 s-rows ----
    s16x8 Wh[2][4], Wl[2][4];
#pragma unroll
    for (int kk = 0; kk < 2; ++kk)
#pragma unroll
        for (int ni = 0; ni < 4; ++ni) {
            const int h = half * 64 + ni * 16 + ln;
            const int boff = br * 8192 + h * 64 + kk * 32 + qr * 8;
            Wh[kk][ni] = *(const s16x8*)&w1hi[boff];
            Wl[kk][ni] = *(const s16x8*)&w1lo[boff];
        }
    float b1v[4], w2v[4];
#pragma unroll
    for (int ni = 0; ni < 4; ++ni) {
        b1v[ni] = fc1b[half * 64 + ni * 16 + ln];
        w2v[ni] = fc2w[half * 64 + ni * 16 + ln];
    }

#pragma unroll
    for (int mi = 0; mi < 2; ++mi) {
        f32x4 a1P[4], a1S[4];
#pragma unroll
        for (int ni = 0; ni < 4; ++ni) {
            a1P[ni] = (f32x4){0.f,0.f,0.f,0.f};
            a1S[ni] = (f32x4){0.f,0.f,0.f,0.f};
        }

#pragma unroll
        for (int kk = 0; kk < 2; ++kk) {
            const int blk = kk * 4 + qr;
            const int sl  = mi * 16 + ln;
            const int a   = sl * 64 + ((blk ^ (sl & 7)) << 3);
            s16x8 ah = *(const s16x8*)&Vhp[a];
            s16x8 al = *(const s16x8*)&Vlp[a];
#pragma unroll
            for (int ni = 0; ni < 4; ++ni) {
                a1P[ni] = __builtin_amdgcn_mfma_f32_16x16x32_bf16(ah, Wh[kk][ni], a1P[ni], 0, 0, 0);
                a1S[ni] = __builtin_amdgcn_mfma_f32_16x16x32_bf16(al, Wh[kk][ni], a1S[ni], 0, 0, 0);
                a1S[ni] = __builtin_amdgcn_mfma_f32_16x16x32_bf16(ah, Wl[kk][ni], a1S[ni], 0, 0, 0);
            }
        }
        float partial[4] = {0.f, 0.f, 0.f, 0.f};
#pragma unroll
        for (int ni = 0; ni < 4; ++ni) {
            f32x4 acc1 = a1P[ni] + a1S[ni];
#pragma unroll
            for (int r = 0; r < 4; ++r)
                partial[r] += gelu_f(acc1[r] + b1v[ni]) * w2v[ni];
        }
#pragma unroll
        for (int r = 0; r < 4; ++r) {
            partial[r] += __shfl_xor(partial[r], 1, 64);
            partial[r] += __shfl_xor(partial[r], 2, 64);
            partial[r] += __shfl_xor(partial[r], 4, 64);
            partial[r] += __shfl_xor(partial[r], 8, 64);
        }
        if (ln == 0) {
#pragma unroll
            for (int r = 0; r < 4; ++r)
                SP[w][mi * 16 + qr * 4 + r] = partial[r];
        }
    }
    __syncthreads();

    if (t < 32) {
        const float bias = fc2b_0[0] + fc2b_1[0];
        out[bS + s0 + t] = SP[0][t] + SP[1][t] + SP[2][t] + SP[3][t] + bias;
    }
}

// ---------------------------------------------------------------------------
extern "C" void kernel_launch(void* const* d_in, const int* in_sizes, int n_in,
                              void* d_out, int out_size, void* d_ws, size_t ws_size,
                              hipStream_t stream)
{
    const float* x = (const float*)d_in[0];
    const float* P[2][10];
    for (int br = 0; br < 2; ++br)
        for (int k = 0; k < 10; ++k)
            P[br][k] = (const float*)d_in[1 + br * 10 + k];
    // order: fc0_w, fc0_b, wave_w1, wave_w2, cw, cb, fc1_w, fc1_b, fc2_w, fc2_b

    char* p = (char*)d_ws;
    const size_t PL = (size_t)BC * SLEN * 4;   // one packed u32 plane: 16.78 MB
    unsigned int* vplane[4];                   // [br][pingpong]
    for (int i = 0; i < 4; ++i) { vplane[i] = (unsigned int*)p; p += PL; }
    unsigned short* Ahi  = (unsigned short*)p; p += 32 * SLEN * 2;
    unsigned short* Alo  = (unsigned short*)p; p += 32 * SLEN * 2;
    unsigned short* MThi = (unsigned short*)p; p += SLEN * 32 * 2;
    unsigned short* MTlo = (unsigned short*)p; p += SLEN * 32 * 2;
    float* Ppart = (float*)p;                  p += (size_t)128 * NT * 28 * 64 * 4;
    unsigned short* cwPhi = (unsigned short*)p; p += 8 * 4096 * 2;   // [L][br]
    unsigned short* cwPlo = (unsigned short*)p; p += 8 * 4096 * 2;
    unsigned short* Dhi   = (unsigned short*)p; p += (size_t)128 * 2048 * 2;
    unsigned short* Dlo   = (unsigned short*)p; p += (size_t)128 * 2048 * 2;
    unsigned short* w1hi  = (unsigned short*)p; p += 2 * 8192 * 2;
    unsigned short* w1lo  = (unsigned short*)p; p += 2 * 8192 * 2;
    float* axbuf          = (float*)p;          p += 66 * 28 * 4;
    float* WsT            = (float*)p;          p += (size_t)4 * 2 * 28 * 4096 * 4;

    unsigned int *v0a = vplane[0], *v0b = vplane[1];
    unsigned int *v1a = vplane[2], *v1b = vplane[3];

    setup_kernel<<<1142, 256, 0, stream>>>(
        x, Ahi, Alo, MThi, MTlo, axbuf,
        P[0][6], P[1][6], P[0][4], P[1][4],
        P[0][2], P[0][3], P[1][2], P[1][3],
        w1hi, w1lo, cwPhi, cwPlo, Dhi, Dlo, WsT);

    mix0_kernel<<<448, 256, 0, stream>>>(
        axbuf, P[0][0], P[0][1], P[1][0], P[1][1],
        WsT, Dhi, Dlo);

    for (int i = 0; i < 3; ++i) {
        layer_kernel<<<2048, 128, 0, stream>>>(
            v0a, v1a, v0b, v1b,
            MThi, MTlo, Ahi, Alo, cwPhi, cwPlo, Dhi, Dlo,
            P[0][5] + (size_t)i * WCH, P[1][5] + (size_t)i * WCH,
            P[0][0], P[0][1], P[1][0], P[1][1], x,
            Ppart, i);
        unsigned int* tmp;
        tmp = v0a; v0a = v0b; v0b = tmp;
        tmp = v1a; v1a = v1b; v1b = tmp;

        mix_kernel<<<448, 256, 0, stream>>>(
            Ppart,
            WsT + (size_t)(i + 1) * 2 * 28 * 4096,
            Dhi, Dlo);
    }

    head_kernel<<<2048, 256, 0, stream>>>(
        v0a, v1a,
        MThi, MTlo, cwPhi, cwPlo, Dhi, Dlo,
        P[0][5] + (size_t)3 * WCH, P[1][5] + (size_t)3 * WCH,
        w1hi, w1lo,
        P[0][7], P[0][8], P[0][9],
        P[1][7], P[1][8], P[1][9],
        (float*)d_out);
}

// Round 8
// 222.665 us; speedup vs baseline: 4.2349x; 1.1797x over previous
//
#include <hip/hip_runtime.h>
#include <hip/hip_bf16.h>
#include <math.h>

// ---------------------------------------------------------------------------
// WNO1d. Round 27: fragment-ordered operand tables. Every MFMA operand table
// (A, M^T, cwT, D, w1) is pre-packed as [..][lane][8] so fragment loads are
// base + lane*16B (coalesced), replacing 64B/128B/2KB-strided gathers that
// dominated per-wave stalls (R6/R7: head pinned at ~50us across occupancy
// changes => stall-bound, not residency-bound). Values & math identical.
// Structure: setup, mix0, (layer, mix)x3, head-split = 9 dispatches.
// ---------------------------------------------------------------------------

#define BDIM 64
#define SLEN 1024
#define WCH  64
#define BC   (BDIM*WCH)
#define NT   16         // 64-s proj tiles per batch

typedef short s16x8 __attribute__((ext_vector_type(8)));
typedef float f32x4 __attribute__((ext_vector_type(4)));
typedef unsigned short u16x4 __attribute__((ext_vector_type(4)));

constexpr float RLv[12] = {
    0.11154074335008017f, 0.4946238903983854f, 0.7511339080215775f,
    0.3152503517092432f, -0.22626469396516913f, -0.12976686756709563f,
    0.09750160558707936f, 0.02752286553001629f, -0.031582039318031156f,
    0.0005538422009938016f, 0.004777257511010651f, -0.00107730108499558f };
constexpr float AHv[12] = {
     RLv[11], -RLv[10],  RLv[9], -RLv[8],  RLv[7], -RLv[6],
     RLv[5],  -RLv[4],   RLv[3], -RLv[2],  RLv[1], -RLv[0] };
constexpr float SLv[12] = {
     RLv[11], RLv[10], RLv[9], RLv[8], RLv[7], RLv[6],
     RLv[5],  RLv[4],  RLv[3], RLv[2], RLv[1], RLv[0] };
constexpr float SHv[12] = {
    -RLv[0],  RLv[1], -RLv[2],  RLv[3], -RLv[4],  RLv[5],
    -RLv[6],  RLv[7], -RLv[8],  RLv[9], -RLv[10], RLv[11] };

__device__ __forceinline__ float gelu_f(float x) {
    float z = 0.7978845608f * (x + 0.044715f * x * x * x);
    return x / (1.0f + __expf(-2.0f * z));
}
__device__ __forceinline__ unsigned short f2bf(float f) {
    __hip_bfloat16 h = __float2bfloat16(f);
    union { __hip_bfloat16 h; unsigned short u; } cv; cv.h = h; return cv.u;
}
__device__ __forceinline__ float bf2f(unsigned short u) {
    union { unsigned short u; __hip_bfloat16 h; } cv; cv.u = u;
    return __bfloat162float(cv.h);
}
// unpack 8 packed u32 (as two uint4) -> hi frag + lo frag (8 v_perm)
__device__ __forceinline__ void unpack_frag2(uint4 a, uint4 b,
                                             s16x8* ah, s16x8* al) {
    union { s16x8 v; unsigned int d[4]; } H, L;
    H.d[0] = __builtin_amdgcn_perm(a.y, a.x, 0x05040100u);
    H.d[1] = __builtin_amdgcn_perm(a.w, a.z, 0x05040100u);
    H.d[2] = __builtin_amdgcn_perm(b.y, b.x, 0x05040100u);
    H.d[3] = __builtin_amdgcn_perm(b.w, b.z, 0x05040100u);
    L.d[0] = __builtin_amdgcn_perm(a.y, a.x, 0x07060302u);
    L.d[1] = __builtin_amdgcn_perm(a.w, a.z, 0x07060302u);
    L.d[2] = __builtin_amdgcn_perm(b.y, b.x, 0x07060302u);
    L.d[3] = __builtin_amdgcn_perm(b.w, b.z, 0x07060302u);
    *ah = H.v; *al = L.v;
}

// swizzled [c][s] plane (64x64 shorts)
__device__ __forceinline__ int swz(int c, int s) {
    return c * 64 + ((((s >> 3) ^ (c & 7)) << 3) | (s & 7));
}
// swizzled [s][c] plane
__device__ __forceinline__ int swz2(int s, int c) {
    return s * 64 + ((((c >> 3) ^ (s & 7)) << 3) | (c & 7));
}

// fragment-table index helpers (element offsets; each frag = lane*8 shorts)
__device__ __host__ __forceinline__ int AF_IDX(int tile, int kk, int mt, int lane) {
    return (((tile * 2 + kk) * 2 + mt) * 64 + lane) * 8;
}
__device__ __host__ __forceinline__ int MTF_IDX(int row16, int lane) {
    return (row16 * 64 + lane) * 8;
}
__device__ __host__ __forceinline__ int CWF_IDX(int L, int br, int w, int kk, int ni) {
    return ((((L * 2 + br) * 2 + w) * 2 + kk) * 2 + ni) * 512;
}
__device__ __host__ __forceinline__ int DF_IDX(int bb, int w, int ni) {
    return ((bb * 2 + w) * 2 + ni) * 512;
}
__device__ __host__ __forceinline__ int W1F_IDX(int br, int half, int kk, int ni) {
    return (((br * 2 + half) * 2 + kk) * 4 + ni) * 512;
}

// 2-wave proj: A[28 x 64-s-tile] x P[64c x 64s] -> Ppart. Wave w owns c-half.
__device__ __forceinline__ void proj2(
    const unsigned short* Phi, const unsigned short* Plo,
    const unsigned short* __restrict__ AFhi, const unsigned short* __restrict__ AFlo,
    float* __restrict__ Ppart, int bb, int tile, int t)
{
    const int lane = t & 63;
    const int w    = t >> 6;
    const int qr   = lane >> 4;
    const int ln   = lane & 15;

    s16x8 pah[2][2], pal[2][2];      // [kk][mt]
#pragma unroll
    for (int kk = 0; kk < 2; ++kk)
#pragma unroll
        for (int mt = 0; mt < 2; ++mt) {
            const int off = AF_IDX(tile, kk, mt, lane);
            pah[kk][mt] = *(const s16x8*)&AFhi[off];
            pal[kk][mt] = *(const s16x8*)&AFlo[off];
        }

    f32x4 pP[2][2], pS[2][2];
#pragma unroll
    for (int mt = 0; mt < 2; ++mt)
#pragma unroll
        for (int ni = 0; ni < 2; ++ni) {
            pP[mt][ni] = (f32x4){0.f,0.f,0.f,0.f};
            pS[mt][ni] = (f32x4){0.f,0.f,0.f,0.f};
        }

#pragma unroll
    for (int kk = 0; kk < 2; ++kk) {
        const int bk = kk * 4 + qr;
#pragma unroll
        for (int ni = 0; ni < 2; ++ni) {
            const int c = w * 32 + ni * 16 + ln;
            const int boff = c * 64 + ((bk ^ (c & 7)) << 3);
            s16x8 bh = *(const s16x8*)&Phi[boff];
            s16x8 bl = *(const s16x8*)&Plo[boff];
#pragma unroll
            for (int mt = 0; mt < 2; ++mt) {
                pP[mt][ni] = __builtin_amdgcn_mfma_f32_16x16x32_bf16(pah[kk][mt], bh, pP[mt][ni], 0, 0, 0);
                pS[mt][ni] = __builtin_amdgcn_mfma_f32_16x16x32_bf16(pal[kk][mt], bh, pS[mt][ni], 0, 0, 0);
                pS[mt][ni] = __builtin_amdgcn_mfma_f32_16x16x32_bf16(pah[kk][mt], bl, pS[mt][ni], 0, 0, 0);
            }
        }
    }
#pragma unroll
    for (int mt = 0; mt < 2; ++mt)
#pragma unroll
        for (int ni = 0; ni < 2; ++ni) {
            const int c = w * 32 + ni * 16 + ln;
            f32x4 pv = pP[mt][ni] + pS[mt][ni];
#pragma unroll
            for (int r = 0; r < 4; ++r) {
                const int xr = mt * 16 + qr * 4 + r;
                if (xr < 28)
                    Ppart[((size_t)(bb * NT + tile) * 28 + xr) * 64 + c] = pv[r];
            }
        }
}

// ---------------------------------------------------------------------------
// setup: 0..1023 A columns; 1024..1051 M rows; 1052..1117 data cascade;
//        1118..1125 weight prep; 1126..1141 WsT transpose.
// All operator tables written in fragment order.
// ---------------------------------------------------------------------------
__global__ __launch_bounds__(256) void setup_kernel(
    const float* __restrict__ x,
    unsigned short* __restrict__ AFhi, unsigned short* __restrict__ AFlo,
    unsigned short* __restrict__ MTFhi, unsigned short* __restrict__ MTFlo,
    float* __restrict__ axbuf,
    const float* __restrict__ fc1w_0, const float* __restrict__ fc1w_1,
    const float* __restrict__ cw_0, const float* __restrict__ cw_1,
    const float* __restrict__ w1_0, const float* __restrict__ w2_0,
    const float* __restrict__ w1_1, const float* __restrict__ w2_1,
    unsigned short* __restrict__ w1Fhi, unsigned short* __restrict__ w1Flo,
    unsigned short* __restrict__ cwFhi, unsigned short* __restrict__ cwFlo,
    unsigned short* __restrict__ DFhi,  unsigned short* __restrict__ DFlo,
    float* __restrict__ WsT)
{
    __shared__ float Af[1024];
    __shared__ float Bff[520];
    __shared__ float hib[14];
    const int t = threadIdx.x;

    if (blockIdx.x < 1024 || (blockIdx.x >= 1052 && blockIdx.x < 1118)) {
        const bool isA = (blockIdx.x < 1024);
        const int s0 = blockIdx.x;
        const int di = blockIdx.x - 1052;
        for (int i = t; i < SLEN; i += 256) {
            float v;
            if (isA)           v = (i == s0) ? 1.0f : 0.0f;
            else if (di < 64)  v = x[di * SLEN + i];
            else if (di == 64) v = (float)i * (1.0f / 1023.0f);
            else               v = 1.0f;
            Af[i] = v;
        }
        __syncthreads();

        const int NIN[8]  = {1024, 517, 264, 137, 74, 42, 26, 18};
        const int NOUT[8] = { 517, 264, 137,  74, 42, 26, 18, 14};
        // column decomposition for AF writes
        const int tile = s0 >> 6, kkc = (s0 >> 5) & 1, qrc = (s0 >> 3) & 3,
                  jc = s0 & 7;
#pragma unroll
        for (int lev = 0; lev < 8; ++lev) {
            float* in  = (lev & 1) ? Bff : Af;
            float* out = (lev & 1) ? Af : Bff;
            const int nin = NIN[lev], nout = NOUT[lev];
            for (int m = t; m < nout; m += 256) {
                float alo = 0.f, ahi = 0.f;
#pragma unroll
                for (int tt = 0; tt < 12; ++tt) {
                    int jj = 2 * m + tt - 10;
                    if (jj < 0)         jj = -1 - jj;
                    else if (jj >= nin) jj = 2 * nin - 1 - jj;
                    float xv = in[jj];
                    alo += xv * RLv[tt];
                    if (lev == 7) ahi += xv * AHv[tt];
                }
                out[m] = alo;
                if (lev == 7) {
                    if (isA) {
                        unsigned short h1 = f2bf(alo);
                        unsigned short l1 = f2bf(alo - bf2f(h1));
                        {   // row m (0..13)
                            const int lane = qrc * 16 + (m & 15);
                            const int off = AF_IDX(tile, kkc, m >> 4, lane) + jc;
                            AFhi[off] = h1; AFlo[off] = l1;
                        }
                        unsigned short h2 = f2bf(ahi);
                        unsigned short l2 = f2bf(ahi - bf2f(h2));
                        {   // row 14+m
                            const int row = 14 + m;
                            const int lane = qrc * 16 + (row & 15);
                            const int off = AF_IDX(tile, kkc, row >> 4, lane) + jc;
                            AFhi[off] = h2; AFlo[off] = l2;
                        }
                    } else {
                        axbuf[di * 28 + m]      = alo;
                        axbuf[di * 28 + 14 + m] = ahi;
                    }
                }
            }
            __syncthreads();
        }
        if (isA && t < 4) {
            {   // A pad rows 28..31 at column s0
                const int row = 28 + t;
                const int lane = qrc * 16 + (row & 15);
                const int off = AF_IDX(tile, kkc, 1, lane) + jc;
                AFhi[off] = 0; AFlo[off] = 0;
            }
            {   // MT pad cols 28..31 at row s0
                const int col = 28 + t;
                const int lane = (col >> 3) * 16 + (s0 & 15);
                const int off = MTF_IDX(s0 >> 4, lane) + (col & 7);
                MTFhi[off] = 0; MTFlo[off] = 0;
            }
        }
        return;
    }

    if (blockIdx.x >= 1126) {
        // WsT: [(L*2+br)*28 + x][i*64+o]
        const int wsb = blockIdx.x - 1126;       // 0..15
        const int L = wsb >> 2, br = (wsb >> 1) & 1, which = wsb & 1;
        const float* src = (which ? (br ? w2_1 : w2_0) : (br ? w1_1 : w1_0))
                         + (size_t)L * 64 * 64 * 14;
        const size_t dbase = ((size_t)(L * 2 + br) * 28 + which * 14) * 4096;
        for (int e = t; e < 4096; e += 256) {
            const float* sp = src + (size_t)e * 14;
            float v[14];
#pragma unroll
            for (int xi = 0; xi < 14; ++xi) v[xi] = sp[xi];
#pragma unroll
            for (int xi = 0; xi < 14; ++xi)
                WsT[dbase + (size_t)xi * 4096 + e] = v[xi];
        }
        return;
    }

    if (blockIdx.x >= 1118) {
        // weight prep (fragment-order outputs)
        const int gid = (blockIdx.x - 1118) * 256 + t;
        for (int idx = gid; idx < 16384; idx += 2048) {
            int br = idx >> 13, r = idx & 8191;
            int h = r >> 6, c = r & 63;
            float f = (br ? fc1w_1 : fc1w_0)[c * 128 + h];
            unsigned short hh = f2bf(f);
            const int half = (h >> 6) & 1, ni = (h >> 4) & 3, lnh = h & 15;
            const int kk = c >> 5, qr = (c >> 3) & 3, j = c & 7;
            const int off = W1F_IDX(br, half, kk, ni) + (qr * 16 + lnh) * 8 + j;
            w1Fhi[off] = hh;
            w1Flo[off] = f2bf(f - bf2f(hh));
        }
        for (int idx = gid; idx < 32768; idx += 2048) {   // cwT split, all layers
            int L = idx >> 13, br = (idx >> 12) & 1, e = idx & 4095;
            int k = e >> 6, o = e & 63;
            float val = (br ? cw_1 : cw_0)[(size_t)L * 4096 + o * 64 + k]
                      + ((k == o) ? 1.0f : 0.0f);
            unsigned short h = f2bf(val);
            const int w = o >> 5, ni = (o >> 4) & 1, lno = o & 15;
            const int kk = k >> 5, qr = (k >> 3) & 3, j = k & 7;
            const int off = CWF_IDX(L, br, w, kk, ni) + (qr * 16 + lno) * 8 + j;
            cwFhi[off] = h;
            cwFlo[off] = f2bf(val - bf2f(h));
        }
        for (int idx = gid; idx < 32768; idx += 2048) {   // D pad x=28..31
            int bb = idx >> 8, o = (idx >> 2) & 63, j3 = idx & 3;
            const int x = 28 + j3;
            const int w = o >> 5, ni = (o >> 4) & 1, lno = o & 15;
            const int off = DF_IDX(bb, w, ni) + ((x >> 3) * 16 + lno) * 8 + (x & 7);
            DFhi[off] = 0;
            DFlo[off] = 0;
        }
        return;
    }

    // synthesis rows (M^T) -> MTF fragment order
    const int u = blockIdx.x - 1024;     // 0..27
    if (t < 14) {
        Af[t]  = (u < 14 && t == u) ? 1.0f : 0.0f;
        hib[t] = (u >= 14 && t == (u - 14)) ? 1.0f : 0.0f;
    }
    __syncthreads();

    const int NH[8] = {14, 18, 26, 42, 74, 137, 264, 517};
    const int NO[8] = {18, 26, 42, 74, 138, 264, 518, 1024};

#pragma unroll
    for (int s = 0; s < 8; ++s) {
        const float* lo = (s & 1) ? Bff : Af;
        float* out      = (s & 1) ? Af : Bff;
        const int N = NH[s], nout = NO[s];
        for (int m = t; m < nout; m += 256) {
            float acc = 0.f;
#pragma unroll
            for (int tt = 0; tt < 12; ++tt) {
                int uu = m + tt - 1;
                if ((uu & 1) == 0) {
                    int q = uu >> 1;
                    if (q < N) {
                        acc += lo[q] * SLv[tt];
                        if (s == 0) acc += hib[q] * SHv[tt];
                    }
                }
            }
            out[m] = acc;
        }
        __syncthreads();
    }
    {
        const int qr = u >> 3, j = u & 7;
        for (int m = t; m < SLEN; m += 256) {
            float f = Af[m];
            unsigned short h = f2bf(f);
            const int off = MTF_IDX(m >> 4, qr * 16 + (m & 15)) + j;
            MTFhi[off] = h;
            MTFlo[off] = f2bf(f - bf2f(h));
        }
    }
}

// ---------------------------------------------------------------------------
// mix0: layer-0 mix from rank-3 formula; writes DF in fragment order.
// ---------------------------------------------------------------------------
__global__ __launch_bounds__(256) void mix0_kernel(
    const float* __restrict__ axbuf,
    const float* __restrict__ fc0w_0, const float* __restrict__ fc0b_0,
    const float* __restrict__ fc0w_1, const float* __restrict__ fc0b_1,
    const float* __restrict__ WsT0,
    unsigned short* __restrict__ DFhi, unsigned short* __restrict__ DFlo)
{
    const int t = threadIdx.x;
    const int br  = blockIdx.x / 224;
    const int sub = blockIdx.x % 224;

    __shared__ float Ws[64][65];
    __shared__ float LO[8][64];
    const int o = t & 63;
    const int w = t >> 6;
    const int x  = sub >> 3;
    const int b0 = (sub & 7) << 3;

    const float* wsrc = WsT0 + ((size_t)(br * 28 + x)) * 4096;
    for (int idx = t; idx < 4096; idx += 256)
        Ws[idx >> 6][idx & 63] = wsrc[idx];

    const float* fc0w = br ? fc0w_1 : fc0w_0;
    const float* fc0b = br ? fc0b_1 : fc0b_0;
    const float agv = axbuf[64 * 28 + x];
    const float a1v = axbuf[65 * 28 + x];
    const float w0o = fc0w[o];
    const float wgo = fc0w[WCH + o];
    const float b0o = fc0b[o];

#pragma unroll
    for (int j = 0; j < 2; ++j) {
        int bi = w + 4 * j;
        int b  = b0 + bi;
        float axv = axbuf[b * 28 + x];
        LO[bi][o] = axv * w0o + agv * wgo + a1v * b0o;
    }
    __syncthreads();

    const int wo = o >> 5, nio = (o >> 4) & 1, lno = o & 15;
    const int dsub = ((x >> 3) * 16 + lno) * 8 + (x & 7);
#pragma unroll
    for (int j = 0; j < 2; ++j) {
        int bi = w + 4 * j;
        int bb = br * 64 + b0 + bi;
        float acc = 0.f;
        for (int i = 0; i < 64; ++i)
            acc += LO[bi][i] * Ws[i][o];
        acc -= LO[bi][o];
        unsigned short h = f2bf(acc);
        const int off = DF_IDX(bb, wo, nio) + dsub;
        DFhi[off] = h;
        DFlo[off] = f2bf(acc - bf2f(h));
    }
}

// ---------------------------------------------------------------------------
// Mix (layers 1..3): reads Ppart; writes DF in fragment order.
// ---------------------------------------------------------------------------
__global__ __launch_bounds__(256) void mix_kernel(
    const float* __restrict__ Ppart,
    const float* __restrict__ WsTL,
    unsigned short* __restrict__ DFhi, unsigned short* __restrict__ DFlo)
{
    const int t = threadIdx.x;
    const int br  = blockIdx.x / 224;
    const int sub = blockIdx.x % 224;

    __shared__ float Ws[64][65];
    __shared__ float LO[8][64];
    const int o = t & 63;
    const int w = t >> 6;
    const int x  = sub >> 3;
    const int b0 = (sub & 7) << 3;

    const float* wsrc = WsTL + ((size_t)(br * 28 + x)) * 4096;
    for (int idx = t; idx < 4096; idx += 256)
        Ws[idx >> 6][idx & 63] = wsrc[idx];

#pragma unroll
    for (int j = 0; j < 2; ++j) {
        int bi = w + 4 * j;
        int bb = br * 64 + b0 + bi;
        float s = 0.f;
        for (int tile = 0; tile < NT; ++tile)
            s += Ppart[((size_t)(bb * NT + tile) * 28 + x) * 64 + o];
        LO[bi][o] = s;
    }
    __syncthreads();

    const int wo = o >> 5, nio = (o >> 4) & 1, lno = o & 15;
    const int dsub = ((x >> 3) * 16 + lno) * 8 + (x & 7);
#pragma unroll
    for (int j = 0; j < 2; ++j) {
        int bi = w + 4 * j;
        int bb = br * 64 + b0 + bi;
        float acc = 0.f;
        for (int i = 0; i < 64; ++i)
            acc += LO[bi][i] * Ws[i][o];
        acc -= LO[bi][o];
        unsigned short h = f2bf(acc);
        const int off = DF_IDX(bb, wo, nio) + dsub;
        DFhi[off] = h;
        DFlo[off] = f2bf(acc - bf2f(h));
    }
}

// ---------------------------------------------------------------------------
// Fused layer (i = 0,1,2): 2048 blocks x 128 thr, 2 waves per 64-s tile.
// All operand-fragment loads coalesced (lane*16B). No barriers.
// ---------------------------------------------------------------------------
__global__ __launch_bounds__(128, 3) void layer_kernel(
    const unsigned int* __restrict__ vin0, const unsigned int* __restrict__ vin1,
    unsigned int* __restrict__ vout0, unsigned int* __restrict__ vout1,
    const unsigned short* __restrict__ MTFhi, const unsigned short* __restrict__ MTFlo,
    const unsigned short* __restrict__ AFhi,  const unsigned short* __restrict__ AFlo,
    const unsigned short* __restrict__ cwFhi, const unsigned short* __restrict__ cwFlo,
    const unsigned short* __restrict__ DFhi,   const unsigned short* __restrict__ DFlo,
    const float* __restrict__ cb_0, const float* __restrict__ cb_1,
    const float* __restrict__ fc0w_0, const float* __restrict__ fc0b_0,
    const float* __restrict__ fc0w_1, const float* __restrict__ fc0b_1,
    const float* __restrict__ xin,
    float* __restrict__ Ppart, int Lidx)
{
    __shared__ unsigned short Phi[4096];   // block-shared swizzled [c][s64]
    __shared__ unsigned short Plo[4096];

    const int t = threadIdx.x;
    const int bid = blockIdx.x;
    const int br  = bid >> 10;
    const int rem = bid & 1023;
    const int b    = rem >> 4;
    const int tile = rem & 15;
    const int s0   = tile << 6;
    const size_t bS = (size_t)b * SLEN;
    const unsigned int* vin = br ? vin1 : vin0;
    unsigned int* vout      = br ? vout1 : vout0;
    const float* cb = br ? cb_1 : cb_0;
    const float* f0w = br ? fc0w_1 : fc0w_0;
    const float* f0b = br ? fc0b_1 : fc0b_0;
    const int bb = br * 64 + b;

    const int lane = t & 63;
    const int w    = t >> 6;          // 0..1: o-half
    const int qr   = lane >> 4;
    const int ln   = lane & 15;

    // ---- preload B fragments (coalesced: base + lane*16B) ----
    s16x8 Bh[2][2], Bl[2][2];
#pragma unroll
    for (int kk = 0; kk < 2; ++kk)
#pragma unroll
        for (int ni = 0; ni < 2; ++ni) {
            const int off = CWF_IDX(Lidx, br, w, kk, ni) + lane * 8;
            Bh[kk][ni] = *(const s16x8*)&cwFhi[off];
            Bl[kk][ni] = *(const s16x8*)&cwFlo[off];
        }
    s16x8 Dhf[2], Dlf[2];
#pragma unroll
    for (int ni = 0; ni < 2; ++ni) {
        const int off = DF_IDX(bb, w, ni) + lane * 8;
        Dhf[ni] = *(const s16x8*)&DFhi[off];
        Dlf[ni] = *(const s16x8*)&DFlo[off];
    }
    float cbv[2];
#pragma unroll
    for (int ni = 0; ni < 2; ++ni) cbv[ni] = cb[w * 32 + ni * 16 + ln];

    // ---- prefetch vin (or x) for mi=0 ----
    uint4 vb[2][2];                 // [kk][half]
    float xpf = 0.f;
    if (Lidx == 0) {
        xpf = xin[bS + s0 + ln];
    } else {
        const size_t a0 = (bS + s0 + ln) * 64 + qr * 8;
        vb[0][0] = *(const uint4*)&vin[a0];
        vb[0][1] = *(const uint4*)&vin[a0 + 4];
        vb[1][0] = *(const uint4*)&vin[a0 + 32];
        vb[1][1] = *(const uint4*)&vin[a0 + 36];
    }

    // ---- 4 m-tiles ----
#pragma unroll
    for (int mi = 0; mi < 4; ++mi) {
        const int srow = mi * 16 + ln;
        uint4 vn[2][2];
        float xnf = 0.f;
        if (mi < 3) {
            if (Lidx == 0) {
                xnf = xin[bS + s0 + (mi + 1) * 16 + ln];
            } else {
                const size_t an = (bS + s0 + (mi + 1) * 16 + ln) * 64 + qr * 8;
                vn[0][0] = *(const uint4*)&vin[an];
                vn[0][1] = *(const uint4*)&vin[an + 4];
                vn[1][0] = *(const uint4*)&vin[an + 32];
                vn[1][1] = *(const uint4*)&vin[an + 36];
            }
        }

        f32x4 accP[2], accS[2];
#pragma unroll
        for (int ni = 0; ni < 2; ++ni) {
            accP[ni] = (f32x4){0.f,0.f,0.f,0.f};
            accS[ni] = (f32x4){0.f,0.f,0.f,0.f};
        }

#pragma unroll
        for (int kk = 0; kk < 2; ++kk) {
            s16x8 ah, al;
            if (Lidx == 0) {
                const int s = s0 + srow;
                const float gv = (float)s * (1.0f / 1023.0f);
#pragma unroll
                for (int j = 0; j < 8; ++j) {
                    const int c = kk * 32 + qr * 8 + j;
                    float val = xpf * f0w[c] + gv * f0w[WCH + c] + f0b[c];
                    unsigned short h = f2bf(val);
                    ah[j] = (short)h;
                    al[j] = (short)f2bf(val - bf2f(h));
                }
            } else {
                unpack_frag2(vb[kk][0], vb[kk][1], &ah, &al);
            }
#pragma unroll
            for (int ni = 0; ni < 2; ++ni) {
                accP[ni] = __builtin_amdgcn_mfma_f32_16x16x32_bf16(ah, Bh[kk][ni], accP[ni], 0, 0, 0);
                accS[ni] = __builtin_amdgcn_mfma_f32_16x16x32_bf16(al, Bh[kk][ni], accS[ni], 0, 0, 0);
                accS[ni] = __builtin_amdgcn_mfma_f32_16x16x32_bf16(ah, Bl[kk][ni], accS[ni], 0, 0, 0);
            }
        }
        {
            const int off = MTF_IDX((s0 >> 4) + mi, lane);
            s16x8 mh = *(const s16x8*)&MTFhi[off];
            s16x8 ml = *(const s16x8*)&MTFlo[off];
#pragma unroll
            for (int ni = 0; ni < 2; ++ni) {
                accP[ni] = __builtin_amdgcn_mfma_f32_16x16x32_bf16(mh, Dhf[ni], accP[ni], 0, 0, 0);
                accS[ni] = __builtin_amdgcn_mfma_f32_16x16x32_bf16(ml, Dhf[ni], accS[ni], 0, 0, 0);
                accS[ni] = __builtin_amdgcn_mfma_f32_16x16x32_bf16(mh, Dlf[ni], accS[ni], 0, 0, 0);
            }
        }
        // epilogue: gelu, split, packed global store + packed b64 LDS writes
#pragma unroll
        for (int ni = 0; ni < 2; ++ni) {
            const int o = w * 32 + ni * 16 + ln;
            f32x4 acc = accP[ni] + accS[ni];
            u16x4 hv, lv;
#pragma unroll
            for (int r = 0; r < 4; ++r) {
                const int sl64 = mi * 16 + qr * 4 + r;
                float val = gelu_f(acc[r] + cbv[ni]);
                unsigned short h = f2bf(val);
                unsigned short l = f2bf(val - bf2f(h));
                vout[(bS + s0 + sl64) * 64 + o] =
                    (unsigned int)h | ((unsigned int)l << 16);
                hv[r] = h;
                lv[r] = l;
            }
            const int a = swz(o, mi * 16 + qr * 4);
            *(u16x4*)&Phi[a] = hv;
            *(u16x4*)&Plo[a] = lv;
        }
        if (mi < 3) {
            if (Lidx == 0) {
                xpf = xnf;
            } else {
                vb[0][0] = vn[0][0]; vb[0][1] = vn[0][1];
                vb[1][0] = vn[1][0]; vb[1][1] = vn[1][1];
            }
        }
    }

    // ---- proj on own c-half (same-wave LDS RAW: no barrier needed) ----
    proj2(Phi, Plo, AFhi, AFlo, Ppart, bb, tile, t);
}

// ---------------------------------------------------------------------------
// Head with fused layer 3, BOTH branches, 32-s blocks: 2048 blocks x 256 thr
// (4 waves = {br}x{o-half}). All operand-fragment loads coalesced.
// ---------------------------------------------------------------------------
__global__ __launch_bounds__(256, 2) void head_kernel(
    const unsigned int* __restrict__ vin0, const unsigned int* __restrict__ vin1,
    const unsigned short* __restrict__ MTFhi, const unsigned short* __restrict__ MTFlo,
    const unsigned short* __restrict__ cwFhi, const unsigned short* __restrict__ cwFlo,
    const unsigned short* __restrict__ DFhi,   const unsigned short* __restrict__ DFlo,
    const float* __restrict__ cb_0, const float* __restrict__ cb_1,
    const unsigned short* __restrict__ w1Fhi, const unsigned short* __restrict__ w1Flo,
    const float* __restrict__ fc1b_0, const float* __restrict__ fc2w_0,
    const float* __restrict__ fc2b_0,
    const float* __restrict__ fc1b_1, const float* __restrict__ fc2w_1,
    const float* __restrict__ fc2b_1,
    float* __restrict__ out)
{
    __shared__ unsigned short Vh[4096];    // [br][swz2 32x64 plane]
    __shared__ unsigned short Vl[4096];
    __shared__ float SP[4][32];            // per-wave partials

    const int t = threadIdx.x;
    const int bid = blockIdx.x;            // 0..2047
    const int b    = bid >> 5;
    const int t32  = bid & 31;
    const int s0   = t32 << 5;
    const size_t bS = (size_t)b * SLEN;

    const int lane = t & 63;
    const int w    = t >> 6;          // 0..3
    const int br   = w >> 1;
    const int half = w & 1;
    const int qr   = lane >> 4;
    const int ln   = lane & 15;

    const unsigned int* vin = br ? vin1 : vin0;
    const float* cb   = (br ? cb_1 : cb_0) + 3 * WCH;
    const float* fc1b = br ? fc1b_1 : fc1b_0;
    const float* fc2w = br ? fc2w_1 : fc2w_0;
    const int bb = br * 64 + b;
    unsigned short* Vhp = Vh + br * 2048;
    unsigned short* Vlp = Vl + br * 2048;

    // ---- phase A: layer-3, own (br, 32-o half), 32 s-rows ----
    {
        s16x8 Bh[2][2], Bl[2][2];
#pragma unroll
        for (int kk = 0; kk < 2; ++kk)
#pragma unroll
            for (int ni = 0; ni < 2; ++ni) {
                const int off = CWF_IDX(3, br, half, kk, ni) + lane * 8;
                Bh[kk][ni] = *(const s16x8*)&cwFhi[off];
                Bl[kk][ni] = *(const s16x8*)&cwFlo[off];
            }
        s16x8 Dhf[2], Dlf[2];
#pragma unroll
        for (int ni = 0; ni < 2; ++ni) {
            const int off = DF_IDX(bb, half, ni) + lane * 8;
            Dhf[ni] = *(const s16x8*)&DFhi[off];
            Dlf[ni] = *(const s16x8*)&DFlo[off];
        }
        float cbv[2];
#pragma unroll
        for (int ni = 0; ni < 2; ++ni) cbv[ni] = cb[half * 32 + ni * 16 + ln];

        uint4 vb[2][2];
        {
            const size_t a0 = (bS + s0 + ln) * 64 + qr * 8;
            vb[0][0] = *(const uint4*)&vin[a0];
            vb[0][1] = *(const uint4*)&vin[a0 + 4];
            vb[1][0] = *(const uint4*)&vin[a0 + 32];
            vb[1][1] = *(const uint4*)&vin[a0 + 36];
        }

#pragma unroll
        for (int mi = 0; mi < 2; ++mi) {
            uint4 vn[2][2];
            if (mi < 1) {
                const size_t an = (bS + s0 + 16 + ln) * 64 + qr * 8;
                vn[0][0] = *(const uint4*)&vin[an];
                vn[0][1] = *(const uint4*)&vin[an + 4];
                vn[1][0] = *(const uint4*)&vin[an + 32];
                vn[1][1] = *(const uint4*)&vin[an + 36];
            }
            f32x4 accP[2], accS[2];
#pragma unroll
            for (int ni = 0; ni < 2; ++ni) {
                accP[ni] = (f32x4){0.f,0.f,0.f,0.f};
                accS[ni] = (f32x4){0.f,0.f,0.f,0.f};
            }

#pragma unroll
            for (int kk = 0; kk < 2; ++kk) {
                s16x8 ah, al;
                unpack_frag2(vb[kk][0], vb[kk][1], &ah, &al);
#pragma unroll
                for (int ni = 0; ni < 2; ++ni) {
                    accP[ni] = __builtin_amdgcn_mfma_f32_16x16x32_bf16(ah, Bh[kk][ni], accP[ni], 0, 0, 0);
                    accS[ni] = __builtin_amdgcn_mfma_f32_16x16x32_bf16(al, Bh[kk][ni], accS[ni], 0, 0, 0);
                    accS[ni] = __builtin_amdgcn_mfma_f32_16x16x32_bf16(ah, Bl[kk][ni], accS[ni], 0, 0, 0);
                }
            }
            {
                const int off = MTF_IDX(t32 * 2 + mi, lane);
                s16x8 mh = *(const s16x8*)&MTFhi[off];
                s16x8 ml = *(const s16x8*)&MTFlo[off];
#pragma unroll
                for (int ni = 0; ni < 2; ++ni) {
                    accP[ni] = __builtin_amdgcn_mfma_f32_16x16x32_bf16(mh, Dhf[ni], accP[ni], 0, 0, 0);
                    accS[ni] = __builtin_amdgcn_mfma_f32_16x16x32_bf16(ml, Dhf[ni], accS[ni], 0, 0, 0);
                    accS[ni] = __builtin_amdgcn_mfma_f32_16x16x32_bf16(mh, Dlf[ni], accS[ni], 0, 0, 0);
                }
            }
#pragma unroll
            for (int ni = 0; ni < 2; ++ni) {
                const int o = half * 32 + ni * 16 + ln;
                f32x4 acc = accP[ni] + accS[ni];
#pragma unroll
                for (int r = 0; r < 4; ++r) {
                    const int sl32 = mi * 16 + qr * 4 + r;
                    float val = acc[r] + cbv[ni];
                    unsigned short h = f2bf(val);
                    unsigned short l = f2bf(val - bf2f(h));
                    const int a = swz2(sl32, o);
                    Vhp[a] = h;
                    Vlp[a] = l;
                }
            }
            if (mi < 1) {
                vb[0][0] = vn[0][0]; vb[0][1] = vn[0][1];
                vb[1][0] = vn[1][0]; vb[1][1] = vn[1][1];
            }
        }
    }
    __syncthreads();

    // ---- phase B: fc1 GEMM, own (br, 64-h half), 32 s-rows ----
    s16x8 Wh[2][4], Wl[2][4];
#pragma unroll
    for (int kk = 0; kk < 2; ++kk)
#pragma unroll
        for (int ni = 0; ni < 4; ++ni) {
            const int off = W1F_IDX(br, half, kk, ni) + lane * 8;
            Wh[kk][ni] = *(const s16x8*)&w1Fhi[off];
            Wl[kk][ni] = *(const s16x8*)&w1Flo[off];
        }
    float b1v[4], w2v[4];
#pragma unroll
    for (int ni = 0; ni < 4; ++ni) {
        b1v[ni] = fc1b[half * 64 + ni * 16 + ln];
        w2v[ni] = fc2w[half * 64 + ni * 16 + ln];
    }

#pragma unroll
    for (int mi = 0; mi < 2; ++mi) {
        f32x4 a1P[4], a1S[4];
#pragma unroll
        for (int ni = 0; ni < 4; ++ni) {
            a1P[ni] = (f32x4){0.f,0.f,0.f,0.f};
            a1S[ni] = (f32x4){0.f,0.f,0.f,0.f};
        }

#pragma unroll
        for (int kk = 0; kk < 2; ++kk) {
            const int blk = kk * 4 + qr;
            const int sl  = mi * 16 + ln;
            const int a   = sl * 64 + ((blk ^ (sl & 7)) << 3);
            s16x8 ah = *(const s16x8*)&Vhp[a];
            s16x8 al = *(const s16x8*)&Vlp[a];
#pragma unroll
            for (int ni = 0; ni < 4; ++ni) {
                a1P[ni] = __builtin_amdgcn_mfma_f32_16x16x32_bf16(ah, Wh[kk][ni], a1P[ni], 0, 0, 0);
                a1S[ni] = __builtin_amdgcn_mfma_f32_16x16x32_bf16(al, Wh[kk][ni], a1S[ni], 0, 0, 0);
                a1S[ni] = __builtin_amdgcn_mfma_f32_16x16x32_bf16(ah, Wl[kk][ni], a1S[ni], 0, 0, 0);
            }
        }
        float partial[4] = {0.f, 0.f, 0.f, 0.f};
#pragma unroll
        for (int ni = 0; ni < 4; ++ni) {
            f32x4 acc1 = a1P[ni] + a1S[ni];
#pragma unroll
            for (int r = 0; r < 4; ++r)
                partial[r] += gelu_f(acc1[r] + b1v[ni]) * w2v[ni];
        }
#pragma unroll
        for (int r = 0; r < 4; ++r) {
            partial[r] += __shfl_xor(partial[r], 1, 64);
            partial[r] += __shfl_xor(partial[r], 2, 64);
            partial[r] += __shfl_xor(partial[r], 4, 64);
            partial[r] += __shfl_xor(partial[r], 8, 64);
        }
        if (ln == 0) {
#pragma unroll
            for (int r = 0; r < 4; ++r)
                SP[w][mi * 16 + qr * 4 + r] = partial[r];
        }
    }
    __syncthreads();

    if (t < 32) {
        const float bias = fc2b_0[0] + fc2b_1[0];
        out[bS + s0 + t] = SP[0][t] + SP[1][t] + SP[2][t] + SP[3][t] + bias;
    }
}

// ---------------------------------------------------------------------------
extern "C" void kernel_launch(void* const* d_in, const int* in_sizes, int n_in,
                              void* d_out, int out_size, void* d_ws, size_t ws_size,
                              hipStream_t stream)
{
    const float* x = (const float*)d_in[0];
    const float* P[2][10];
    for (int br = 0; br < 2; ++br)
        for (int k = 0; k < 10; ++k)
            P[br][k] = (const float*)d_in[1 + br * 10 + k];
    // order: fc0_w, fc0_b, wave_w1, wave_w2, cw, cb, fc1_w, fc1_b, fc2_w, fc2_b

    char* p = (char*)d_ws;
    const size_t PL = (size_t)BC * SLEN * 4;   // one packed u32 plane: 16.78 MB
    unsigned int* vplane[4];                   // [br][pingpong]
    for (int i = 0; i < 4; ++i) { vplane[i] = (unsigned int*)p; p += PL; }
    unsigned short* AFhi  = (unsigned short*)p; p += 32768 * 2;
    unsigned short* AFlo  = (unsigned short*)p; p += 32768 * 2;
    unsigned short* MTFhi = (unsigned short*)p; p += 32768 * 2;
    unsigned short* MTFlo = (unsigned short*)p; p += 32768 * 2;
    float* Ppart = (float*)p;                  p += (size_t)128 * NT * 28 * 64 * 4;
    unsigned short* cwFhi = (unsigned short*)p; p += 32768 * 2;
    unsigned short* cwFlo = (unsigned short*)p; p += 32768 * 2;
    unsigned short* DFhi  = (unsigned short*)p; p += (size_t)128 * 2048 * 2;
    unsigned short* DFlo  = (unsigned short*)p; p += (size_t)128 * 2048 * 2;
    unsigned short* w1Fhi = (unsigned short*)p; p += 16384 * 2;
    unsigned short* w1Flo = (unsigned short*)p; p += 16384 * 2;
    float* axbuf          = (float*)p;          p += 66 * 28 * 4;
    float* WsT            = (float*)p;          p += (size_t)4 * 2 * 28 * 4096 * 4;

    unsigned int *v0a = vplane[0], *v0b = vplane[1];
    unsigned int *v1a = vplane[2], *v1b = vplane[3];

    setup_kernel<<<1142, 256, 0, stream>>>(
        x, AFhi, AFlo, MTFhi, MTFlo, axbuf,
        P[0][6], P[1][6], P[0][4], P[1][4],
        P[0][2], P[0][3], P[1][2], P[1][3],
        w1Fhi, w1Flo, cwFhi, cwFlo, DFhi, DFlo, WsT);

    mix0_kernel<<<448, 256, 0, stream>>>(
        axbuf, P[0][0], P[0][1], P[1][0], P[1][1],
        WsT, DFhi, DFlo);

    for (int i = 0; i < 3; ++i) {
        layer_kernel<<<2048, 128, 0, stream>>>(
            v0a, v1a, v0b, v1b,
            MTFhi, MTFlo, AFhi, AFlo, cwFhi, cwFlo, DFhi, DFlo,
            P[0][5] + (size_t)i * WCH, P[1][5] + (size_t)i * WCH,
            P[0][0], P[0][1], P[1][0], P[1][1], x,
            Ppart, i);
        unsigned int* tmp;
        tmp = v0a; v0a = v0b; v0b = tmp;
        tmp = v1a; v1a = v1b; v1b = tmp;

        mix_kernel<<<448, 256, 0, stream>>>(
            Ppart,
            WsT + (size_t)(i + 1) * 2 * 28 * 4096,
            DFhi, DFlo);
    }

    head_kernel<<<2048, 256, 0, stream>>>(
        v0a, v1a,
        MTFhi, MTFlo, cwFhi, cwFlo, DFhi, DFlo,
        P[0][5] + (size_t)3 * WCH, P[1][5] + (size_t)3 * WCH,
        w1Fhi, w1Flo,
        P[0][7], P[0][8], P[0][9],
        P[1][7], P[1][8], P[1][9],
        (float*)d_out);
}

// Round 9
// 219.397 us; speedup vs baseline: 4.2980x; 1.0149x over previous
//
#include <hip/hip_runtime.h>
#include <hip/hip_bf16.h>
#include <math.h>

// ---------------------------------------------------------------------------
// WNO1d. Round 28: fragment-ordered ACTIVATION planes (R8 confirmed the
// mechanism on operand tables: coalescing fragment reads -30us). v planes now
// stored as VF[b][tile][mi][kk][lane][8 u32] so consumer lanes read 8 packed
// channels at base+lane*32B (one 2KB coalesced wave transaction) instead of
// 16B/lane at 256B stride. Producer epilogue scatters at 32B granule (writes
// don't stall; reads do). Values bit-identical; only addresses change.
// Structure: setup, mix0, (layer, mix)x3, head-split = 9 dispatches.
// ---------------------------------------------------------------------------

#define BDIM 64
#define SLEN 1024
#define WCH  64
#define BC   (BDIM*WCH)
#define NT   16         // 64-s proj tiles per batch

typedef short s16x8 __attribute__((ext_vector_type(8)));
typedef float f32x4 __attribute__((ext_vector_type(4)));
typedef unsigned short u16x4 __attribute__((ext_vector_type(4)));

constexpr float RLv[12] = {
    0.11154074335008017f, 0.4946238903983854f, 0.7511339080215775f,
    0.3152503517092432f, -0.22626469396516913f, -0.12976686756709563f,
    0.09750160558707936f, 0.02752286553001629f, -0.031582039318031156f,
    0.0005538422009938016f, 0.004777257511010651f, -0.00107730108499558f };
constexpr float AHv[12] = {
     RLv[11], -RLv[10],  RLv[9], -RLv[8],  RLv[7], -RLv[6],
     RLv[5],  -RLv[4],   RLv[3], -RLv[2],  RLv[1], -RLv[0] };
constexpr float SLv[12] = {
     RLv[11], RLv[10], RLv[9], RLv[8], RLv[7], RLv[6],
     RLv[5],  RLv[4],  RLv[3], RLv[2], RLv[1], RLv[0] };
constexpr float SHv[12] = {
    -RLv[0],  RLv[1], -RLv[2],  RLv[3], -RLv[4],  RLv[5],
    -RLv[6],  RLv[7], -RLv[8],  RLv[9], -RLv[10], RLv[11] };

__device__ __forceinline__ float gelu_f(float x) {
    float z = 0.7978845608f * (x + 0.044715f * x * x * x);
    return x / (1.0f + __expf(-2.0f * z));
}
__device__ __forceinline__ unsigned short f2bf(float f) {
    __hip_bfloat16 h = __float2bfloat16(f);
    union { __hip_bfloat16 h; unsigned short u; } cv; cv.h = h; return cv.u;
}
__device__ __forceinline__ float bf2f(unsigned short u) {
    union { unsigned short u; __hip_bfloat16 h; } cv; cv.u = u;
    return __bfloat162float(cv.h);
}
// unpack 8 packed u32 (as two uint4) -> hi frag + lo frag (8 v_perm)
__device__ __forceinline__ void unpack_frag2(uint4 a, uint4 b,
                                             s16x8* ah, s16x8* al) {
    union { s16x8 v; unsigned int d[4]; } H, L;
    H.d[0] = __builtin_amdgcn_perm(a.y, a.x, 0x05040100u);
    H.d[1] = __builtin_amdgcn_perm(a.w, a.z, 0x05040100u);
    H.d[2] = __builtin_amdgcn_perm(b.y, b.x, 0x05040100u);
    H.d[3] = __builtin_amdgcn_perm(b.w, b.z, 0x05040100u);
    L.d[0] = __builtin_amdgcn_perm(a.y, a.x, 0x07060302u);
    L.d[1] = __builtin_amdgcn_perm(a.w, a.z, 0x07060302u);
    L.d[2] = __builtin_amdgcn_perm(b.y, b.x, 0x07060302u);
    L.d[3] = __builtin_amdgcn_perm(b.w, b.z, 0x07060302u);
    *ah = H.v; *al = L.v;
}

// swizzled [c][s] plane (64x64 shorts)
__device__ __forceinline__ int swz(int c, int s) {
    return c * 64 + ((((s >> 3) ^ (c & 7)) << 3) | (s & 7));
}
// swizzled [s][c] plane
__device__ __forceinline__ int swz2(int s, int c) {
    return s * 64 + ((((c >> 3) ^ (s & 7)) << 3) | (c & 7));
}

// fragment-table index helpers (element offsets; each frag = lane*8 shorts)
__device__ __host__ __forceinline__ int AF_IDX(int tile, int kk, int mt, int lane) {
    return (((tile * 2 + kk) * 2 + mt) * 64 + lane) * 8;
}
__device__ __host__ __forceinline__ int MTF_IDX(int row16, int lane) {
    return (row16 * 64 + lane) * 8;
}
__device__ __host__ __forceinline__ int CWF_IDX(int L, int br, int w, int kk, int ni) {
    return ((((L * 2 + br) * 2 + w) * 2 + kk) * 2 + ni) * 512;
}
__device__ __host__ __forceinline__ int DF_IDX(int bb, int w, int ni) {
    return ((bb * 2 + w) * 2 + ni) * 512;
}
__device__ __host__ __forceinline__ int W1F_IDX(int br, int half, int kk, int ni) {
    return (((br * 2 + half) * 2 + kk) * 4 + ni) * 512;
}
// fragment-ordered activation plane (u32 element offset):
// VF[b][tile][mi][kk][lane][8]; element j holds v[s=tile*64+mi*16+(lane&15)]
// [c=kk*32+(lane>>4)*8+j] packed hi|lo<<16.
__device__ __forceinline__ size_t VF_IDX(int b, int tile, int mi, int kk, int lane) {
    return ((size_t)(((b * 16 + tile) * 4 + mi) * 2 + kk) * 64 + lane) * 8;
}

// 2-wave proj: A[28 x 64-s-tile] x P[64c x 64s] -> Ppart. Wave w owns c-half.
__device__ __forceinline__ void proj2(
    const unsigned short* Phi, const unsigned short* Plo,
    const unsigned short* __restrict__ AFhi, const unsigned short* __restrict__ AFlo,
    float* __restrict__ Ppart, int bb, int tile, int t)
{
    const int lane = t & 63;
    const int w    = t >> 6;
    const int qr   = lane >> 4;
    const int ln   = lane & 15;

    s16x8 pah[2][2], pal[2][2];      // [kk][mt]
#pragma unroll
    for (int kk = 0; kk < 2; ++kk)
#pragma unroll
        for (int mt = 0; mt < 2; ++mt) {
            const int off = AF_IDX(tile, kk, mt, lane);
            pah[kk][mt] = *(const s16x8*)&AFhi[off];
            pal[kk][mt] = *(const s16x8*)&AFlo[off];
        }

    f32x4 pP[2][2], pS[2][2];
#pragma unroll
    for (int mt = 0; mt < 2; ++mt)
#pragma unroll
        for (int ni = 0; ni < 2; ++ni) {
            pP[mt][ni] = (f32x4){0.f,0.f,0.f,0.f};
            pS[mt][ni] = (f32x4){0.f,0.f,0.f,0.f};
        }

#pragma unroll
    for (int kk = 0; kk < 2; ++kk) {
        const int bk = kk * 4 + qr;
#pragma unroll
        for (int ni = 0; ni < 2; ++ni) {
            const int c = w * 32 + ni * 16 + ln;
            const int boff = c * 64 + ((bk ^ (c & 7)) << 3);
            s16x8 bh = *(const s16x8*)&Phi[boff];
            s16x8 bl = *(const s16x8*)&Plo[boff];
#pragma unroll
            for (int mt = 0; mt < 2; ++mt) {
                pP[mt][ni] = __builtin_amdgcn_mfma_f32_16x16x32_bf16(pah[kk][mt], bh, pP[mt][ni], 0, 0, 0);
                pS[mt][ni] = __builtin_amdgcn_mfma_f32_16x16x32_bf16(pal[kk][mt], bh, pS[mt][ni], 0, 0, 0);
                pS[mt][ni] = __builtin_amdgcn_mfma_f32_16x16x32_bf16(pah[kk][mt], bl, pS[mt][ni], 0, 0, 0);
            }
        }
    }
#pragma unroll
    for (int mt = 0; mt < 2; ++mt)
#pragma unroll
        for (int ni = 0; ni < 2; ++ni) {
            const int c = w * 32 + ni * 16 + ln;
            f32x4 pv = pP[mt][ni] + pS[mt][ni];
#pragma unroll
            for (int r = 0; r < 4; ++r) {
                const int xr = mt * 16 + qr * 4 + r;
                if (xr < 28)
                    Ppart[((size_t)(bb * NT + tile) * 28 + xr) * 64 + c] = pv[r];
            }
        }
}

// ---------------------------------------------------------------------------
// setup: 0..1023 A columns; 1024..1051 M rows; 1052..1117 data cascade;
//        1118..1125 weight prep; 1126..1141 WsT transpose.
// ---------------------------------------------------------------------------
__global__ __launch_bounds__(256) void setup_kernel(
    const float* __restrict__ x,
    unsigned short* __restrict__ AFhi, unsigned short* __restrict__ AFlo,
    unsigned short* __restrict__ MTFhi, unsigned short* __restrict__ MTFlo,
    float* __restrict__ axbuf,
    const float* __restrict__ fc1w_0, const float* __restrict__ fc1w_1,
    const float* __restrict__ cw_0, const float* __restrict__ cw_1,
    const float* __restrict__ w1_0, const float* __restrict__ w2_0,
    const float* __restrict__ w1_1, const float* __restrict__ w2_1,
    unsigned short* __restrict__ w1Fhi, unsigned short* __restrict__ w1Flo,
    unsigned short* __restrict__ cwFhi, unsigned short* __restrict__ cwFlo,
    unsigned short* __restrict__ DFhi,  unsigned short* __restrict__ DFlo,
    float* __restrict__ WsT)
{
    __shared__ float Af[1024];
    __shared__ float Bff[520];
    __shared__ float hib[14];
    const int t = threadIdx.x;

    if (blockIdx.x < 1024 || (blockIdx.x >= 1052 && blockIdx.x < 1118)) {
        const bool isA = (blockIdx.x < 1024);
        const int s0 = blockIdx.x;
        const int di = blockIdx.x - 1052;
        for (int i = t; i < SLEN; i += 256) {
            float v;
            if (isA)           v = (i == s0) ? 1.0f : 0.0f;
            else if (di < 64)  v = x[di * SLEN + i];
            else if (di == 64) v = (float)i * (1.0f / 1023.0f);
            else               v = 1.0f;
            Af[i] = v;
        }
        __syncthreads();

        const int NIN[8]  = {1024, 517, 264, 137, 74, 42, 26, 18};
        const int NOUT[8] = { 517, 264, 137,  74, 42, 26, 18, 14};
        // column decomposition for AF writes
        const int tile = s0 >> 6, kkc = (s0 >> 5) & 1, qrc = (s0 >> 3) & 3,
                  jc = s0 & 7;
#pragma unroll
        for (int lev = 0; lev < 8; ++lev) {
            float* in  = (lev & 1) ? Bff : Af;
            float* out = (lev & 1) ? Af : Bff;
            const int nin = NIN[lev], nout = NOUT[lev];
            for (int m = t; m < nout; m += 256) {
                float alo = 0.f, ahi = 0.f;
#pragma unroll
                for (int tt = 0; tt < 12; ++tt) {
                    int jj = 2 * m + tt - 10;
                    if (jj < 0)         jj = -1 - jj;
                    else if (jj >= nin) jj = 2 * nin - 1 - jj;
                    float xv = in[jj];
                    alo += xv * RLv[tt];
                    if (lev == 7) ahi += xv * AHv[tt];
                }
                out[m] = alo;
                if (lev == 7) {
                    if (isA) {
                        unsigned short h1 = f2bf(alo);
                        unsigned short l1 = f2bf(alo - bf2f(h1));
                        {   // row m (0..13)
                            const int lane = qrc * 16 + (m & 15);
                            const int off = AF_IDX(tile, kkc, m >> 4, lane) + jc;
                            AFhi[off] = h1; AFlo[off] = l1;
                        }
                        unsigned short h2 = f2bf(ahi);
                        unsigned short l2 = f2bf(ahi - bf2f(h2));
                        {   // row 14+m
                            const int row = 14 + m;
                            const int lane = qrc * 16 + (row & 15);
                            const int off = AF_IDX(tile, kkc, row >> 4, lane) + jc;
                            AFhi[off] = h2; AFlo[off] = l2;
                        }
                    } else {
                        axbuf[di * 28 + m]      = alo;
                        axbuf[di * 28 + 14 + m] = ahi;
                    }
                }
            }
            __syncthreads();
        }
        if (isA && t < 4) {
            {   // A pad rows 28..31 at column s0
                const int row = 28 + t;
                const int lane = qrc * 16 + (row & 15);
                const int off = AF_IDX(tile, kkc, 1, lane) + jc;
                AFhi[off] = 0; AFlo[off] = 0;
            }
            {   // MT pad cols 28..31 at row s0
                const int col = 28 + t;
                const int lane = (col >> 3) * 16 + (s0 & 15);
                const int off = MTF_IDX(s0 >> 4, lane) + (col & 7);
                MTFhi[off] = 0; MTFlo[off] = 0;
            }
        }
        return;
    }

    if (blockIdx.x >= 1126) {
        // WsT: [(L*2+br)*28 + x][i*64+o]
        const int wsb = blockIdx.x - 1126;       // 0..15
        const int L = wsb >> 2, br = (wsb >> 1) & 1, which = wsb & 1;
        const float* src = (which ? (br ? w2_1 : w2_0) : (br ? w1_1 : w1_0))
                         + (size_t)L * 64 * 64 * 14;
        const size_t dbase = ((size_t)(L * 2 + br) * 28 + which * 14) * 4096;
        for (int e = t; e < 4096; e += 256) {
            const float* sp = src + (size_t)e * 14;
            float v[14];
#pragma unroll
            for (int xi = 0; xi < 14; ++xi) v[xi] = sp[xi];
#pragma unroll
            for (int xi = 0; xi < 14; ++xi)
                WsT[dbase + (size_t)xi * 4096 + e] = v[xi];
        }
        return;
    }

    if (blockIdx.x >= 1118) {
        // weight prep (fragment-order outputs)
        const int gid = (blockIdx.x - 1118) * 256 + t;
        for (int idx = gid; idx < 16384; idx += 2048) {
            int br = idx >> 13, r = idx & 8191;
            int h = r >> 6, c = r & 63;
            float f = (br ? fc1w_1 : fc1w_0)[c * 128 + h];
            unsigned short hh = f2bf(f);
            const int half = (h >> 6) & 1, ni = (h >> 4) & 3, lnh = h & 15;
            const int kk = c >> 5, qr = (c >> 3) & 3, j = c & 7;
            const int off = W1F_IDX(br, half, kk, ni) + (qr * 16 + lnh) * 8 + j;
            w1Fhi[off] = hh;
            w1Flo[off] = f2bf(f - bf2f(hh));
        }
        for (int idx = gid; idx < 32768; idx += 2048) {   // cwT split, all layers
            int L = idx >> 13, br = (idx >> 12) & 1, e = idx & 4095;
            int k = e >> 6, o = e & 63;
            float val = (br ? cw_1 : cw_0)[(size_t)L * 4096 + o * 64 + k]
                      + ((k == o) ? 1.0f : 0.0f);
            unsigned short h = f2bf(val);
            const int w = o >> 5, ni = (o >> 4) & 1, lno = o & 15;
            const int kk = k >> 5, qr = (k >> 3) & 3, j = k & 7;
            const int off = CWF_IDX(L, br, w, kk, ni) + (qr * 16 + lno) * 8 + j;
            cwFhi[off] = h;
            cwFlo[off] = f2bf(val - bf2f(h));
        }
        for (int idx = gid; idx < 32768; idx += 2048) {   // D pad x=28..31
            int bb = idx >> 8, o = (idx >> 2) & 63, j3 = idx & 3;
            const int x = 28 + j3;
            const int w = o >> 5, ni = (o >> 4) & 1, lno = o & 15;
            const int off = DF_IDX(bb, w, ni) + ((x >> 3) * 16 + lno) * 8 + (x & 7);
            DFhi[off] = 0;
            DFlo[off] = 0;
        }
        return;
    }

    // synthesis rows (M^T) -> MTF fragment order
    const int u = blockIdx.x - 1024;     // 0..27
    if (t < 14) {
        Af[t]  = (u < 14 && t == u) ? 1.0f : 0.0f;
        hib[t] = (u >= 14 && t == (u - 14)) ? 1.0f : 0.0f;
    }
    __syncthreads();

    const int NH[8] = {14, 18, 26, 42, 74, 137, 264, 517};
    const int NO[8] = {18, 26, 42, 74, 138, 264, 518, 1024};

#pragma unroll
    for (int s = 0; s < 8; ++s) {
        const float* lo = (s & 1) ? Bff : Af;
        float* out      = (s & 1) ? Af : Bff;
        const int N = NH[s], nout = NO[s];
        for (int m = t; m < nout; m += 256) {
            float acc = 0.f;
#pragma unroll
            for (int tt = 0; tt < 12; ++tt) {
                int uu = m + tt - 1;
                if ((uu & 1) == 0) {
                    int q = uu >> 1;
                    if (q < N) {
                        acc += lo[q] * SLv[tt];
                        if (s == 0) acc += hib[q] * SHv[tt];
                    }
                }
            }
            out[m] = acc;
        }
        __syncthreads();
    }
    {
        const int qr = u >> 3, j = u & 7;
        for (int m = t; m < SLEN; m += 256) {
            float f = Af[m];
            unsigned short h = f2bf(f);
            const int off = MTF_IDX(m >> 4, qr * 16 + (m & 15)) + j;
            MTFhi[off] = h;
            MTFlo[off] = f2bf(f - bf2f(h));
        }
    }
}

// ---------------------------------------------------------------------------
// mix0: layer-0 mix from rank-3 formula; writes DF in fragment order.
// ---------------------------------------------------------------------------
__global__ __launch_bounds__(256) void mix0_kernel(
    const float* __restrict__ axbuf,
    const float* __restrict__ fc0w_0, const float* __restrict__ fc0b_0,
    const float* __restrict__ fc0w_1, const float* __restrict__ fc0b_1,
    const float* __restrict__ WsT0,
    unsigned short* __restrict__ DFhi, unsigned short* __restrict__ DFlo)
{
    const int t = threadIdx.x;
    const int br  = blockIdx.x / 224;
    const int sub = blockIdx.x % 224;

    __shared__ float Ws[64][65];
    __shared__ float LO[8][64];
    const int o = t & 63;
    const int w = t >> 6;
    const int x  = sub >> 3;
    const int b0 = (sub & 7) << 3;

    const float* wsrc = WsT0 + ((size_t)(br * 28 + x)) * 4096;
    for (int idx = t; idx < 4096; idx += 256)
        Ws[idx >> 6][idx & 63] = wsrc[idx];

    const float* fc0w = br ? fc0w_1 : fc0w_0;
    const float* fc0b = br ? fc0b_1 : fc0b_0;
    const float agv = axbuf[64 * 28 + x];
    const float a1v = axbuf[65 * 28 + x];
    const float w0o = fc0w[o];
    const float wgo = fc0w[WCH + o];
    const float b0o = fc0b[o];

#pragma unroll
    for (int j = 0; j < 2; ++j) {
        int bi = w + 4 * j;
        int b  = b0 + bi;
        float axv = axbuf[b * 28 + x];
        LO[bi][o] = axv * w0o + agv * wgo + a1v * b0o;
    }
    __syncthreads();

    const int wo = o >> 5, nio = (o >> 4) & 1, lno = o & 15;
    const int dsub = ((x >> 3) * 16 + lno) * 8 + (x & 7);
#pragma unroll
    for (int j = 0; j < 2; ++j) {
        int bi = w + 4 * j;
        int bb = br * 64 + b0 + bi;
        float acc = 0.f;
        for (int i = 0; i < 64; ++i)
            acc += LO[bi][i] * Ws[i][o];
        acc -= LO[bi][o];
        unsigned short h = f2bf(acc);
        const int off = DF_IDX(bb, wo, nio) + dsub;
        DFhi[off] = h;
        DFlo[off] = f2bf(acc - bf2f(h));
    }
}

// ---------------------------------------------------------------------------
// Mix (layers 1..3): reads Ppart; writes DF in fragment order.
// ---------------------------------------------------------------------------
__global__ __launch_bounds__(256) void mix_kernel(
    const float* __restrict__ Ppart,
    const float* __restrict__ WsTL,
    unsigned short* __restrict__ DFhi, unsigned short* __restrict__ DFlo)
{
    const int t = threadIdx.x;
    const int br  = blockIdx.x / 224;
    const int sub = blockIdx.x % 224;

    __shared__ float Ws[64][65];
    __shared__ float LO[8][64];
    const int o = t & 63;
    const int w = t >> 6;
    const int x  = sub >> 3;
    const int b0 = (sub & 7) << 3;

    const float* wsrc = WsTL + ((size_t)(br * 28 + x)) * 4096;
    for (int idx = t; idx < 4096; idx += 256)
        Ws[idx >> 6][idx & 63] = wsrc[idx];

#pragma unroll
    for (int j = 0; j < 2; ++j) {
        int bi = w + 4 * j;
        int bb = br * 64 + b0 + bi;
        float s = 0.f;
        for (int tile = 0; tile < NT; ++tile)
            s += Ppart[((size_t)(bb * NT + tile) * 28 + x) * 64 + o];
        LO[bi][o] = s;
    }
    __syncthreads();

    const int wo = o >> 5, nio = (o >> 4) & 1, lno = o & 15;
    const int dsub = ((x >> 3) * 16 + lno) * 8 + (x & 7);
#pragma unroll
    for (int j = 0; j < 2; ++j) {
        int bi = w + 4 * j;
        int bb = br * 64 + b0 + bi;
        float acc = 0.f;
        for (int i = 0; i < 64; ++i)
            acc += LO[bi][i] * Ws[i][o];
        acc -= LO[bi][o];
        unsigned short h = f2bf(acc);
        const int off = DF_IDX(bb, wo, nio) + dsub;
        DFhi[off] = h;
        DFlo[off] = f2bf(acc - bf2f(h));
    }
}

// ---------------------------------------------------------------------------
// Fused layer (i = 0,1,2): 2048 blocks x 128 thr, 2 waves per 64-s tile.
// All operand-fragment AND activation loads coalesced. No barriers.
// ---------------------------------------------------------------------------
__global__ __launch_bounds__(128, 3) void layer_kernel(
    const unsigned int* __restrict__ vin0, const unsigned int* __restrict__ vin1,
    unsigned int* __restrict__ vout0, unsigned int* __restrict__ vout1,
    const unsigned short* __restrict__ MTFhi, const unsigned short* __restrict__ MTFlo,
    const unsigned short* __restrict__ AFhi,  const unsigned short* __restrict__ AFlo,
    const unsigned short* __restrict__ cwFhi, const unsigned short* __restrict__ cwFlo,
    const unsigned short* __restrict__ DFhi,   const unsigned short* __restrict__ DFlo,
    const float* __restrict__ cb_0, const float* __restrict__ cb_1,
    const float* __restrict__ fc0w_0, const float* __restrict__ fc0b_0,
    const float* __restrict__ fc0w_1, const float* __restrict__ fc0b_1,
    const float* __restrict__ xin,
    float* __restrict__ Ppart, int Lidx)
{
    __shared__ unsigned short Phi[4096];   // block-shared swizzled [c][s64]
    __shared__ unsigned short Plo[4096];

    const int t = threadIdx.x;
    const int bid = blockIdx.x;
    const int br  = bid >> 10;
    const int rem = bid & 1023;
    const int b    = rem >> 4;
    const int tile = rem & 15;
    const int s0   = tile << 6;
    const size_t bS = (size_t)b * SLEN;
    const unsigned int* vin = br ? vin1 : vin0;
    unsigned int* vout      = br ? vout1 : vout0;
    const float* cb = br ? cb_1 : cb_0;
    const float* f0w = br ? fc0w_1 : fc0w_0;
    const float* f0b = br ? fc0b_1 : fc0b_0;
    const int bb = br * 64 + b;

    const int lane = t & 63;
    const int w    = t >> 6;          // 0..1: o-half
    const int qr   = lane >> 4;
    const int ln   = lane & 15;

    // ---- preload B fragments (coalesced: base + lane*16B) ----
    s16x8 Bh[2][2], Bl[2][2];
#pragma unroll
    for (int kk = 0; kk < 2; ++kk)
#pragma unroll
        for (int ni = 0; ni < 2; ++ni) {
            const int off = CWF_IDX(Lidx, br, w, kk, ni) + lane * 8;
            Bh[kk][ni] = *(const s16x8*)&cwFhi[off];
            Bl[kk][ni] = *(const s16x8*)&cwFlo[off];
        }
    s16x8 Dhf[2], Dlf[2];
#pragma unroll
    for (int ni = 0; ni < 2; ++ni) {
        const int off = DF_IDX(bb, w, ni) + lane * 8;
        Dhf[ni] = *(const s16x8*)&DFhi[off];
        Dlf[ni] = *(const s16x8*)&DFlo[off];
    }
    float cbv[2];
#pragma unroll
    for (int ni = 0; ni < 2; ++ni) cbv[ni] = cb[w * 32 + ni * 16 + ln];

    // ---- prefetch vin (or x) for mi=0 (VF: base + lane*32B, coalesced) ----
    uint4 vb[2][2];                 // [kk][half]
    float xpf = 0.f;
    if (Lidx == 0) {
        xpf = xin[bS + s0 + ln];
    } else {
#pragma unroll
        for (int kk = 0; kk < 2; ++kk) {
            const size_t a0 = VF_IDX(b, tile, 0, kk, lane);
            vb[kk][0] = *(const uint4*)&vin[a0];
            vb[kk][1] = *(const uint4*)&vin[a0 + 4];
        }
    }

    // ---- 4 m-tiles ----
#pragma unroll
    for (int mi = 0; mi < 4; ++mi) {
        const int srow = mi * 16 + ln;
        uint4 vn[2][2];
        float xnf = 0.f;
        if (mi < 3) {
            if (Lidx == 0) {
                xnf = xin[bS + s0 + (mi + 1) * 16 + ln];
            } else {
#pragma unroll
                for (int kk = 0; kk < 2; ++kk) {
                    const size_t an = VF_IDX(b, tile, mi + 1, kk, lane);
                    vn[kk][0] = *(const uint4*)&vin[an];
                    vn[kk][1] = *(const uint4*)&vin[an + 4];
                }
            }
        }

        f32x4 accP[2], accS[2];
#pragma unroll
        for (int ni = 0; ni < 2; ++ni) {
            accP[ni] = (f32x4){0.f,0.f,0.f,0.f};
            accS[ni] = (f32x4){0.f,0.f,0.f,0.f};
        }

#pragma unroll
        for (int kk = 0; kk < 2; ++kk) {
            s16x8 ah, al;
            if (Lidx == 0) {
                const int s = s0 + srow;
                const float gv = (float)s * (1.0f / 1023.0f);
#pragma unroll
                for (int j = 0; j < 8; ++j) {
                    const int c = kk * 32 + qr * 8 + j;
                    float val = xpf * f0w[c] + gv * f0w[WCH + c] + f0b[c];
                    unsigned short h = f2bf(val);
                    ah[j] = (short)h;
                    al[j] = (short)f2bf(val - bf2f(h));
                }
            } else {
                unpack_frag2(vb[kk][0], vb[kk][1], &ah, &al);
            }
#pragma unroll
            for (int ni = 0; ni < 2; ++ni) {
                accP[ni] = __builtin_amdgcn_mfma_f32_16x16x32_bf16(ah, Bh[kk][ni], accP[ni], 0, 0, 0);
                accS[ni] = __builtin_amdgcn_mfma_f32_16x16x32_bf16(al, Bh[kk][ni], accS[ni], 0, 0, 0);
                accS[ni] = __builtin_amdgcn_mfma_f32_16x16x32_bf16(ah, Bl[kk][ni], accS[ni], 0, 0, 0);
            }
        }
        {
            const int off = MTF_IDX((s0 >> 4) + mi, lane);
            s16x8 mh = *(const s16x8*)&MTFhi[off];
            s16x8 ml = *(const s16x8*)&MTFlo[off];
#pragma unroll
            for (int ni = 0; ni < 2; ++ni) {
                accP[ni] = __builtin_amdgcn_mfma_f32_16x16x32_bf16(mh, Dhf[ni], accP[ni], 0, 0, 0);
                accS[ni] = __builtin_amdgcn_mfma_f32_16x16x32_bf16(ml, Dhf[ni], accS[ni], 0, 0, 0);
                accS[ni] = __builtin_amdgcn_mfma_f32_16x16x32_bf16(mh, Dlf[ni], accS[ni], 0, 0, 0);
            }
        }
        // epilogue: gelu, split, VF-order global store + packed b64 LDS writes
#pragma unroll
        for (int ni = 0; ni < 2; ++ni) {
            const int o = w * 32 + ni * 16 + ln;
            f32x4 acc = accP[ni] + accS[ni];
            u16x4 hv, lv;
            // consumer-fragment coords for channel o: kk'=w, lane' varies by r
            const int lgrp = (ni * 2 + (ln >> 3)) * 16;   // lane' base
            const int jj = ln & 7;
#pragma unroll
            for (int r = 0; r < 4; ++r) {
                float val = gelu_f(acc[r] + cbv[ni]);
                unsigned short h = f2bf(val);
                unsigned short l = f2bf(val - bf2f(h));
                vout[VF_IDX(b, tile, mi, w, lgrp + qr * 4 + r) + jj] =
                    (unsigned int)h | ((unsigned int)l << 16);
                hv[r] = h;
                lv[r] = l;
            }
            const int a = swz(o, mi * 16 + qr * 4);
            *(u16x4*)&Phi[a] = hv;
            *(u16x4*)&Plo[a] = lv;
        }
        if (mi < 3) {
            if (Lidx == 0) {
                xpf = xnf;
            } else {
#pragma unroll
                for (int kk = 0; kk < 2; ++kk) {
                    vb[kk][0] = vn[kk][0]; vb[kk][1] = vn[kk][1];
                }
            }
        }
    }

    // ---- proj on own c-half (same-wave LDS RAW: no barrier needed) ----
    proj2(Phi, Plo, AFhi, AFlo, Ppart, bb, tile, t);
}

// ---------------------------------------------------------------------------
// Head with fused layer 3, BOTH branches, 32-s blocks: 2048 blocks x 256 thr
// (4 waves = {br}x{o-half}). All fragment + activation loads coalesced.
// ---------------------------------------------------------------------------
__global__ __launch_bounds__(256, 2) void head_kernel(
    const unsigned int* __restrict__ vin0, const unsigned int* __restrict__ vin1,
    const unsigned short* __restrict__ MTFhi, const unsigned short* __restrict__ MTFlo,
    const unsigned short* __restrict__ cwFhi, const unsigned short* __restrict__ cwFlo,
    const unsigned short* __restrict__ DFhi,   const unsigned short* __restrict__ DFlo,
    const float* __restrict__ cb_0, const float* __restrict__ cb_1,
    const unsigned short* __restrict__ w1Fhi, const unsigned short* __restrict__ w1Flo,
    const float* __restrict__ fc1b_0, const float* __restrict__ fc2w_0,
    const float* __restrict__ fc2b_0,
    const float* __restrict__ fc1b_1, const float* __restrict__ fc2w_1,
    const float* __restrict__ fc2b_1,
    float* __restrict__ out)
{
    __shared__ unsigned short Vh[4096];    // [br][swz2 32x64 plane]
    __shared__ unsigned short Vl[4096];
    __shared__ float SP[4][32];            // per-wave partials

    const int t = threadIdx.x;
    const int bid = blockIdx.x;            // 0..2047
    const int b    = bid >> 5;
    const int t32  = bid & 31;
    const int s0   = t32 << 5;
    const size_t bS = (size_t)b * SLEN;
    const int tile64 = t32 >> 1;           // VF tile
    const int mibase = (t32 & 1) * 2;      // VF mi base

    const int lane = t & 63;
    const int w    = t >> 6;          // 0..3
    const int br   = w >> 1;
    const int half = w & 1;
    const int qr   = lane >> 4;
    const int ln   = lane & 15;

    const unsigned int* vin = br ? vin1 : vin0;
    const float* cb   = (br ? cb_1 : cb_0) + 3 * WCH;
    const float* fc1b = br ? fc1b_1 : fc1b_0;
    const float* fc2w = br ? fc2w_1 : fc2w_0;
    const int bb = br * 64 + b;
    unsigned short* Vhp = Vh + br * 2048;
    unsigned short* Vlp = Vl + br * 2048;

    // ---- phase A: layer-3, own (br, 32-o half), 32 s-rows ----
    {
        s16x8 Bh[2][2], Bl[2][2];
#pragma unroll
        for (int kk = 0; kk < 2; ++kk)
#pragma unroll
            for (int ni = 0; ni < 2; ++ni) {
                const int off = CWF_IDX(3, br, half, kk, ni) + lane * 8;
                Bh[kk][ni] = *(const s16x8*)&cwFhi[off];
                Bl[kk][ni] = *(const s16x8*)&cwFlo[off];
            }
        s16x8 Dhf[2], Dlf[2];
#pragma unroll
        for (int ni = 0; ni < 2; ++ni) {
            const int off = DF_IDX(bb, half, ni) + lane * 8;
            Dhf[ni] = *(const s16x8*)&DFhi[off];
            Dlf[ni] = *(const s16x8*)&DFlo[off];
        }
        float cbv[2];
#pragma unroll
        for (int ni = 0; ni < 2; ++ni) cbv[ni] = cb[half * 32 + ni * 16 + ln];

        uint4 vb[2][2];
#pragma unroll
        for (int kk = 0; kk < 2; ++kk) {
            const size_t a0 = VF_IDX(b, tile64, mibase, kk, lane);
            vb[kk][0] = *(const uint4*)&vin[a0];
            vb[kk][1] = *(const uint4*)&vin[a0 + 4];
        }

#pragma unroll
        for (int mi = 0; mi < 2; ++mi) {
            uint4 vn[2][2];
            if (mi < 1) {
#pragma unroll
                for (int kk = 0; kk < 2; ++kk) {
                    const size_t an = VF_IDX(b, tile64, mibase + 1, kk, lane);
                    vn[kk][0] = *(const uint4*)&vin[an];
                    vn[kk][1] = *(const uint4*)&vin[an + 4];
                }
            }
            f32x4 accP[2], accS[2];
#pragma unroll
            for (int ni = 0; ni < 2; ++ni) {
                accP[ni] = (f32x4){0.f,0.f,0.f,0.f};
                accS[ni] = (f32x4){0.f,0.f,0.f,0.f};
            }

#pragma unroll
            for (int kk = 0; kk < 2; ++kk) {
                s16x8 ah, al;
                unpack_frag2(vb[kk][0], vb[kk][1], &ah, &al);
#pragma unroll
                for (int ni = 0; ni < 2; ++ni) {
                    accP[ni] = __builtin_amdgcn_mfma_f32_16x16x32_bf16(ah, Bh[kk][ni], accP[ni], 0, 0, 0);
                    accS[ni] = __builtin_amdgcn_mfma_f32_16x16x32_bf16(al, Bh[kk][ni], accS[ni], 0, 0, 0);
                    accS[ni] = __builtin_amdgcn_mfma_f32_16x16x32_bf16(ah, Bl[kk][ni], accS[ni], 0, 0, 0);
                }
            }
            {
                const int off = MTF_IDX(t32 * 2 + mi, lane);
                s16x8 mh = *(const s16x8*)&MTFhi[off];
                s16x8 ml = *(const s16x8*)&MTFlo[off];
#pragma unroll
                for (int ni = 0; ni < 2; ++ni) {
                    accP[ni] = __builtin_amdgcn_mfma_f32_16x16x32_bf16(mh, Dhf[ni], accP[ni], 0, 0, 0);
                    accS[ni] = __builtin_amdgcn_mfma_f32_16x16x32_bf16(ml, Dhf[ni], accS[ni], 0, 0, 0);
                    accS[ni] = __builtin_amdgcn_mfma_f32_16x16x32_bf16(mh, Dlf[ni], accS[ni], 0, 0, 0);
                }
            }
#pragma unroll
            for (int ni = 0; ni < 2; ++ni) {
                const int o = half * 32 + ni * 16 + ln;
                f32x4 acc = accP[ni] + accS[ni];
#pragma unroll
                for (int r = 0; r < 4; ++r) {
                    const int sl32 = mi * 16 + qr * 4 + r;
                    float val = acc[r] + cbv[ni];
                    unsigned short h = f2bf(val);
                    unsigned short l = f2bf(val - bf2f(h));
                    const int a = swz2(sl32, o);
                    Vhp[a] = h;
                    Vlp[a] = l;
                }
            }
            if (mi < 1) {
#pragma unroll
                for (int kk = 0; kk < 2; ++kk) {
                    vb[kk][0] = vn[kk][0]; vb[kk][1] = vn[kk][1];
                }
            }
        }
    }
    __syncthreads();

    // ---- phase B: fc1 GEMM, own (br, 64-h half), 32 s-rows ----
    s16x8 Wh[2][4], Wl[2][4];
#pragma unroll
    for (int kk = 0; kk < 2; ++kk)
#pragma unroll
        for (int ni = 0; ni < 4; ++ni) {
            const int off = W1F_IDX(br, half, kk, ni) + lane * 8;
            Wh[kk][ni] = *(const s16x8*)&w1Fhi[off];
            Wl[kk][ni] = *(const s16x8*)&w1Flo[off];
        }
    float b1v[4], w2v[4];
#pragma unroll
    for (int ni = 0; ni < 4; ++ni) {
        b1v[ni] = fc1b[half * 64 + ni * 16 + ln];
        w2v[ni] = fc2w[half * 64 + ni * 16 + ln];
    }

#pragma unroll
    for (int mi = 0; mi < 2; ++mi) {
        f32x4 a1P[4], a1S[4];
#pragma unroll
        for (int ni = 0; ni < 4; ++ni) {
            a1P[ni] = (f32x4){0.f,0.f,0.f,0.f};
            a1S[ni] = (f32x4){0.f,0.f,0.f,0.f};
        }

#pragma unroll
        for (int kk = 0; kk < 2; ++kk) {
            const int blk = kk * 4 + qr;
            const int sl  = mi * 16 + ln;
            const int a   = sl * 64 + ((blk ^ (sl & 7)) << 3);
            s16x8 ah = *(const s16x8*)&Vhp[a];
            s16x8 al = *(const s16x8*)&Vlp[a];
#pragma unroll
            for (int ni = 0; ni < 4; ++ni) {
                a1P[ni] = __builtin_amdgcn_mfma_f32_16x16x32_bf16(ah, Wh[kk][ni], a1P[ni], 0, 0, 0);
                a1S[ni] = __builtin_amdgcn_mfma_f32_16x16x32_bf16(al, Wh[kk][ni], a1S[ni], 0, 0, 0);
                a1S[ni] = __builtin_amdgcn_mfma_f32_16x16x32_bf16(ah, Wl[kk][ni], a1S[ni], 0, 0, 0);
            }
        }
        float partial[4] = {0.f, 0.f, 0.f, 0.f};
#pragma unroll
        for (int ni = 0; ni < 4; ++ni) {
            f32x4 acc1 = a1P[ni] + a1S[ni];
#pragma unroll
            for (int r = 0; r < 4; ++r)
                partial[r] += gelu_f(acc1[r] + b1v[ni]) * w2v[ni];
        }
#pragma unroll
        for (int r = 0; r < 4; ++r) {
            partial[r] += __shfl_xor(partial[r], 1, 64);
            partial[r] += __shfl_xor(partial[r], 2, 64);
            partial[r] += __shfl_xor(partial[r], 4, 64);
            partial[r] += __shfl_xor(partial[r], 8, 64);
        }
        if (ln == 0) {
#pragma unroll
            for (int r = 0; r < 4; ++r)
                SP[w][mi * 16 + qr * 4 + r] = partial[r];
        }
    }
    __syncthreads();

    if (t < 32) {
        const float bias = fc2b_0[0] + fc2b_1[0];
        out[bS + s0 + t] = SP[0][t] + SP[1][t] + SP[2][t] + SP[3][t] + bias;
    }
}

// ---------------------------------------------------------------------------
extern "C" void kernel_launch(void* const* d_in, const int* in_sizes, int n_in,
                              void* d_out, int out_size, void* d_ws, size_t ws_size,
                              hipStream_t stream)
{
    const float* x = (const float*)d_in[0];
    const float* P[2][10];
    for (int br = 0; br < 2; ++br)
        for (int k = 0; k < 10; ++k)
            P[br][k] = (const float*)d_in[1 + br * 10 + k];
    // order: fc0_w, fc0_b, wave_w1, wave_w2, cw, cb, fc1_w, fc1_b, fc2_w, fc2_b

    char* p = (char*)d_ws;
    const size_t PL = (size_t)BC * SLEN * 4;   // one packed u32 plane: 16.78 MB
    unsigned int* vplane[4];                   // [br][pingpong]
    for (int i = 0; i < 4; ++i) { vplane[i] = (unsigned int*)p; p += PL; }
    unsigned short* AFhi  = (unsigned short*)p; p += 32768 * 2;
    unsigned short* AFlo  = (unsigned short*)p; p += 32768 * 2;
    unsigned short* MTFhi = (unsigned short*)p; p += 32768 * 2;
    unsigned short* MTFlo = (unsigned short*)p; p += 32768 * 2;
    float* Ppart = (float*)p;                  p += (size_t)128 * NT * 28 * 64 * 4;
    unsigned short* cwFhi = (unsigned short*)p; p += 32768 * 2;
    unsigned short* cwFlo = (unsigned short*)p; p += 32768 * 2;
    unsigned short* DFhi  = (unsigned short*)p; p += (size_t)128 * 2048 * 2;
    unsigned short* DFlo  = (unsigned short*)p; p += (size_t)128 * 2048 * 2;
    unsigned short* w1Fhi = (unsigned short*)p; p += 16384 * 2;
    unsigned short* w1Flo = (unsigned short*)p; p += 16384 * 2;
    float* axbuf          = (float*)p;          p += 66 * 28 * 4;
    float* WsT            = (float*)p;          p += (size_t)4 * 2 * 28 * 4096 * 4;

    unsigned int *v0a = vplane[0], *v0b = vplane[1];
    unsigned int *v1a = vplane[2], *v1b = vplane[3];

    setup_kernel<<<1142, 256, 0, stream>>>(
        x, AFhi, AFlo, MTFhi, MTFlo, axbuf,
        P[0][6], P[1][6], P[0][4], P[1][4],
        P[0][2], P[0][3], P[1][2], P[1][3],
        w1Fhi, w1Flo, cwFhi, cwFlo, DFhi, DFlo, WsT);

    mix0_kernel<<<448, 256, 0, stream>>>(
        axbuf, P[0][0], P[0][1], P[1][0], P[1][1],
        WsT, DFhi, DFlo);

    for (int i = 0; i < 3; ++i) {
        layer_kernel<<<2048, 128, 0, stream>>>(
            v0a, v1a, v0b, v1b,
            MTFhi, MTFlo, AFhi, AFlo, cwFhi, cwFlo, DFhi, DFlo,
            P[0][5] + (size_t)i * WCH, P[1][5] + (size_t)i * WCH,
            P[0][0], P[0][1], P[1][0], P[1][1], x,
            Ppart, i);
        unsigned int* tmp;
        tmp = v0a; v0a = v0b; v0b = tmp;
        tmp = v1a; v1a = v1b; v1b = tmp;

        mix_kernel<<<448, 256, 0, stream>>>(
            Ppart,
            WsT + (size_t)(i + 1) * 2 * 28 * 4096,
            DFhi, DFlo);
    }

    head_kernel<<<2048, 256, 0, stream>>>(
        v0a, v1a,
        MTFhi, MTFlo, cwFhi, cwFlo, DFhi, DFlo,
        P[0][5] + (size_t)3 * WCH, P[1][5] + (size_t)3 * WCH,
        w1Fhi, w1Flo,
        P[0][7], P[0][8], P[0][9],
        P[1][7], P[1][8], P[1][9],
        (float*)d_out);
}

// Round 10
// 218.641 us; speedup vs baseline: 4.3128x; 1.0035x over previous
//
#include <hip/hip_runtime.h>
#include <hip/hip_bf16.h>
#include <math.h>

// ---------------------------------------------------------------------------
// WNO1d. Round 29: parallelize setup's serial tail. The WsT transpose ran on
// 16 blocks (16/256 CUs busy) issuing 56B-stride gathers over cold params
// (~20-30us hidden under the 43us fill ceiling); weight prep ran on 8 blocks.
// Remap: weight prep 8 -> 256 blocks, WsT 16 -> 256 blocks (one 14-float
// vector slice per thread). Setup grid 1142 -> 1630. All math byte-identical
// to R28 (219us). Structure: setup, mix0, (layer, mix)x3, head = 9 dispatches.
// ---------------------------------------------------------------------------

#define BDIM 64
#define SLEN 1024
#define WCH  64
#define BC   (BDIM*WCH)
#define NT   16         // 64-s proj tiles per batch

typedef short s16x8 __attribute__((ext_vector_type(8)));
typedef float f32x4 __attribute__((ext_vector_type(4)));
typedef unsigned short u16x4 __attribute__((ext_vector_type(4)));

constexpr float RLv[12] = {
    0.11154074335008017f, 0.4946238903983854f, 0.7511339080215775f,
    0.3152503517092432f, -0.22626469396516913f, -0.12976686756709563f,
    0.09750160558707936f, 0.02752286553001629f, -0.031582039318031156f,
    0.0005538422009938016f, 0.004777257511010651f, -0.00107730108499558f };
constexpr float AHv[12] = {
     RLv[11], -RLv[10],  RLv[9], -RLv[8],  RLv[7], -RLv[6],
     RLv[5],  -RLv[4],   RLv[3], -RLv[2],  RLv[1], -RLv[0] };
constexpr float SLv[12] = {
     RLv[11], RLv[10], RLv[9], RLv[8], RLv[7], RLv[6],
     RLv[5],  RLv[4],  RLv[3], RLv[2], RLv[1], RLv[0] };
constexpr float SHv[12] = {
    -RLv[0],  RLv[1], -RLv[2],  RLv[3], -RLv[4],  RLv[5],
    -RLv[6],  RLv[7], -RLv[8],  RLv[9], -RLv[10], RLv[11] };

__device__ __forceinline__ float gelu_f(float x) {
    float z = 0.7978845608f * (x + 0.044715f * x * x * x);
    return x / (1.0f + __expf(-2.0f * z));
}
__device__ __forceinline__ unsigned short f2bf(float f) {
    __hip_bfloat16 h = __float2bfloat16(f);
    union { __hip_bfloat16 h; unsigned short u; } cv; cv.h = h; return cv.u;
}
__device__ __forceinline__ float bf2f(unsigned short u) {
    union { unsigned short u; __hip_bfloat16 h; } cv; cv.u = u;
    return __bfloat162float(cv.h);
}
// unpack 8 packed u32 (as two uint4) -> hi frag + lo frag (8 v_perm)
__device__ __forceinline__ void unpack_frag2(uint4 a, uint4 b,
                                             s16x8* ah, s16x8* al) {
    union { s16x8 v; unsigned int d[4]; } H, L;
    H.d[0] = __builtin_amdgcn_perm(a.y, a.x, 0x05040100u);
    H.d[1] = __builtin_amdgcn_perm(a.w, a.z, 0x05040100u);
    H.d[2] = __builtin_amdgcn_perm(b.y, b.x, 0x05040100u);
    H.d[3] = __builtin_amdgcn_perm(b.w, b.z, 0x05040100u);
    L.d[0] = __builtin_amdgcn_perm(a.y, a.x, 0x07060302u);
    L.d[1] = __builtin_amdgcn_perm(a.w, a.z, 0x07060302u);
    L.d[2] = __builtin_amdgcn_perm(b.y, b.x, 0x07060302u);
    L.d[3] = __builtin_amdgcn_perm(b.w, b.z, 0x07060302u);
    *ah = H.v; *al = L.v;
}

// swizzled [c][s] plane (64x64 shorts)
__device__ __forceinline__ int swz(int c, int s) {
    return c * 64 + ((((s >> 3) ^ (c & 7)) << 3) | (s & 7));
}
// swizzled [s][c] plane
__device__ __forceinline__ int swz2(int s, int c) {
    return s * 64 + ((((c >> 3) ^ (s & 7)) << 3) | (c & 7));
}

// fragment-table index helpers (element offsets; each frag = lane*8 shorts)
__device__ __host__ __forceinline__ int AF_IDX(int tile, int kk, int mt, int lane) {
    return (((tile * 2 + kk) * 2 + mt) * 64 + lane) * 8;
}
__device__ __host__ __forceinline__ int MTF_IDX(int row16, int lane) {
    return (row16 * 64 + lane) * 8;
}
__device__ __host__ __forceinline__ int CWF_IDX(int L, int br, int w, int kk, int ni) {
    return ((((L * 2 + br) * 2 + w) * 2 + kk) * 2 + ni) * 512;
}
__device__ __host__ __forceinline__ int DF_IDX(int bb, int w, int ni) {
    return ((bb * 2 + w) * 2 + ni) * 512;
}
__device__ __host__ __forceinline__ int W1F_IDX(int br, int half, int kk, int ni) {
    return (((br * 2 + half) * 2 + kk) * 4 + ni) * 512;
}
// fragment-ordered activation plane (u32 element offset):
// VF[b][tile][mi][kk][lane][8]; element j holds v[s=tile*64+mi*16+(lane&15)]
// [c=kk*32+(lane>>4)*8+j] packed hi|lo<<16.
__device__ __forceinline__ size_t VF_IDX(int b, int tile, int mi, int kk, int lane) {
    return ((size_t)(((b * 16 + tile) * 4 + mi) * 2 + kk) * 64 + lane) * 8;
}

// 2-wave proj: A[28 x 64-s-tile] x P[64c x 64s] -> Ppart. Wave w owns c-half.
__device__ __forceinline__ void proj2(
    const unsigned short* Phi, const unsigned short* Plo,
    const unsigned short* __restrict__ AFhi, const unsigned short* __restrict__ AFlo,
    float* __restrict__ Ppart, int bb, int tile, int t)
{
    const int lane = t & 63;
    const int w    = t >> 6;
    const int qr   = lane >> 4;
    const int ln   = lane & 15;

    s16x8 pah[2][2], pal[2][2];      // [kk][mt]
#pragma unroll
    for (int kk = 0; kk < 2; ++kk)
#pragma unroll
        for (int mt = 0; mt < 2; ++mt) {
            const int off = AF_IDX(tile, kk, mt, lane);
            pah[kk][mt] = *(const s16x8*)&AFhi[off];
            pal[kk][mt] = *(const s16x8*)&AFlo[off];
        }

    f32x4 pP[2][2], pS[2][2];
#pragma unroll
    for (int mt = 0; mt < 2; ++mt)
#pragma unroll
        for (int ni = 0; ni < 2; ++ni) {
            pP[mt][ni] = (f32x4){0.f,0.f,0.f,0.f};
            pS[mt][ni] = (f32x4){0.f,0.f,0.f,0.f};
        }

#pragma unroll
    for (int kk = 0; kk < 2; ++kk) {
        const int bk = kk * 4 + qr;
#pragma unroll
        for (int ni = 0; ni < 2; ++ni) {
            const int c = w * 32 + ni * 16 + ln;
            const int boff = c * 64 + ((bk ^ (c & 7)) << 3);
            s16x8 bh = *(const s16x8*)&Phi[boff];
            s16x8 bl = *(const s16x8*)&Plo[boff];
#pragma unroll
            for (int mt = 0; mt < 2; ++mt) {
                pP[mt][ni] = __builtin_amdgcn_mfma_f32_16x16x32_bf16(pah[kk][mt], bh, pP[mt][ni], 0, 0, 0);
                pS[mt][ni] = __builtin_amdgcn_mfma_f32_16x16x32_bf16(pal[kk][mt], bh, pS[mt][ni], 0, 0, 0);
                pS[mt][ni] = __builtin_amdgcn_mfma_f32_16x16x32_bf16(pah[kk][mt], bl, pS[mt][ni], 0, 0, 0);
            }
        }
    }
#pragma unroll
    for (int mt = 0; mt < 2; ++mt)
#pragma unroll
        for (int ni = 0; ni < 2; ++ni) {
            const int c = w * 32 + ni * 16 + ln;
            f32x4 pv = pP[mt][ni] + pS[mt][ni];
#pragma unroll
            for (int r = 0; r < 4; ++r) {
                const int xr = mt * 16 + qr * 4 + r;
                if (xr < 28)
                    Ppart[((size_t)(bb * NT + tile) * 28 + xr) * 64 + c] = pv[r];
            }
        }
}

// ---------------------------------------------------------------------------
// setup: 0..1023 A columns; 1024..1051 M rows; 1052..1117 data cascade;
//        1118..1373 weight prep (256 blocks); 1374..1629 WsT (256 blocks).
// ---------------------------------------------------------------------------
__global__ __launch_bounds__(256) void setup_kernel(
    const float* __restrict__ x,
    unsigned short* __restrict__ AFhi, unsigned short* __restrict__ AFlo,
    unsigned short* __restrict__ MTFhi, unsigned short* __restrict__ MTFlo,
    float* __restrict__ axbuf,
    const float* __restrict__ fc1w_0, const float* __restrict__ fc1w_1,
    const float* __restrict__ cw_0, const float* __restrict__ cw_1,
    const float* __restrict__ w1_0, const float* __restrict__ w2_0,
    const float* __restrict__ w1_1, const float* __restrict__ w2_1,
    unsigned short* __restrict__ w1Fhi, unsigned short* __restrict__ w1Flo,
    unsigned short* __restrict__ cwFhi, unsigned short* __restrict__ cwFlo,
    unsigned short* __restrict__ DFhi,  unsigned short* __restrict__ DFlo,
    float* __restrict__ WsT)
{
    __shared__ float Af[1024];
    __shared__ float Bff[520];
    __shared__ float hib[14];
    const int t = threadIdx.x;

    if (blockIdx.x < 1024 || (blockIdx.x >= 1052 && blockIdx.x < 1118)) {
        const bool isA = (blockIdx.x < 1024);
        const int s0 = blockIdx.x;
        const int di = blockIdx.x - 1052;
        for (int i = t; i < SLEN; i += 256) {
            float v;
            if (isA)           v = (i == s0) ? 1.0f : 0.0f;
            else if (di < 64)  v = x[di * SLEN + i];
            else if (di == 64) v = (float)i * (1.0f / 1023.0f);
            else               v = 1.0f;
            Af[i] = v;
        }
        __syncthreads();

        const int NIN[8]  = {1024, 517, 264, 137, 74, 42, 26, 18};
        const int NOUT[8] = { 517, 264, 137,  74, 42, 26, 18, 14};
        // column decomposition for AF writes
        const int tile = s0 >> 6, kkc = (s0 >> 5) & 1, qrc = (s0 >> 3) & 3,
                  jc = s0 & 7;
#pragma unroll
        for (int lev = 0; lev < 8; ++lev) {
            float* in  = (lev & 1) ? Bff : Af;
            float* out = (lev & 1) ? Af : Bff;
            const int nin = NIN[lev], nout = NOUT[lev];
            for (int m = t; m < nout; m += 256) {
                float alo = 0.f, ahi = 0.f;
#pragma unroll
                for (int tt = 0; tt < 12; ++tt) {
                    int jj = 2 * m + tt - 10;
                    if (jj < 0)         jj = -1 - jj;
                    else if (jj >= nin) jj = 2 * nin - 1 - jj;
                    float xv = in[jj];
                    alo += xv * RLv[tt];
                    if (lev == 7) ahi += xv * AHv[tt];
                }
                out[m] = alo;
                if (lev == 7) {
                    if (isA) {
                        unsigned short h1 = f2bf(alo);
                        unsigned short l1 = f2bf(alo - bf2f(h1));
                        {   // row m (0..13)
                            const int lane = qrc * 16 + (m & 15);
                            const int off = AF_IDX(tile, kkc, m >> 4, lane) + jc;
                            AFhi[off] = h1; AFlo[off] = l1;
                        }
                        unsigned short h2 = f2bf(ahi);
                        unsigned short l2 = f2bf(ahi - bf2f(h2));
                        {   // row 14+m
                            const int row = 14 + m;
                            const int lane = qrc * 16 + (row & 15);
                            const int off = AF_IDX(tile, kkc, row >> 4, lane) + jc;
                            AFhi[off] = h2; AFlo[off] = l2;
                        }
                    } else {
                        axbuf[di * 28 + m]      = alo;
                        axbuf[di * 28 + 14 + m] = ahi;
                    }
                }
            }
            __syncthreads();
        }
        if (isA && t < 4) {
            {   // A pad rows 28..31 at column s0
                const int row = 28 + t;
                const int lane = qrc * 16 + (row & 15);
                const int off = AF_IDX(tile, kkc, 1, lane) + jc;
                AFhi[off] = 0; AFlo[off] = 0;
            }
            {   // MT pad cols 28..31 at row s0
                const int col = 28 + t;
                const int lane = (col >> 3) * 16 + (s0 & 15);
                const int off = MTF_IDX(s0 >> 4, lane) + (col & 7);
                MTFhi[off] = 0; MTFlo[off] = 0;
            }
        }
        return;
    }

    if (blockIdx.x >= 1374) {
        // WsT: [(L*2+br)*28 + x][i*64+o]; 256 blocks, 16 per slab.
        const int wsb  = blockIdx.x - 1374;      // 0..255
        const int slab = wsb >> 4;               // 0..15
        const int sub  = wsb & 15;               // 0..15
        const int L = slab >> 2, br = (slab >> 1) & 1, which = slab & 1;
        const float* src = (which ? (br ? w2_1 : w2_0) : (br ? w1_1 : w1_0))
                         + (size_t)L * 64 * 64 * 14;
        const size_t dbase = ((size_t)(L * 2 + br) * 28 + which * 14) * 4096;
        const int e = sub * 256 + t;             // one element per thread
        const float* sp = src + (size_t)e * 14;
        float v[14];
#pragma unroll
        for (int xi = 0; xi < 14; ++xi) v[xi] = sp[xi];
#pragma unroll
        for (int xi = 0; xi < 14; ++xi)
            WsT[dbase + (size_t)xi * 4096 + e] = v[xi];
        return;
    }

    if (blockIdx.x >= 1118) {
        // weight prep (fragment-order outputs); 256 blocks.
        const int gid = (blockIdx.x - 1118) * 256 + t;   // 0..65535
        for (int idx = gid; idx < 16384; idx += 65536) {
            int br = idx >> 13, r = idx & 8191;
            int h = r >> 6, c = r & 63;
            float f = (br ? fc1w_1 : fc1w_0)[c * 128 + h];
            unsigned short hh = f2bf(f);
            const int half = (h >> 6) & 1, ni = (h >> 4) & 3, lnh = h & 15;
            const int kk = c >> 5, qr = (c >> 3) & 3, j = c & 7;
            const int off = W1F_IDX(br, half, kk, ni) + (qr * 16 + lnh) * 8 + j;
            w1Fhi[off] = hh;
            w1Flo[off] = f2bf(f - bf2f(hh));
        }
        for (int idx = gid; idx < 32768; idx += 65536) {   // cwT split, all layers
            int L = idx >> 13, br = (idx >> 12) & 1, e = idx & 4095;
            int k = e >> 6, o = e & 63;
            float val = (br ? cw_1 : cw_0)[(size_t)L * 4096 + o * 64 + k]
                      + ((k == o) ? 1.0f : 0.0f);
            unsigned short h = f2bf(val);
            const int w = o >> 5, ni = (o >> 4) & 1, lno = o & 15;
            const int kk = k >> 5, qr = (k >> 3) & 3, j = k & 7;
            const int off = CWF_IDX(L, br, w, kk, ni) + (qr * 16 + lno) * 8 + j;
            cwFhi[off] = h;
            cwFlo[off] = f2bf(val - bf2f(h));
        }
        for (int idx = gid; idx < 32768; idx += 65536) {   // D pad x=28..31
            int bb = idx >> 8, o = (idx >> 2) & 63, j3 = idx & 3;
            const int x = 28 + j3;
            const int w = o >> 5, ni = (o >> 4) & 1, lno = o & 15;
            const int off = DF_IDX(bb, w, ni) + ((x >> 3) * 16 + lno) * 8 + (x & 7);
            DFhi[off] = 0;
            DFlo[off] = 0;
        }
        return;
    }

    // synthesis rows (M^T) -> MTF fragment order
    const int u = blockIdx.x - 1024;     // 0..27
    if (t < 14) {
        Af[t]  = (u < 14 && t == u) ? 1.0f : 0.0f;
        hib[t] = (u >= 14 && t == (u - 14)) ? 1.0f : 0.0f;
    }
    __syncthreads();

    const int NH[8] = {14, 18, 26, 42, 74, 137, 264, 517};
    const int NO[8] = {18, 26, 42, 74, 138, 264, 518, 1024};

#pragma unroll
    for (int s = 0; s < 8; ++s) {
        const float* lo = (s & 1) ? Bff : Af;
        float* out      = (s & 1) ? Af : Bff;
        const int N = NH[s], nout = NO[s];
        for (int m = t; m < nout; m += 256) {
            float acc = 0.f;
#pragma unroll
            for (int tt = 0; tt < 12; ++tt) {
                int uu = m + tt - 1;
                if ((uu & 1) == 0) {
                    int q = uu >> 1;
                    if (q < N) {
                        acc += lo[q] * SLv[tt];
                        if (s == 0) acc += hib[q] * SHv[tt];
                    }
                }
            }
            out[m] = acc;
        }
        __syncthreads();
    }
    {
        const int qr = u >> 3, j = u & 7;
        for (int m = t; m < SLEN; m += 256) {
            float f = Af[m];
            unsigned short h = f2bf(f);
            const int off = MTF_IDX(m >> 4, qr * 16 + (m & 15)) + j;
            MTFhi[off] = h;
            MTFlo[off] = f2bf(f - bf2f(h));
        }
    }
}

// ---------------------------------------------------------------------------
// mix0: layer-0 mix from rank-3 formula; writes DF in fragment order.
// ---------------------------------------------------------------------------
__global__ __launch_bounds__(256) void mix0_kernel(
    const float* __restrict__ axbuf,
    const float* __restrict__ fc0w_0, const float* __restrict__ fc0b_0,
    const float* __restrict__ fc0w_1, const float* __restrict__ fc0b_1,
    const float* __restrict__ WsT0,
    unsigned short* __restrict__ DFhi, unsigned short* __restrict__ DFlo)
{
    const int t = threadIdx.x;
    const int br  = blockIdx.x / 224;
    const int sub = blockIdx.x % 224;

    __shared__ float Ws[64][65];
    __shared__ float LO[8][64];
    const int o = t & 63;
    const int w = t >> 6;
    const int x  = sub >> 3;
    const int b0 = (sub & 7) << 3;

    const float* wsrc = WsT0 + ((size_t)(br * 28 + x)) * 4096;
    for (int idx = t; idx < 4096; idx += 256)
        Ws[idx >> 6][idx & 63] = wsrc[idx];

    const float* fc0w = br ? fc0w_1 : fc0w_0;
    const float* fc0b = br ? fc0b_1 : fc0b_0;
    const float agv = axbuf[64 * 28 + x];
    const float a1v = axbuf[65 * 28 + x];
    const float w0o = fc0w[o];
    const float wgo = fc0w[WCH + o];
    const float b0o = fc0b[o];

#pragma unroll
    for (int j = 0; j < 2; ++j) {
        int bi = w + 4 * j;
        int b  = b0 + bi;
        float axv = axbuf[b * 28 + x];
        LO[bi][o] = axv * w0o + agv * wgo + a1v * b0o;
    }
    __syncthreads();

    const int wo = o >> 5, nio = (o >> 4) & 1, lno = o & 15;
    const int dsub = ((x >> 3) * 16 + lno) * 8 + (x & 7);
#pragma unroll
    for (int j = 0; j < 2; ++j) {
        int bi = w + 4 * j;
        int bb = br * 64 + b0 + bi;
        float acc = 0.f;
        for (int i = 0; i < 64; ++i)
            acc += LO[bi][i] * Ws[i][o];
        acc -= LO[bi][o];
        unsigned short h = f2bf(acc);
        const int off = DF_IDX(bb, wo, nio) + dsub;
        DFhi[off] = h;
        DFlo[off] = f2bf(acc - bf2f(h));
    }
}

// ---------------------------------------------------------------------------
// Mix (layers 1..3): reads Ppart; writes DF in fragment order.
// ---------------------------------------------------------------------------
__global__ __launch_bounds__(256) void mix_kernel(
    const float* __restrict__ Ppart,
    const float* __restrict__ WsTL,
    unsigned short* __restrict__ DFhi, unsigned short* __restrict__ DFlo)
{
    const int t = threadIdx.x;
    const int br  = blockIdx.x / 224;
    const int sub = blockIdx.x % 224;

    __shared__ float Ws[64][65];
    __shared__ float LO[8][64];
    const int o = t & 63;
    const int w = t >> 6;
    const int x  = sub >> 3;
    const int b0 = (sub & 7) << 3;

    const float* wsrc = WsTL + ((size_t)(br * 28 + x)) * 4096;
    for (int idx = t; idx < 4096; idx += 256)
        Ws[idx >> 6][idx & 63] = wsrc[idx];

#pragma unroll
    for (int j = 0; j < 2; ++j) {
        int bi = w + 4 * j;
        int bb = br * 64 + b0 + bi;
        float s = 0.f;
        for (int tile = 0; tile < NT; ++tile)
            s += Ppart[((size_t)(bb * NT + tile) * 28 + x) * 64 + o];
        LO[bi][o] = s;
    }
    __syncthreads();

    const int wo = o >> 5, nio = (o >> 4) & 1, lno = o & 15;
    const int dsub = ((x >> 3) * 16 + lno) * 8 + (x & 7);
#pragma unroll
    for (int j = 0; j < 2; ++j) {
        int bi = w + 4 * j;
        int bb = br * 64 + b0 + bi;
        float acc = 0.f;
        for (int i = 0; i < 64; ++i)
            acc += LO[bi][i] * Ws[i][o];
        acc -= LO[bi][o];
        unsigned short h = f2bf(acc);
        const int off = DF_IDX(bb, wo, nio) + dsub;
        DFhi[off] = h;
        DFlo[off] = f2bf(acc - bf2f(h));
    }
}

// ---------------------------------------------------------------------------
// Fused layer (i = 0,1,2): 2048 blocks x 128 thr, 2 waves per 64-s tile.
// All operand-fragment AND activation loads coalesced. No barriers.
// ---------------------------------------------------------------------------
__global__ __launch_bounds__(128, 3) void layer_kernel(
    const unsigned int* __restrict__ vin0, const unsigned int* __restrict__ vin1,
    unsigned int* __restrict__ vout0, unsigned int* __restrict__ vout1,
    const unsigned short* __restrict__ MTFhi, const unsigned short* __restrict__ MTFlo,
    const unsigned short* __restrict__ AFhi,  const unsigned short* __restrict__ AFlo,
    const unsigned short* __restrict__ cwFhi, const unsigned short* __restrict__ cwFlo,
    const unsigned short* __restrict__ DFhi,   const unsigned short* __restrict__ DFlo,
    const float* __restrict__ cb_0, const float* __restrict__ cb_1,
    const float* __restrict__ fc0w_0, const float* __restrict__ fc0b_0,
    const float* __restrict__ fc0w_1, const float* __restrict__ fc0b_1,
    const float* __restrict__ xin,
    float* __restrict__ Ppart, int Lidx)
{
    __shared__ unsigned short Phi[4096];   // block-shared swizzled [c][s64]
    __shared__ unsigned short Plo[4096];

    const int t = threadIdx.x;
    const int bid = blockIdx.x;
    const int br  = bid >> 10;
    const int rem = bid & 1023;
    const int b    = rem >> 4;
    const int tile = rem & 15;
    const int s0   = tile << 6;
    const size_t bS = (size_t)b * SLEN;
    const unsigned int* vin = br ? vin1 : vin0;
    unsigned int* vout      = br ? vout1 : vout0;
    const float* cb = br ? cb_1 : cb_0;
    const float* f0w = br ? fc0w_1 : fc0w_0;
    const float* f0b = br ? fc0b_1 : fc0b_0;
    const int bb = br * 64 + b;

    const int lane = t & 63;
    const int w    = t >> 6;          // 0..1: o-half
    const int qr   = lane >> 4;
    const int ln   = lane & 15;

    // ---- preload B fragments (coalesced: base + lane*16B) ----
    s16x8 Bh[2][2], Bl[2][2];
#pragma unroll
    for (int kk = 0; kk < 2; ++kk)
#pragma unroll
        for (int ni = 0; ni < 2; ++ni) {
            const int off = CWF_IDX(Lidx, br, w, kk, ni) + lane * 8;
            Bh[kk][ni] = *(const s16x8*)&cwFhi[off];
            Bl[kk][ni] = *(const s16x8*)&cwFlo[off];
        }
    s16x8 Dhf[2], Dlf[2];
#pragma unroll
    for (int ni = 0; ni < 2; ++ni) {
        const int off = DF_IDX(bb, w, ni) + lane * 8;
        Dhf[ni] = *(const s16x8*)&DFhi[off];
        Dlf[ni] = *(const s16x8*)&DFlo[off];
    }
    float cbv[2];
#pragma unroll
    for (int ni = 0; ni < 2; ++ni) cbv[ni] = cb[w * 32 + ni * 16 + ln];

    // ---- prefetch vin (or x) for mi=0 (VF: base + lane*32B, coalesced) ----
    uint4 vb[2][2];                 // [kk][half]
    float xpf = 0.f;
    if (Lidx == 0) {
        xpf = xin[bS + s0 + ln];
    } else {
#pragma unroll
        for (int kk = 0; kk < 2; ++kk) {
            const size_t a0 = VF_IDX(b, tile, 0, kk, lane);
            vb[kk][0] = *(const uint4*)&vin[a0];
            vb[kk][1] = *(const uint4*)&vin[a0 + 4];
        }
    }

    // ---- 4 m-tiles ----
#pragma unroll
    for (int mi = 0; mi < 4; ++mi) {
        const int srow = mi * 16 + ln;
        uint4 vn[2][2];
        float xnf = 0.f;
        if (mi < 3) {
            if (Lidx == 0) {
                xnf = xin[bS + s0 + (mi + 1) * 16 + ln];
            } else {
#pragma unroll
                for (int kk = 0; kk < 2; ++kk) {
                    const size_t an = VF_IDX(b, tile, mi + 1, kk, lane);
                    vn[kk][0] = *(const uint4*)&vin[an];
                    vn[kk][1] = *(const uint4*)&vin[an + 4];
                }
            }
        }

        f32x4 accP[2], accS[2];
#pragma unroll
        for (int ni = 0; ni < 2; ++ni) {
            accP[ni] = (f32x4){0.f,0.f,0.f,0.f};
            accS[ni] = (f32x4){0.f,0.f,0.f,0.f};
        }

#pragma unroll
        for (int kk = 0; kk < 2; ++kk) {
            s16x8 ah, al;
            if (Lidx == 0) {
                const int s = s0 + srow;
                const float gv = (float)s * (1.0f / 1023.0f);
#pragma unroll
                for (int j = 0; j < 8; ++j) {
                    const int c = kk * 32 + qr * 8 + j;
                    float val = xpf * f0w[c] + gv * f0w[WCH + c] + f0b[c];
                    unsigned short h = f2bf(val);
                    ah[j] = (short)h;
                    al[j] = (short)f2bf(val - bf2f(h));
                }
            } else {
                unpack_frag2(vb[kk][0], vb[kk][1], &ah, &al);
            }
#pragma unroll
            for (int ni = 0; ni < 2; ++ni) {
                accP[ni] = __builtin_amdgcn_mfma_f32_16x16x32_bf16(ah, Bh[kk][ni], accP[ni], 0, 0, 0);
                accS[ni] = __builtin_amdgcn_mfma_f32_16x16x32_bf16(al, Bh[kk][ni], accS[ni], 0, 0, 0);
                accS[ni] = __builtin_amdgcn_mfma_f32_16x16x32_bf16(ah, Bl[kk][ni], accS[ni], 0, 0, 0);
            }
        }
        {
            const int off = MTF_IDX((s0 >> 4) + mi, lane);
            s16x8 mh = *(const s16x8*)&MTFhi[off];
            s16x8 ml = *(const s16x8*)&MTFlo[off];
#pragma unroll
            for (int ni = 0; ni < 2; ++ni) {
                accP[ni] = __builtin_amdgcn_mfma_f32_16x16x32_bf16(mh, Dhf[ni], accP[ni], 0, 0, 0);
                accS[ni] = __builtin_amdgcn_mfma_f32_16x16x32_bf16(ml, Dhf[ni], accS[ni], 0, 0, 0);
                accS[ni] = __builtin_amdgcn_mfma_f32_16x16x32_bf16(mh, Dlf[ni], accS[ni], 0, 0, 0);
            }
        }
        // epilogue: gelu, split, VF-order global store + packed b64 LDS writes
#pragma unroll
        for (int ni = 0; ni < 2; ++ni) {
            const int o = w * 32 + ni * 16 + ln;
            f32x4 acc = accP[ni] + accS[ni];
            u16x4 hv, lv;
            // consumer-fragment coords for channel o: kk'=w, lane' varies by r
            const int lgrp = (ni * 2 + (ln >> 3)) * 16;   // lane' base
            const int jj = ln & 7;
#pragma unroll
            for (int r = 0; r < 4; ++r) {
                float val = gelu_f(acc[r] + cbv[ni]);
                unsigned short h = f2bf(val);
                unsigned short l = f2bf(val - bf2f(h));
                vout[VF_IDX(b, tile, mi, w, lgrp + qr * 4 + r) + jj] =
                    (unsigned int)h | ((unsigned int)l << 16);
                hv[r] = h;
                lv[r] = l;
            }
            const int a = swz(o, mi * 16 + qr * 4);
            *(u16x4*)&Phi[a] = hv;
            *(u16x4*)&Plo[a] = lv;
        }
        if (mi < 3) {
            if (Lidx == 0) {
                xpf = xnf;
            } else {
#pragma unroll
                for (int kk = 0; kk < 2; ++kk) {
                    vb[kk][0] = vn[kk][0]; vb[kk][1] = vn[kk][1];
                }
            }
        }
    }

    // ---- proj on own c-half (same-wave LDS RAW: no barrier needed) ----
    proj2(Phi, Plo, AFhi, AFlo, Ppart, bb, tile, t);
}

// ---------------------------------------------------------------------------
// Head with fused layer 3, BOTH branches, 32-s blocks: 2048 blocks x 256 thr
// (4 waves = {br}x{o-half}). All fragment + activation loads coalesced.
// ---------------------------------------------------------------------------
__global__ __launch_bounds__(256, 2) void head_kernel(
    const unsigned int* __restrict__ vin0, const unsigned int* __restrict__ vin1,
    const unsigned short* __restrict__ MTFhi, const unsigned short* __restrict__ MTFlo,
    const unsigned short* __restrict__ cwFhi, const unsigned short* __restrict__ cwFlo,
    const unsigned short* __restrict__ DFhi,   const unsigned short* __restrict__ DFlo,
    const float* __restrict__ cb_0, const float* __restrict__ cb_1,
    const unsigned short* __restrict__ w1Fhi, const unsigned short* __restrict__ w1Flo,
    const float* __restrict__ fc1b_0, const float* __restrict__ fc2w_0,
    const float* __restrict__ fc2b_0,
    const float* __restrict__ fc1b_1, const float* __restrict__ fc2w_1,
    const float* __restrict__ fc2b_1,
    float* __restrict__ out)
{
    __shared__ unsigned short Vh[4096];    // [br][swz2 32x64 plane]
    __shared__ unsigned short Vl[4096];
    __shared__ float SP[4][32];            // per-wave partials

    const int t = threadIdx.x;
    const int bid = blockIdx.x;            // 0..2047
    const int b    = bid >> 5;
    const int t32  = bid & 31;
    const int s0   = t32 << 5;
    const size_t bS = (size_t)b * SLEN;
    const int tile64 = t32 >> 1;           // VF tile
    const int mibase = (t32 & 1) * 2;      // VF mi base

    const int lane = t & 63;
    const int w    = t >> 6;          // 0..3
    const int br   = w >> 1;
    const int half = w & 1;
    const int qr   = lane >> 4;
    const int ln   = lane & 15;

    const unsigned int* vin = br ? vin1 : vin0;
    const float* cb   = (br ? cb_1 : cb_0) + 3 * WCH;
    const float* fc1b = br ? fc1b_1 : fc1b_0;
    const float* fc2w = br ? fc2w_1 : fc2w_0;
    const int bb = br * 64 + b;
    unsigned short* Vhp = Vh + br * 2048;
    unsigned short* Vlp = Vl + br * 2048;

    // ---- phase A: layer-3, own (br, 32-o half), 32 s-rows ----
    {
        s16x8 Bh[2][2], Bl[2][2];
#pragma unroll
        for (int kk = 0; kk < 2; ++kk)
#pragma unroll
            for (int ni = 0; ni < 2; ++ni) {
                const int off = CWF_IDX(3, br, half, kk, ni) + lane * 8;
                Bh[kk][ni] = *(const s16x8*)&cwFhi[off];
                Bl[kk][ni] = *(const s16x8*)&cwFlo[off];
            }
        s16x8 Dhf[2], Dlf[2];
#pragma unroll
        for (int ni = 0; ni < 2; ++ni) {
            const int off = DF_IDX(bb, half, ni) + lane * 8;
            Dhf[ni] = *(const s16x8*)&DFhi[off];
            Dlf[ni] = *(const s16x8*)&DFlo[off];
        }
        float cbv[2];
#pragma unroll
        for (int ni = 0; ni < 2; ++ni) cbv[ni] = cb[half * 32 + ni * 16 + ln];

        uint4 vb[2][2];
#pragma unroll
        for (int kk = 0; kk < 2; ++kk) {
            const size_t a0 = VF_IDX(b, tile64, mibase, kk, lane);
            vb[kk][0] = *(const uint4*)&vin[a0];
            vb[kk][1] = *(const uint4*)&vin[a0 + 4];
        }

#pragma unroll
        for (int mi = 0; mi < 2; ++mi) {
            uint4 vn[2][2];
            if (mi < 1) {
#pragma unroll
                for (int kk = 0; kk < 2; ++kk) {
                    const size_t an = VF_IDX(b, tile64, mibase + 1, kk, lane);
                    vn[kk][0] = *(const uint4*)&vin[an];
                    vn[kk][1] = *(const uint4*)&vin[an + 4];
                }
            }
            f32x4 accP[2], accS[2];
#pragma unroll
            for (int ni = 0; ni < 2; ++ni) {
                accP[ni] = (f32x4){0.f,0.f,0.f,0.f};
                accS[ni] = (f32x4){0.f,0.f,0.f,0.f};
            }

#pragma unroll
            for (int kk = 0; kk < 2; ++kk) {
                s16x8 ah, al;
                unpack_frag2(vb[kk][0], vb[kk][1], &ah, &al);
#pragma unroll
                for (int ni = 0; ni < 2; ++ni) {
                    accP[ni] = __builtin_amdgcn_mfma_f32_16x16x32_bf16(ah, Bh[kk][ni], accP[ni], 0, 0, 0);
                    accS[ni] = __builtin_amdgcn_mfma_f32_16x16x32_bf16(al, Bh[kk][ni], accS[ni], 0, 0, 0);
                    accS[ni] = __builtin_amdgcn_mfma_f32_16x16x32_bf16(ah, Bl[kk][ni], accS[ni], 0, 0, 0);
                }
            }
            {
                const int off = MTF_IDX(t32 * 2 + mi, lane);
                s16x8 mh = *(const s16x8*)&MTFhi[off];
                s16x8 ml = *(const s16x8*)&MTFlo[off];
#pragma unroll
                for (int ni = 0; ni < 2; ++ni) {
                    accP[ni] = __builtin_amdgcn_mfma_f32_16x16x32_bf16(mh, Dhf[ni], accP[ni], 0, 0, 0);
                    accS[ni] = __builtin_amdgcn_mfma_f32_16x16x32_bf16(ml, Dhf[ni], accS[ni], 0, 0, 0);
                    accS[ni] = __builtin_amdgcn_mfma_f32_16x16x32_bf16(mh, Dlf[ni], accS[ni], 0, 0, 0);
                }
            }
#pragma unroll
            for (int ni = 0; ni < 2; ++ni) {
                const int o = half * 32 + ni * 16 + ln;
                f32x4 acc = accP[ni] + accS[ni];
#pragma unroll
                for (int r = 0; r < 4; ++r) {
                    const int sl32 = mi * 16 + qr * 4 + r;
                    float val = acc[r] + cbv[ni];
                    unsigned short h = f2bf(val);
                    unsigned short l = f2bf(val - bf2f(h));
                    const int a = swz2(sl32, o);
                    Vhp[a] = h;
                    Vlp[a] = l;
                }
            }
            if (mi < 1) {
#pragma unroll
                for (int kk = 0; kk < 2; ++kk) {
                    vb[kk][0] = vn[kk][0]; vb[kk][1] = vn[kk][1];
                }
            }
        }
    }
    __syncthreads();

    // ---- phase B: fc1 GEMM, own (br, 64-h half), 32 s-rows ----
    s16x8 Wh[2][4], Wl[2][4];
#pragma unroll
    for (int kk = 0; kk < 2; ++kk)
#pragma unroll
        for (int ni = 0; ni < 4; ++ni) {
            const int off = W1F_IDX(br, half, kk, ni) + lane * 8;
            Wh[kk][ni] = *(const s16x8*)&w1Fhi[off];
            Wl[kk][ni] = *(const s16x8*)&w1Flo[off];
        }
    float b1v[4], w2v[4];
#pragma unroll
    for (int ni = 0; ni < 4; ++ni) {
        b1v[ni] = fc1b[half * 64 + ni * 16 + ln];
        w2v[ni] = fc2w[half * 64 + ni * 16 + ln];
    }

#pragma unroll
    for (int mi = 0; mi < 2; ++mi) {
        f32x4 a1P[4], a1S[4];
#pragma unroll
        for (int ni = 0; ni < 4; ++ni) {
            a1P[ni] = (f32x4){0.f,0.f,0.f,0.f};
            a1S[ni] = (f32x4){0.f,0.f,0.f,0.f};
        }

#pragma unroll
        for (int kk = 0; kk < 2; ++kk) {
            const int blk = kk * 4 + qr;
            const int sl  = mi * 16 + ln;
            const int a   = sl * 64 + ((blk ^ (sl & 7)) << 3);
            s16x8 ah = *(const s16x8*)&Vhp[a];
            s16x8 al = *(const s16x8*)&Vlp[a];
#pragma unroll
            for (int ni = 0; ni < 4; ++ni) {
                a1P[ni] = __builtin_amdgcn_mfma_f32_16x16x32_bf16(ah, Wh[kk][ni], a1P[ni], 0, 0, 0);
                a1S[ni] = __builtin_amdgcn_mfma_f32_16x16x32_bf16(al, Wh[kk][ni], a1S[ni], 0, 0, 0);
                a1S[ni] = __builtin_amdgcn_mfma_f32_16x16x32_bf16(ah, Wl[kk][ni], a1S[ni], 0, 0, 0);
            }
        }
        float partial[4] = {0.f, 0.f, 0.f, 0.f};
#pragma unroll
        for (int ni = 0; ni < 4; ++ni) {
            f32x4 acc1 = a1P[ni] + a1S[ni];
#pragma unroll
            for (int r = 0; r < 4; ++r)
                partial[r] += gelu_f(acc1[r] + b1v[ni]) * w2v[ni];
        }
#pragma unroll
        for (int r = 0; r < 4; ++r) {
            partial[r] += __shfl_xor(partial[r], 1, 64);
            partial[r] += __shfl_xor(partial[r], 2, 64);
            partial[r] += __shfl_xor(partial[r], 4, 64);
            partial[r] += __shfl_xor(partial[r], 8, 64);
        }
        if (ln == 0) {
#pragma unroll
            for (int r = 0; r < 4; ++r)
                SP[w][mi * 16 + qr * 4 + r] = partial[r];
        }
    }
    __syncthreads();

    if (t < 32) {
        const float bias = fc2b_0[0] + fc2b_1[0];
        out[bS + s0 + t] = SP[0][t] + SP[1][t] + SP[2][t] + SP[3][t] + bias;
    }
}

// ---------------------------------------------------------------------------
extern "C" void kernel_launch(void* const* d_in, const int* in_sizes, int n_in,
                              void* d_out, int out_size, void* d_ws, size_t ws_size,
                              hipStream_t stream)
{
    const float* x = (const float*)d_in[0];
    const float* P[2][10];
    for (int br = 0; br < 2; ++br)
        for (int k = 0; k < 10; ++k)
            P[br][k] = (const float*)d_in[1 + br * 10 + k];
    // order: fc0_w, fc0_b, wave_w1, wave_w2, cw, cb, fc1_w, fc1_b, fc2_w, fc2_b

    char* p = (char*)d_ws;
    const size_t PL = (size_t)BC * SLEN * 4;   // one packed u32 plane: 16.78 MB
    unsigned int* vplane[4];                   // [br][pingpong]
    for (int i = 0; i < 4; ++i) { vplane[i] = (unsigned int*)p; p += PL; }
    unsigned short* AFhi  = (unsigned short*)p; p += 32768 * 2;
    unsigned short* AFlo  = (unsigned short*)p; p += 32768 * 2;
    unsigned short* MTFhi = (unsigned short*)p; p += 32768 * 2;
    unsigned short* MTFlo = (unsigned short*)p; p += 32768 * 2;
    float* Ppart = (float*)p;                  p += (size_t)128 * NT * 28 * 64 * 4;
    unsigned short* cwFhi = (unsigned short*)p; p += 32768 * 2;
    unsigned short* cwFlo = (unsigned short*)p; p += 32768 * 2;
    unsigned short* DFhi  = (unsigned short*)p; p += (size_t)128 * 2048 * 2;
    unsigned short* DFlo  = (unsigned short*)p; p += (size_t)128 * 2048 * 2;
    unsigned short* w1Fhi = (unsigned short*)p; p += 16384 * 2;
    unsigned short* w1Flo = (unsigned short*)p; p += 16384 * 2;
    float* axbuf          = (float*)p;          p += 66 * 28 * 4;
    float* WsT            = (float*)p;          p += (size_t)4 * 2 * 28 * 4096 * 4;

    unsigned int *v0a = vplane[0], *v0b = vplane[1];
    unsigned int *v1a = vplane[2], *v1b = vplane[3];

    setup_kernel<<<1630, 256, 0, stream>>>(
        x, AFhi, AFlo, MTFhi, MTFlo, axbuf,
        P[0][6], P[1][6], P[0][4], P[1][4],
        P[0][2], P[0][3], P[1][2], P[1][3],
        w1Fhi, w1Flo, cwFhi, cwFlo, DFhi, DFlo, WsT);

    mix0_kernel<<<448, 256, 0, stream>>>(
        axbuf, P[0][0], P[0][1], P[1][0], P[1][1],
        WsT, DFhi, DFlo);

    for (int i = 0; i < 3; ++i) {
        layer_kernel<<<2048, 128, 0, stream>>>(
            v0a, v1a, v0b, v1b,
            MTFhi, MTFlo, AFhi, AFlo, cwFhi, cwFlo, DFhi, DFlo,
            P[0][5] + (size_t)i * WCH, P[1][5] + (size_t)i * WCH,
            P[0][0], P[0][1], P[1][0], P[1][1], x,
            Ppart, i);
        unsigned int* tmp;
        tmp = v0a; v0a = v0b; v0b = tmp;
        tmp = v1a; v1a = v1b; v1b = tmp;

        mix_kernel<<<448, 256, 0, stream>>>(
            Ppart,
            WsT + (size_t)(i + 1) * 2 * 28 * 4096,
            DFhi, DFlo);
    }

    head_kernel<<<2048, 256, 0, stream>>>(
        v0a, v1a,
        MTFhi, MTFlo, cwFhi, cwFlo, DFhi, DFlo,
        P[0][5] + (size_t)3 * WCH, P[1][5] + (size_t)3 * WCH,
        w1Fhi, w1Flo,
        P[0][7], P[0][8], P[0][9],
        P[1][7], P[1][8], P[1][9],
        (float*)d_out);
}